// Round 3
// baseline (11211.189 us; speedup 1.0000x reference)
//
#include <hip/hip_runtime.h>
#include <hip/hip_bf16.h>

#define B_ 4
#define S_ 2048
#define D_ 512
#define H_ 8
#define HD_ 64
#define L_ 2
#define V_ 30000
#define NPATCH_ 16
#define PLEN_ 128

// ---------------- embed + n-gram hash add ----------------
__global__ __launch_bounds__(128) void embed_ngram_kernel(
    const int* __restrict__ bytes, const float* __restrict__ byte_emb,
    const float* __restrict__ ng_emb, float* __restrict__ x)
{
    const int bs = blockIdx.x;          // b*S + s
    const int s  = bs % S_;
    const int b  = bs / S_;
    const int d  = threadIdx.x * 4;     // 128 threads * 4 floats = 512
    const int* brow = bytes + (size_t)b * S_;

    const int c = brow[s];
    float4 v = *reinterpret_cast<const float4*>(byte_emb + (size_t)c * D_ + d);

    // n=3: 31^2,31,1 ; n=4: 31^3=29791,... ; n=5: 31^4 mod 30000 = 23521,...
    if (s >= 2) {
        int h = (brow[s-2]*961 + brow[s-1]*31 + brow[s]) % V_;
        const float4 g = *reinterpret_cast<const float4*>(ng_emb + ((size_t)0*V_ + h)*D_ + d);
        v.x += 0.25f*g.x; v.y += 0.25f*g.y; v.z += 0.25f*g.z; v.w += 0.25f*g.w;
    }
    if (s >= 3) {
        int h = (brow[s-3]*29791 + brow[s-2]*961 + brow[s-1]*31 + brow[s]) % V_;
        const float4 g = *reinterpret_cast<const float4*>(ng_emb + ((size_t)1*V_ + h)*D_ + d);
        v.x += 0.25f*g.x; v.y += 0.25f*g.y; v.z += 0.25f*g.z; v.w += 0.25f*g.w;
    }
    if (s >= 4) {
        int h = (brow[s-4]*23521 + brow[s-3]*29791 + brow[s-2]*961 + brow[s-1]*31 + brow[s]) % V_;
        const float4 g = *reinterpret_cast<const float4*>(ng_emb + ((size_t)2*V_ + h)*D_ + d);
        v.x += 0.25f*g.x; v.y += 0.25f*g.y; v.z += 0.25f*g.z; v.w += 0.25f*g.w;
    }
    *reinterpret_cast<float4*>(x + (size_t)bs * D_ + d) = v;
}

// ---------------- GEMM: Y = X @ W^T + bias [,relu][,+resid] ----------------
// X [M,K] f32 row-major, W [N,K] f32 row-major, Y [M,N] f32.
// M%64==0, N%64==0, K%16==0 at all call sites.
__global__ __launch_bounds__(256) void gemm_kernel(
    const float* __restrict__ X, const float* __restrict__ W,
    const float* __restrict__ bias, const float* __restrict__ resid,
    float* __restrict__ Y, int M, int N, int K, int do_relu)
{
    __shared__ float As[16][68];
    __shared__ float Bs[16][68];
    const int tid = threadIdx.x;
    const int bm = blockIdx.y * 64, bn = blockIdx.x * 64;
    const int ty = tid >> 4, tx = tid & 15;
    const int lrow = tid >> 2, lc4 = (tid & 3) * 4;

    float acc[4][4];
#pragma unroll
    for (int i = 0; i < 4; ++i)
#pragma unroll
        for (int j = 0; j < 4; ++j) acc[i][j] = 0.f;

    for (int k0 = 0; k0 < K; k0 += 16) {
        const float4 xv = *reinterpret_cast<const float4*>(X + (size_t)(bm + lrow) * K + k0 + lc4);
        const float4 wv = *reinterpret_cast<const float4*>(W + (size_t)(bn + lrow) * K + k0 + lc4);
        __syncthreads();
        As[lc4+0][lrow] = xv.x; As[lc4+1][lrow] = xv.y;
        As[lc4+2][lrow] = xv.z; As[lc4+3][lrow] = xv.w;
        Bs[lc4+0][lrow] = wv.x; Bs[lc4+1][lrow] = wv.y;
        Bs[lc4+2][lrow] = wv.z; Bs[lc4+3][lrow] = wv.w;
        __syncthreads();
#pragma unroll
        for (int kk = 0; kk < 16; ++kk) {
            float a0 = As[kk][ty*4+0], a1 = As[kk][ty*4+1], a2 = As[kk][ty*4+2], a3 = As[kk][ty*4+3];
            float b0 = Bs[kk][tx*4+0], b1 = Bs[kk][tx*4+1], b2 = Bs[kk][tx*4+2], b3 = Bs[kk][tx*4+3];
            acc[0][0] += a0*b0; acc[0][1] += a0*b1; acc[0][2] += a0*b2; acc[0][3] += a0*b3;
            acc[1][0] += a1*b0; acc[1][1] += a1*b1; acc[1][2] += a1*b2; acc[1][3] += a1*b3;
            acc[2][0] += a2*b0; acc[2][1] += a2*b1; acc[2][2] += a2*b2; acc[2][3] += a2*b3;
            acc[3][0] += a3*b0; acc[3][1] += a3*b1; acc[3][2] += a3*b2; acc[3][3] += a3*b3;
        }
    }

#pragma unroll
    for (int i = 0; i < 4; ++i) {
        const int m = bm + ty*4 + i;
#pragma unroll
        for (int j = 0; j < 4; ++j) {
            const int n = bn + tx*4 + j;
            float v = acc[i][j] + bias[n];
            if (do_relu) v = fmaxf(v, 0.f);
            if (resid) v += resid[(size_t)m * N + n];
            Y[(size_t)m * N + n] = v;
        }
    }
}

// ---------------- causal attention, one wave per (b,h,q) row --------------
// qkv rows: [q(512) | k(512) | v(512)], head h owns cols h*64..h*64+63.
__global__ __launch_bounds__(256) void attn_kernel(
    const float* __restrict__ qkv, float* __restrict__ o)
{
    const int wid  = blockIdx.x * 4 + (threadIdx.x >> 6);
    const int lane = threadIdx.x & 63;
    const int q  = wid % S_;
    const int bh = wid / S_;
    const int h  = bh % H_;
    const int b  = bh / H_;

    const float* base = qkv + (size_t)b * S_ * 1536;
    const float qv = base[(size_t)q * 1536 + h*HD_ + lane] * 0.125f;  // 1/sqrt(64) folded
    const float* kbase = base + 512 + h*HD_;

    float m = -INFINITY, l = 0.f, acc = 0.f;
    for (int k = 0; k <= q; ++k) {
        const float* row = kbase + (size_t)k * 1536;
        float s = qv * row[lane];
#pragma unroll
        for (int off = 32; off; off >>= 1) s += __shfl_xor(s, off, 64);
        const float vv = row[512 + lane];
        const float nm = fmaxf(m, s);
        const float al = __expf(m - nm);   // first iter: exp(-inf)=0
        const float p  = __expf(s - nm);
        l = l * al + p;
        acc = acc * al + p * vv;
        m = nm;
    }
    o[((size_t)b * S_ + q) * D_ + h*HD_ + lane] = acc / l;
}

// ---------------- LayerNorm (optional residual add) ----------------
__global__ __launch_bounds__(256) void ln_kernel(
    float* __restrict__ dst, const float* __restrict__ src, const float* __restrict__ add,
    const float* __restrict__ w, const float* __restrict__ b, float eps)
{
    const int row = blockIdx.x, tid = threadIdx.x;
    const int lane = tid & 63, wave = tid >> 6;
    float2 v = *reinterpret_cast<const float2*>(src + (size_t)row * D_ + tid*2);
    if (add) {
        float2 a = *reinterpret_cast<const float2*>(add + (size_t)row * D_ + tid*2);
        v.x += a.x; v.y += a.y;
    }
    __shared__ float red[8];
    float s = v.x + v.y;
#pragma unroll
    for (int off = 32; off; off >>= 1) s += __shfl_xor(s, off, 64);
    if (lane == 0) red[wave] = s;
    __syncthreads();
    const float mean = (red[0]+red[1]+red[2]+red[3]) * (1.f/D_);
    const float d0 = v.x - mean, d1 = v.y - mean;
    float sq = d0*d0 + d1*d1;
#pragma unroll
    for (int off = 32; off; off >>= 1) sq += __shfl_xor(sq, off, 64);
    if (lane == 0) red[4+wave] = sq;
    __syncthreads();
    const float var = (red[4]+red[5]+red[6]+red[7]) * (1.f/D_);
    const float inv = rsqrtf(var + eps);
    *reinterpret_cast<float2*>(dst + (size_t)row * D_ + tid*2) =
        make_float2(d0*inv*w[tid*2] + b[tid*2], d1*inv*w[tid*2+1] + b[tid*2+1]);
}

// ---------------- patch mean-pool ----------------
__global__ __launch_bounds__(256) void meanpool_kernel(
    const float* __restrict__ x, float* __restrict__ query)
{
    const int bp = blockIdx.x;           // 0..63
    const int d = threadIdx.x * 2;
    const float* base = x + (size_t)bp * PLEN_ * D_ + d;
    float s0 = 0.f, s1 = 0.f;
    for (int l = 0; l < PLEN_; ++l) {
        float2 v = *reinterpret_cast<const float2*>(base + (size_t)l * D_);
        s0 += v.x; s1 += v.y;
    }
    query[(size_t)bp*D_ + d]     = s0 * (1.f/PLEN_);
    query[(size_t)bp*D_ + d + 1] = s1 * (1.f/PLEN_);
}

// ---------------- patch cross-attention, one wave per (b,p,h) -------------
// kv rows (width 1024): [k(512) | v(512)]
__global__ __launch_bounds__(256) void patch_attn_kernel(
    const float* __restrict__ qbuf, const float* __restrict__ kv,
    float* __restrict__ o)
{
    const int wid  = blockIdx.x * 4 + (threadIdx.x >> 6);  // 0..511
    const int lane = threadIdx.x & 63;
    const int h  = wid % H_;
    const int bp = wid / H_;      // 0..63
    const float qv = qbuf[(size_t)bp*D_ + h*HD_ + lane] * 0.125f;
    const float* base = kv + (size_t)bp * PLEN_ * 1024 + h*HD_;

    float m = -INFINITY, l = 0.f, acc = 0.f;
    for (int t = 0; t < PLEN_; ++t) {
        const float* row = base + (size_t)t * 1024;
        float s = qv * row[lane];
#pragma unroll
        for (int off = 32; off; off >>= 1) s += __shfl_xor(s, off, 64);
        const float vv = row[512 + lane];
        const float nm = fmaxf(m, s);
        const float al = __expf(m - nm);
        const float p  = __expf(s - nm);
        l = l * al + p;
        acc = acc * al + p * vv;
        m = nm;
    }
    o[(size_t)bp*D_ + h*HD_ + lane] = acc / l;
}

extern "C" void kernel_launch(void* const* d_in, const int* in_sizes, int n_in,
                              void* d_out, int out_size, void* d_ws, size_t ws_size,
                              hipStream_t stream)
{
    const int*   byte_seq = (const int*)d_in[0];
    const float* byte_emb = (const float*)d_in[2];
    const float* ng_emb   = (const float*)d_in[3];
    const float* qkv_w = (const float*)d_in[4];
    const float* qkv_b = (const float*)d_in[5];
    const float* out_w = (const float*)d_in[6];
    const float* out_b = (const float*)d_in[7];
    const float* ln1_w = (const float*)d_in[8];
    const float* ln1_b = (const float*)d_in[9];
    const float* ln2_w = (const float*)d_in[10];
    const float* ln2_b = (const float*)d_in[11];
    const float* ff1_w = (const float*)d_in[12];
    const float* ff1_b = (const float*)d_in[13];
    const float* ff2_w = (const float*)d_in[14];
    const float* ff2_b = (const float*)d_in[15];
    const float* ca_qkv_w = (const float*)d_in[16];
    const float* ca_qkv_b = (const float*)d_in[17];
    const float* ca_out_w = (const float*)d_in[18];
    const float* ca_out_b = (const float*)d_in[19];
    const float* ca_ln_w  = (const float*)d_in[20];
    const float* ca_ln_b  = (const float*)d_in[21];
    const float* norm_w   = (const float*)d_in[22];
    const float* norm_b   = (const float*)d_in[23];
    float* out = (float*)d_out;          // reference output dtype is float32

    char* ws = (char*)d_ws;
    float* x    = (float*)(ws);                                  // 8192x512   (16MB)
    float* bufA = (float*)(ws + (size_t)16*1024*1024);           // 8192x2048  (64MB)
    float* bufB = (float*)(ws + (size_t)80*1024*1024);           // 8192x512   (16MB)
    float* query   = (float*)(ws + (size_t)96*1024*1024);        // 64x512
    float* qn      = query + 64*512;
    float* qsm     = qn + 64*512;
    float* oca     = qsm + 64*512;
    float* patches = oca + 64*512;

    const int M = B_ * S_;   // 8192

    // 1. byte embedding + n-gram hash adds
    embed_ngram_kernel<<<M, 128, 0, stream>>>(byte_seq, byte_emb, ng_emb, x);

    // 2. transformer layers
    for (int l = 0; l < L_; ++l) {
        gemm_kernel<<<dim3(1536/64, M/64), 256, 0, stream>>>(
            x, qkv_w + (size_t)l*1536*D_, qkv_b + l*1536, nullptr, bufA, M, 1536, D_, 0);
        attn_kernel<<<B_*H_*S_/4, 256, 0, stream>>>(bufA, bufB);
        gemm_kernel<<<dim3(D_/64, M/64), 256, 0, stream>>>(
            bufB, out_w + (size_t)l*D_*D_, out_b + l*D_, nullptr, bufA, M, D_, D_, 0);
        ln_kernel<<<M, 256, 0, stream>>>(x, x, bufA, ln1_w + l*D_, ln1_b + l*D_, 1e-5f);
        gemm_kernel<<<dim3(2048/64, M/64), 256, 0, stream>>>(
            x, ff1_w + (size_t)l*2048*D_, ff1_b + l*2048, nullptr, bufA, M, 2048, D_, 1);
        gemm_kernel<<<dim3(D_/64, M/64), 256, 0, stream>>>(
            bufA, ff2_w + (size_t)l*D_*2048, ff2_b + l*D_, nullptr, bufB, M, D_, 2048, 0);
        ln_kernel<<<M, 256, 0, stream>>>(x, x, bufB, ln2_w + l*D_, ln2_b + l*D_, 1e-5f);
    }

    // 3. patch cross-attention
    meanpool_kernel<<<B_*NPATCH_, 256, 0, stream>>>(x, query);
    ln_kernel<<<B_*NPATCH_, 256, 0, stream>>>(qn, query, nullptr, ca_ln_w, ca_ln_b, 1e-6f);
    ln_kernel<<<M, 256, 0, stream>>>(bufB, x, nullptr, ca_ln_w, ca_ln_b, 1e-6f);
    gemm_kernel<<<dim3(1024/64, M/64), 256, 0, stream>>>(
        bufB, ca_qkv_w + (size_t)512*D_, ca_qkv_b + 512, nullptr, bufA, M, 1024, D_, 0);
    gemm_kernel<<<dim3(D_/64, 1), 256, 0, stream>>>(
        qn, ca_qkv_w, ca_qkv_b, nullptr, qsm, 64, D_, D_, 0);
    patch_attn_kernel<<<B_*NPATCH_*H_/4, 256, 0, stream>>>(qsm, bufA, oca);
    gemm_kernel<<<dim3(D_/64, 1), 256, 0, stream>>>(
        oca, ca_out_w, ca_out_b, query, patches, 64, D_, D_, 0);

    // 4. final LayerNorms -> f32 outputs
    ln_kernel<<<M, 256, 0, stream>>>(out, x, nullptr, norm_w, norm_b, 1e-6f);
    ln_kernel<<<B_*NPATCH_, 256, 0, stream>>>(
        out + (size_t)M*D_, patches, nullptr, norm_w, norm_b, 1e-6f);
}

// Round 4
// 4214.779 us; speedup vs baseline: 2.6600x; 2.6600x over previous
//
#include <hip/hip_runtime.h>
#include <hip/hip_bf16.h>

#define B_ 4
#define S_ 2048
#define D_ 512
#define H_ 8
#define HD_ 64
#define L_ 2
#define V_ 30000
#define NPATCH_ 16
#define PLEN_ 128

// ---------------- embed + n-gram hash add ----------------
__global__ __launch_bounds__(128) void embed_ngram_kernel(
    const int* __restrict__ bytes, const float* __restrict__ byte_emb,
    const float* __restrict__ ng_emb, float* __restrict__ x)
{
    const int bs = blockIdx.x;          // b*S + s
    const int s  = bs % S_;
    const int b  = bs / S_;
    const int d  = threadIdx.x * 4;     // 128 threads * 4 floats = 512
    const int* brow = bytes + (size_t)b * S_;

    const int c = brow[s];
    float4 v = *reinterpret_cast<const float4*>(byte_emb + (size_t)c * D_ + d);

    // n=3: 31^2,31,1 ; n=4: 31^3=29791,... ; n=5: 31^4 mod 30000 = 23521,...
    if (s >= 2) {
        int h = (brow[s-2]*961 + brow[s-1]*31 + brow[s]) % V_;
        const float4 g = *reinterpret_cast<const float4*>(ng_emb + ((size_t)0*V_ + h)*D_ + d);
        v.x += 0.25f*g.x; v.y += 0.25f*g.y; v.z += 0.25f*g.z; v.w += 0.25f*g.w;
    }
    if (s >= 3) {
        int h = (brow[s-3]*29791 + brow[s-2]*961 + brow[s-1]*31 + brow[s]) % V_;
        const float4 g = *reinterpret_cast<const float4*>(ng_emb + ((size_t)1*V_ + h)*D_ + d);
        v.x += 0.25f*g.x; v.y += 0.25f*g.y; v.z += 0.25f*g.z; v.w += 0.25f*g.w;
    }
    if (s >= 4) {
        int h = (brow[s-4]*23521 + brow[s-3]*29791 + brow[s-2]*961 + brow[s-1]*31 + brow[s]) % V_;
        const float4 g = *reinterpret_cast<const float4*>(ng_emb + ((size_t)2*V_ + h)*D_ + d);
        v.x += 0.25f*g.x; v.y += 0.25f*g.y; v.z += 0.25f*g.z; v.w += 0.25f*g.w;
    }
    *reinterpret_cast<float4*>(x + (size_t)bs * D_ + d) = v;
}

// ---------------- GEMM: Y = X @ W^T + bias [,relu][,+resid] ----------------
__global__ __launch_bounds__(256) void gemm_kernel(
    const float* __restrict__ X, const float* __restrict__ W,
    const float* __restrict__ bias, const float* __restrict__ resid,
    float* __restrict__ Y, int M, int N, int K, int do_relu)
{
    __shared__ float As[16][68];
    __shared__ float Bs[16][68];
    const int tid = threadIdx.x;
    const int bm = blockIdx.y * 64, bn = blockIdx.x * 64;
    const int ty = tid >> 4, tx = tid & 15;
    const int lrow = tid >> 2, lc4 = (tid & 3) * 4;

    float acc[4][4];
#pragma unroll
    for (int i = 0; i < 4; ++i)
#pragma unroll
        for (int j = 0; j < 4; ++j) acc[i][j] = 0.f;

    for (int k0 = 0; k0 < K; k0 += 16) {
        const float4 xv = *reinterpret_cast<const float4*>(X + (size_t)(bm + lrow) * K + k0 + lc4);
        const float4 wv = *reinterpret_cast<const float4*>(W + (size_t)(bn + lrow) * K + k0 + lc4);
        __syncthreads();
        As[lc4+0][lrow] = xv.x; As[lc4+1][lrow] = xv.y;
        As[lc4+2][lrow] = xv.z; As[lc4+3][lrow] = xv.w;
        Bs[lc4+0][lrow] = wv.x; Bs[lc4+1][lrow] = wv.y;
        Bs[lc4+2][lrow] = wv.z; Bs[lc4+3][lrow] = wv.w;
        __syncthreads();
#pragma unroll
        for (int kk = 0; kk < 16; ++kk) {
            float a0 = As[kk][ty*4+0], a1 = As[kk][ty*4+1], a2 = As[kk][ty*4+2], a3 = As[kk][ty*4+3];
            float b0 = Bs[kk][tx*4+0], b1 = Bs[kk][tx*4+1], b2 = Bs[kk][tx*4+2], b3 = Bs[kk][tx*4+3];
            acc[0][0] += a0*b0; acc[0][1] += a0*b1; acc[0][2] += a0*b2; acc[0][3] += a0*b3;
            acc[1][0] += a1*b0; acc[1][1] += a1*b1; acc[1][2] += a1*b2; acc[1][3] += a1*b3;
            acc[2][0] += a2*b0; acc[2][1] += a2*b1; acc[2][2] += a2*b2; acc[2][3] += a2*b3;
            acc[3][0] += a3*b0; acc[3][1] += a3*b1; acc[3][2] += a3*b2; acc[3][3] += a3*b3;
        }
    }

#pragma unroll
    for (int i = 0; i < 4; ++i) {
        const int m = bm + ty*4 + i;
#pragma unroll
        for (int j = 0; j < 4; ++j) {
            const int n = bn + tx*4 + j;
            float v = acc[i][j] + bias[n];
            if (do_relu) v = fmaxf(v, 0.f);
            if (resid) v += resid[(size_t)m * N + n];
            Y[(size_t)m * N + n] = v;
        }
    }
}

// ---------------- causal flash attention, LDS-tiled, f32 -------------------
// Block: 4 waves = 32 q-rows of one (b,h). K/V tiles of 64 rows in LDS.
// Phase A: lane = k-in-tile (64 scores per q-row in parallel).
// Phase B: lane = d (P broadcast from LDS, wave-private).
// K/V LDS layout: [64][68] with 4-float chunk index XOR-swizzled by (row>>3)
// so phase-A per-lane-row ds_read_b128 is bandwidth-bound, not 8-way-conflicted.
__global__ __launch_bounds__(256) void attn_kernel(
    const float* __restrict__ qkv, float* __restrict__ o)
{
    __shared__ float Ks[64*68];
    __shared__ float Vs[64*68];
    __shared__ float Qs[32*68];
    __shared__ float Ps[4*8*68];

    const int t    = threadIdx.x;
    const int lane = t & 63;
    const int w    = t >> 6;          // wave 0..3
    const int qb   = blockIdx.x;      // 0..63
    const int bh   = blockIdx.y;      // 0..31
    const int h    = bh & 7;
    const int b    = bh >> 3;
    const int q0   = qb * 32;

    const float* base = qkv + (size_t)b * S_ * 1536;
    const int koff = 512 + h * 64;
    const int voff = 1024 + h * 64;

    // stage Q tile (rows q0..q0+31) into Qs[32][68] (unswizzled; broadcast reads)
    if (t < 128) {
        const int jr = t >> 2;                 // 0..31
        const int d0 = (t & 3) * 16;
        const float* src = base + (size_t)(q0 + jr) * 1536 + h * 64 + d0;
        float* dst = Qs + jr * 68 + d0;
        *reinterpret_cast<float4*>(dst)      = *reinterpret_cast<const float4*>(src);
        *reinterpret_cast<float4*>(dst + 4)  = *reinterpret_cast<const float4*>(src + 4);
        *reinterpret_cast<float4*>(dst + 8)  = *reinterpret_cast<const float4*>(src + 8);
        *reinterpret_cast<float4*>(dst + 12) = *reinterpret_cast<const float4*>(src + 12);
    }

    float s[8], oacc[8], mrow[8], lrow[8], alpha[8];
#pragma unroll
    for (int r = 0; r < 8; ++r) { oacc[r]=0.f; mrow[r]=-INFINITY; lrow[r]=0.f; }

    const int ntiles = q0 / 64 + 1;
    const int jrow  = t >> 2;          // staging row 0..63
    const int cbase = (t & 3) * 4;     // staging chunk base (of 16 chunks)

    for (int tile = 0; tile < ntiles; ++tile) {
        const int kt = tile * 64;
        __syncthreads();               // previous tile fully consumed
        // ---- stage K,V tile (chunk-swizzled) ----
        {
            const float* srcK = base + (size_t)(kt + jrow) * 1536 + koff;
            const float* srcV = base + (size_t)(kt + jrow) * 1536 + voff;
            const int sw = jrow >> 3;
#pragma unroll
            for (int i = 0; i < 4; ++i) {
                const int c  = cbase + i;
                const int cs = c ^ sw;
                const float4 kv = *reinterpret_cast<const float4*>(srcK + 4*c);
                const float4 vv = *reinterpret_cast<const float4*>(srcV + 4*c);
                *reinterpret_cast<float4*>(Ks + jrow*68 + 4*cs) = kv;
                *reinterpret_cast<float4*>(Vs + jrow*68 + 4*cs) = vv;
            }
        }
        __syncthreads();

        // ---- phase A: scores, lane = k ----
#pragma unroll
        for (int r = 0; r < 8; ++r) s[r] = 0.f;
        const int ksw = lane >> 3;
        const float* qsbase = Qs + (w * 8) * 68;
#pragma unroll
        for (int c = 0; c < 16; ++c) {
            const float4 kf = *reinterpret_cast<const float4*>(Ks + lane*68 + 4*(c ^ ksw));
#pragma unroll
            for (int r = 0; r < 8; ++r) {
                const float4 qf = *reinterpret_cast<const float4*>(qsbase + r*68 + 4*c);
                s[r] += qf.x*kf.x + qf.y*kf.y + qf.z*kf.z + qf.w*kf.w;
            }
        }

        // ---- mask + online softmax (per q-row, reduce over 64 k-lanes) ----
        const int kv_g = kt + lane;
#pragma unroll
        for (int r = 0; r < 8; ++r) {
            const int qrow = q0 + w*8 + r;
            const float sv = (kv_g <= qrow) ? s[r] * 0.125f : -INFINITY;
            float tm = sv;
#pragma unroll
            for (int off = 32; off; off >>= 1) tm = fmaxf(tm, __shfl_xor(tm, off, 64));
            const float nm = fmaxf(mrow[r], tm);
            const float al = __expf(mrow[r] - nm);   // first tile: exp(-inf)=0
            const float p  = __expf(sv - nm);        // masked lanes: exp(-inf)=0
            float ps = p;
#pragma unroll
            for (int off = 32; off; off >>= 1) ps += __shfl_xor(ps, off, 64);
            lrow[r]  = lrow[r]*al + ps;
            mrow[r]  = nm;
            alpha[r] = al;
            Ps[(w*8 + r)*68 + lane] = p;             // wave-private, no barrier
        }

        // ---- phase B: PV, lane = d ----
#pragma unroll
        for (int r = 0; r < 8; ++r) oacc[r] *= alpha[r];
        const float* psbase = Ps + (w*8)*68;
        const int dsw4 = (lane >> 2);
        const int dlo  = (lane & 3);
#pragma unroll
        for (int c = 0; c < 16; ++c) {
            const int k0 = 4*c;
            const float va = Vs[(k0+0)*68 + 4*(dsw4 ^ ((k0+0)>>3)) + dlo];
            const float vb = Vs[(k0+1)*68 + 4*(dsw4 ^ ((k0+1)>>3)) + dlo];
            const float vc = Vs[(k0+2)*68 + 4*(dsw4 ^ ((k0+2)>>3)) + dlo];
            const float vd = Vs[(k0+3)*68 + 4*(dsw4 ^ ((k0+3)>>3)) + dlo];
#pragma unroll
            for (int r = 0; r < 8; ++r) {
                const float4 pf = *reinterpret_cast<const float4*>(psbase + r*68 + k0);
                oacc[r] += pf.x*va + pf.y*vb + pf.z*vc + pf.w*vd;
            }
        }
    }

    // ---- epilogue ----
#pragma unroll
    for (int r = 0; r < 8; ++r) {
        const int qrow = q0 + w*8 + r;
        o[((size_t)b*S_ + qrow)*D_ + h*64 + lane] = oacc[r] / lrow[r];
    }
}

// ---------------- LayerNorm (optional residual add) ----------------
__global__ __launch_bounds__(256) void ln_kernel(
    float* __restrict__ dst, const float* __restrict__ src, const float* __restrict__ add,
    const float* __restrict__ w, const float* __restrict__ b, float eps)
{
    const int row = blockIdx.x, tid = threadIdx.x;
    const int lane = tid & 63, wave = tid >> 6;
    float2 v = *reinterpret_cast<const float2*>(src + (size_t)row * D_ + tid*2);
    if (add) {
        float2 a = *reinterpret_cast<const float2*>(add + (size_t)row * D_ + tid*2);
        v.x += a.x; v.y += a.y;
    }
    __shared__ float red[8];
    float s = v.x + v.y;
#pragma unroll
    for (int off = 32; off; off >>= 1) s += __shfl_xor(s, off, 64);
    if (lane == 0) red[wave] = s;
    __syncthreads();
    const float mean = (red[0]+red[1]+red[2]+red[3]) * (1.f/D_);
    const float d0 = v.x - mean, d1 = v.y - mean;
    float sq = d0*d0 + d1*d1;
#pragma unroll
    for (int off = 32; off; off >>= 1) sq += __shfl_xor(sq, off, 64);
    if (lane == 0) red[4+wave] = sq;
    __syncthreads();
    const float var = (red[4]+red[5]+red[6]+red[7]) * (1.f/D_);
    const float inv = rsqrtf(var + eps);
    *reinterpret_cast<float2*>(dst + (size_t)row * D_ + tid*2) =
        make_float2(d0*inv*w[tid*2] + b[tid*2], d1*inv*w[tid*2+1] + b[tid*2+1]);
}

// ---------------- patch mean-pool ----------------
__global__ __launch_bounds__(256) void meanpool_kernel(
    const float* __restrict__ x, float* __restrict__ query)
{
    const int bp = blockIdx.x;           // 0..63
    const int d = threadIdx.x * 2;
    const float* base = x + (size_t)bp * PLEN_ * D_ + d;
    float s0 = 0.f, s1 = 0.f;
    for (int l = 0; l < PLEN_; ++l) {
        float2 v = *reinterpret_cast<const float2*>(base + (size_t)l * D_);
        s0 += v.x; s1 += v.y;
    }
    query[(size_t)bp*D_ + d]     = s0 * (1.f/PLEN_);
    query[(size_t)bp*D_ + d + 1] = s1 * (1.f/PLEN_);
}

// ---------------- patch cross-attention, one wave per (b,p,h) -------------
__global__ __launch_bounds__(256) void patch_attn_kernel(
    const float* __restrict__ qbuf, const float* __restrict__ kv,
    float* __restrict__ o)
{
    const int wid  = blockIdx.x * 4 + (threadIdx.x >> 6);  // 0..511
    const int lane = threadIdx.x & 63;
    const int h  = wid % H_;
    const int bp = wid / H_;      // 0..63
    const float qv = qbuf[(size_t)bp*D_ + h*HD_ + lane] * 0.125f;
    const float* base = kv + (size_t)bp * PLEN_ * 1024 + h*HD_;

    float m = -INFINITY, l = 0.f, acc = 0.f;
    for (int t = 0; t < PLEN_; ++t) {
        const float* row = base + (size_t)t * 1024;
        float s = qv * row[lane];
#pragma unroll
        for (int off = 32; off; off >>= 1) s += __shfl_xor(s, off, 64);
        const float vv = row[512 + lane];
        const float nm = fmaxf(m, s);
        const float al = __expf(m - nm);
        const float p  = __expf(s - nm);
        l = l * al + p;
        acc = acc * al + p * vv;
        m = nm;
    }
    o[(size_t)bp*D_ + h*HD_ + lane] = acc / l;
}

extern "C" void kernel_launch(void* const* d_in, const int* in_sizes, int n_in,
                              void* d_out, int out_size, void* d_ws, size_t ws_size,
                              hipStream_t stream)
{
    const int*   byte_seq = (const int*)d_in[0];
    const float* byte_emb = (const float*)d_in[2];
    const float* ng_emb   = (const float*)d_in[3];
    const float* qkv_w = (const float*)d_in[4];
    const float* qkv_b = (const float*)d_in[5];
    const float* out_w = (const float*)d_in[6];
    const float* out_b = (const float*)d_in[7];
    const float* ln1_w = (const float*)d_in[8];
    const float* ln1_b = (const float*)d_in[9];
    const float* ln2_w = (const float*)d_in[10];
    const float* ln2_b = (const float*)d_in[11];
    const float* ff1_w = (const float*)d_in[12];
    const float* ff1_b = (const float*)d_in[13];
    const float* ff2_w = (const float*)d_in[14];
    const float* ff2_b = (const float*)d_in[15];
    const float* ca_qkv_w = (const float*)d_in[16];
    const float* ca_qkv_b = (const float*)d_in[17];
    const float* ca_out_w = (const float*)d_in[18];
    const float* ca_out_b = (const float*)d_in[19];
    const float* ca_ln_w  = (const float*)d_in[20];
    const float* ca_ln_b  = (const float*)d_in[21];
    const float* norm_w   = (const float*)d_in[22];
    const float* norm_b   = (const float*)d_in[23];
    float* out = (float*)d_out;

    char* ws = (char*)d_ws;
    float* x    = (float*)(ws);                                  // 8192x512   (16MB)
    float* bufA = (float*)(ws + (size_t)16*1024*1024);           // 8192x2048  (64MB)
    float* bufB = (float*)(ws + (size_t)80*1024*1024);           // 8192x512   (16MB)
    float* query   = (float*)(ws + (size_t)96*1024*1024);        // 64x512
    float* qn      = query + 64*512;
    float* qsm     = qn + 64*512;
    float* oca     = qsm + 64*512;
    float* patches = oca + 64*512;

    const int M = B_ * S_;   // 8192

    // 1. byte embedding + n-gram hash adds
    embed_ngram_kernel<<<M, 128, 0, stream>>>(byte_seq, byte_emb, ng_emb, x);

    // 2. transformer layers
    for (int l = 0; l < L_; ++l) {
        gemm_kernel<<<dim3(1536/64, M/64), 256, 0, stream>>>(
            x, qkv_w + (size_t)l*1536*D_, qkv_b + l*1536, nullptr, bufA, M, 1536, D_, 0);
        attn_kernel<<<dim3(S_/32, B_*H_), 256, 0, stream>>>(bufA, bufB);
        gemm_kernel<<<dim3(D_/64, M/64), 256, 0, stream>>>(
            bufB, out_w + (size_t)l*D_*D_, out_b + l*D_, nullptr, bufA, M, D_, D_, 0);
        ln_kernel<<<M, 256, 0, stream>>>(x, x, bufA, ln1_w + l*D_, ln1_b + l*D_, 1e-5f);
        gemm_kernel<<<dim3(2048/64, M/64), 256, 0, stream>>>(
            x, ff1_w + (size_t)l*2048*D_, ff1_b + l*2048, nullptr, bufA, M, 2048, D_, 1);
        gemm_kernel<<<dim3(D_/64, M/64), 256, 0, stream>>>(
            bufA, ff2_w + (size_t)l*D_*2048, ff2_b + l*D_, nullptr, bufB, M, D_, 2048, 0);
        ln_kernel<<<M, 256, 0, stream>>>(x, x, bufB, ln2_w + l*D_, ln2_b + l*D_, 1e-5f);
    }

    // 3. patch cross-attention
    meanpool_kernel<<<B_*NPATCH_, 256, 0, stream>>>(x, query);
    ln_kernel<<<B_*NPATCH_, 256, 0, stream>>>(qn, query, nullptr, ca_ln_w, ca_ln_b, 1e-6f);
    ln_kernel<<<M, 256, 0, stream>>>(bufB, x, nullptr, ca_ln_w, ca_ln_b, 1e-6f);
    gemm_kernel<<<dim3(1024/64, M/64), 256, 0, stream>>>(
        bufB, ca_qkv_w + (size_t)512*D_, ca_qkv_b + 512, nullptr, bufA, M, 1024, D_, 0);
    gemm_kernel<<<dim3(D_/64, 1), 256, 0, stream>>>(
        qn, ca_qkv_w, ca_qkv_b, nullptr, qsm, 64, D_, D_, 0);
    patch_attn_kernel<<<B_*NPATCH_*H_/4, 256, 0, stream>>>(qsm, bufA, oca);
    gemm_kernel<<<dim3(D_/64, 1), 256, 0, stream>>>(
        oca, ca_out_w, ca_out_b, query, patches, 64, D_, D_, 0);

    // 4. final LayerNorms -> f32 outputs
    ln_kernel<<<M, 256, 0, stream>>>(out, x, nullptr, norm_w, norm_b, 1e-6f);
    ln_kernel<<<B_*NPATCH_, 256, 0, stream>>>(
        out + (size_t)M*D_, patches, nullptr, norm_w, norm_b, 1e-6f);
}

// Round 5
// 2027.079 us; speedup vs baseline: 5.5307x; 2.0792x over previous
//
#include <hip/hip_runtime.h>
#include <hip/hip_bf16.h>

#define B_ 4
#define S_ 2048
#define D_ 512
#define H_ 8
#define HD_ 64
#define L_ 2
#define V_ 30000
#define NPATCH_ 16
#define PLEN_ 128

typedef short bf16x8 __attribute__((ext_vector_type(8)));
typedef float f32x4 __attribute__((ext_vector_type(4)));

__device__ __forceinline__ unsigned short f2bf(float f) {
    unsigned u = __float_as_uint(f);
    return (unsigned short)((u + 0x7FFFu + ((u >> 16) & 1u)) >> 16);   // RNE
}

// ---------------- embed + n-gram hash add ----------------
__global__ __launch_bounds__(128) void embed_ngram_kernel(
    const int* __restrict__ bytes, const float* __restrict__ byte_emb,
    const float* __restrict__ ng_emb, float* __restrict__ x)
{
    const int bs = blockIdx.x;          // b*S + s
    const int s  = bs % S_;
    const int b  = bs / S_;
    const int d  = threadIdx.x * 4;
    const int* brow = bytes + (size_t)b * S_;

    const int c = brow[s];
    float4 v = *reinterpret_cast<const float4*>(byte_emb + (size_t)c * D_ + d);

    if (s >= 2) {
        int h = (brow[s-2]*961 + brow[s-1]*31 + brow[s]) % V_;
        const float4 g = *reinterpret_cast<const float4*>(ng_emb + ((size_t)0*V_ + h)*D_ + d);
        v.x += 0.25f*g.x; v.y += 0.25f*g.y; v.z += 0.25f*g.z; v.w += 0.25f*g.w;
    }
    if (s >= 3) {
        int h = (brow[s-3]*29791 + brow[s-2]*961 + brow[s-1]*31 + brow[s]) % V_;
        const float4 g = *reinterpret_cast<const float4*>(ng_emb + ((size_t)1*V_ + h)*D_ + d);
        v.x += 0.25f*g.x; v.y += 0.25f*g.y; v.z += 0.25f*g.z; v.w += 0.25f*g.w;
    }
    if (s >= 4) {
        int h = (brow[s-4]*23521 + brow[s-3]*29791 + brow[s-2]*961 + brow[s-1]*31 + brow[s]) % V_;
        const float4 g = *reinterpret_cast<const float4*>(ng_emb + ((size_t)2*V_ + h)*D_ + d);
        v.x += 0.25f*g.x; v.y += 0.25f*g.y; v.z += 0.25f*g.z; v.w += 0.25f*g.w;
    }
    *reinterpret_cast<float4*>(x + (size_t)bs * D_ + d) = v;
}

// ---------------- GEMM: Y = X @ W^T + bias [,relu][,+resid] ----------------
// BF16OUT: write bf16 bits (for attention input) instead of f32.
template<bool BF16OUT>
__global__ __launch_bounds__(256) void gemm_kernel(
    const float* __restrict__ X, const float* __restrict__ W,
    const float* __restrict__ bias, const float* __restrict__ resid,
    void* __restrict__ Yout, int M, int N, int K, int do_relu)
{
    __shared__ float As[16][68];
    __shared__ float Bs[16][68];
    const int tid = threadIdx.x;
    const int bm = blockIdx.y * 64, bn = blockIdx.x * 64;
    const int ty = tid >> 4, tx = tid & 15;
    const int lrow = tid >> 2, lc4 = (tid & 3) * 4;

    float acc[4][4];
#pragma unroll
    for (int i = 0; i < 4; ++i)
#pragma unroll
        for (int j = 0; j < 4; ++j) acc[i][j] = 0.f;

    for (int k0 = 0; k0 < K; k0 += 16) {
        const float4 xv = *reinterpret_cast<const float4*>(X + (size_t)(bm + lrow) * K + k0 + lc4);
        const float4 wv = *reinterpret_cast<const float4*>(W + (size_t)(bn + lrow) * K + k0 + lc4);
        __syncthreads();
        As[lc4+0][lrow] = xv.x; As[lc4+1][lrow] = xv.y;
        As[lc4+2][lrow] = xv.z; As[lc4+3][lrow] = xv.w;
        Bs[lc4+0][lrow] = wv.x; Bs[lc4+1][lrow] = wv.y;
        Bs[lc4+2][lrow] = wv.z; Bs[lc4+3][lrow] = wv.w;
        __syncthreads();
#pragma unroll
        for (int kk = 0; kk < 16; ++kk) {
            float a0 = As[kk][ty*4+0], a1 = As[kk][ty*4+1], a2 = As[kk][ty*4+2], a3 = As[kk][ty*4+3];
            float b0 = Bs[kk][tx*4+0], b1 = Bs[kk][tx*4+1], b2 = Bs[kk][tx*4+2], b3 = Bs[kk][tx*4+3];
            acc[0][0] += a0*b0; acc[0][1] += a0*b1; acc[0][2] += a0*b2; acc[0][3] += a0*b3;
            acc[1][0] += a1*b0; acc[1][1] += a1*b1; acc[1][2] += a1*b2; acc[1][3] += a1*b3;
            acc[2][0] += a2*b0; acc[2][1] += a2*b1; acc[2][2] += a2*b2; acc[2][3] += a2*b3;
            acc[3][0] += a3*b0; acc[3][1] += a3*b1; acc[3][2] += a3*b2; acc[3][3] += a3*b3;
        }
    }

#pragma unroll
    for (int i = 0; i < 4; ++i) {
        const int m = bm + ty*4 + i;
#pragma unroll
        for (int j = 0; j < 4; ++j) {
            const int n = bn + tx*4 + j;
            float v = acc[i][j] + bias[n];
            if (do_relu) v = fmaxf(v, 0.f);
            if (resid) v += resid[(size_t)m * N + n];
            if constexpr (BF16OUT)
                ((unsigned short*)Yout)[(size_t)m * N + n] = f2bf(v);
            else
                ((float*)Yout)[(size_t)m * N + n] = v;
        }
    }
}

// ---------------- MFMA bf16 causal flash attention ------------------------
// qkvb: bf16 bits [B,S,1536] rows [q|k|v]. o: f32 [B,S,512].
// Block: 4 waves; wave w owns q-rows q0B+w*16..+15. KV tiles of 64 keys.
// mfma_f32_16x16x32_bf16: A/B frag: lane holds row l&15, k=(l>>4)*8+i.
//                         C/D: col = l&15, row = 4*(l>>4)+reg.
__global__ __launch_bounds__(256) void attn_mfma_kernel(
    const unsigned short* __restrict__ qkvb, float* __restrict__ o)
{
    __shared__ unsigned short Ks[64*72];     // [key][d]  stride 72
    __shared__ unsigned short Vt[64*72];     // [d][key]  stride 72 (transposed!)
    __shared__ unsigned short Plds[4*16*72]; // per-wave [16 q][64 key]

    const int t    = threadIdx.x;
    const int lane = t & 63;
    const int w    = t >> 6;
    const int qb   = blockIdx.x;          // 0..31
    const int bh   = blockIdx.y;          // 0..31
    const int h    = bh & 7;
    const int b    = bh >> 3;
    const int q0B  = qb * 64;
    const int q0w  = q0B + w * 16;

    const unsigned short* base = qkvb + (size_t)b * S_ * 1536;
    const int l15 = lane & 15, lg = lane >> 4;

    // Q fragments (held in registers for the whole kernel)
    bf16x8 qf0, qf1;
    {
        const unsigned short* qr = base + (size_t)(q0w + l15) * 1536 + h*64 + lg*8;
        qf0 = *reinterpret_cast<const bf16x8*>(qr);
        qf1 = *reinterpret_cast<const bf16x8*>(qr + 32);
    }

    f32x4 oacc[4];
#pragma unroll
    for (int i = 0; i < 4; ++i) oacc[i] = (f32x4){0.f,0.f,0.f,0.f};
    float mrow[4] = {-INFINITY,-INFINITY,-INFINITY,-INFINITY};
    float lrow[4] = {0.f,0.f,0.f,0.f};

    const int ntiles = qb + 1;
    const int skey = t >> 2, sd0 = (t & 3) * 16;   // staging assignment
    unsigned short* pw_base = Plds + w*16*72;

    for (int tile = 0; tile < ntiles; ++tile) {
        const int kt = tile * 64;
        __syncthreads();
        // ---- stage K [key][d] and V^T [d][key] (bf16) ----
        {
            const unsigned short* srcK = base + (size_t)(kt + skey) * 1536 + 512  + h*64 + sd0;
            const unsigned short* srcV = base + (size_t)(kt + skey) * 1536 + 1024 + h*64 + sd0;
            *reinterpret_cast<bf16x8*>(&Ks[skey*72 + sd0])     = *reinterpret_cast<const bf16x8*>(srcK);
            *reinterpret_cast<bf16x8*>(&Ks[skey*72 + sd0 + 8]) = *reinterpret_cast<const bf16x8*>(srcK + 8);
            bf16x8 v0 = *reinterpret_cast<const bf16x8*>(srcV);
            bf16x8 v1 = *reinterpret_cast<const bf16x8*>(srcV + 8);
#pragma unroll
            for (int j = 0; j < 8; ++j) Vt[(sd0+j)*72 + skey]   = (unsigned short)v0[j];
#pragma unroll
            for (int j = 0; j < 8; ++j) Vt[(sd0+8+j)*72 + skey] = (unsigned short)v1[j];
        }
        __syncthreads();

        // ---- QK^T: S[16q x 64key] in 4 acc tiles ----
        f32x4 sacc[4];
#pragma unroll
        for (int kt16 = 0; kt16 < 4; ++kt16) {
            sacc[kt16] = (f32x4){0.f,0.f,0.f,0.f};
            const unsigned short* kp = &Ks[(kt16*16 + l15)*72 + lg*8];
            bf16x8 k0 = *reinterpret_cast<const bf16x8*>(kp);
            bf16x8 k1 = *reinterpret_cast<const bf16x8*>(kp + 32);
            sacc[kt16] = __builtin_amdgcn_mfma_f32_16x16x32_bf16(qf0, k0, sacc[kt16], 0, 0, 0);
            sacc[kt16] = __builtin_amdgcn_mfma_f32_16x16x32_bf16(qf1, k1, sacc[kt16], 0, 0, 0);
        }

        // ---- scale + causal mask + online softmax ----
        const bool diag = (tile == ntiles - 1);
        float sv[4][4];   // [key-subtile][reg]
#pragma unroll
        for (int kt16 = 0; kt16 < 4; ++kt16) {
#pragma unroll
            for (int r = 0; r < 4; ++r) {
                float s = sacc[kt16][r] * 0.125f;
                if (diag) {
                    const int key = kt + kt16*16 + l15;
                    const int q   = q0w + 4*lg + r;
                    if (key > q) s = -INFINITY;
                }
                sv[kt16][r] = s;
            }
        }
#pragma unroll
        for (int r = 0; r < 4; ++r) {
            float tm = fmaxf(fmaxf(sv[0][r], sv[1][r]), fmaxf(sv[2][r], sv[3][r]));
#pragma unroll
            for (int off = 8; off; off >>= 1) tm = fmaxf(tm, __shfl_xor(tm, off, 64));
            const float nm = fmaxf(mrow[r], tm);
            const float al = __expf(mrow[r] - nm);    // first tile: exp(-inf)=0
            mrow[r] = nm;
            float ps = 0.f;
#pragma unroll
            for (int kt16 = 0; kt16 < 4; ++kt16) {
                const float p = __expf(sv[kt16][r] - nm);
                ps += p;
                pw_base[(4*lg + r)*72 + kt16*16 + l15] = f2bf(p);
            }
#pragma unroll
            for (int off = 8; off; off >>= 1) ps += __shfl_xor(ps, off, 64);
            lrow[r] = lrow[r]*al + ps;
#pragma unroll
            for (int dt = 0; dt < 4; ++dt) oacc[dt][r] *= al;
        }

        // ---- PV: O[16q x 64d] += P @ V ----
        const unsigned short* pr = &pw_base[l15*72 + lg*8];
        bf16x8 pa0 = *reinterpret_cast<const bf16x8*>(pr);
        bf16x8 pa1 = *reinterpret_cast<const bf16x8*>(pr + 32);
#pragma unroll
        for (int dt = 0; dt < 4; ++dt) {
            const unsigned short* vp = &Vt[(dt*16 + l15)*72 + lg*8];
            bf16x8 v0 = *reinterpret_cast<const bf16x8*>(vp);
            bf16x8 v1 = *reinterpret_cast<const bf16x8*>(vp + 32);
            oacc[dt] = __builtin_amdgcn_mfma_f32_16x16x32_bf16(pa0, v0, oacc[dt], 0, 0, 0);
            oacc[dt] = __builtin_amdgcn_mfma_f32_16x16x32_bf16(pa1, v1, oacc[dt], 0, 0, 0);
        }
    }

    // ---- epilogue ----
#pragma unroll
    for (int dt = 0; dt < 4; ++dt) {
#pragma unroll
        for (int r = 0; r < 4; ++r) {
            const int q = q0w + 4*lg + r;
            o[((size_t)b*S_ + q)*D_ + h*64 + dt*16 + l15] = oacc[dt][r] / lrow[r];
        }
    }
}

// ---------------- LayerNorm (optional residual add) ----------------
__global__ __launch_bounds__(256) void ln_kernel(
    float* __restrict__ dst, const float* __restrict__ src, const float* __restrict__ add,
    const float* __restrict__ w, const float* __restrict__ b, float eps)
{
    const int row = blockIdx.x, tid = threadIdx.x;
    const int lane = tid & 63, wave = tid >> 6;
    float2 v = *reinterpret_cast<const float2*>(src + (size_t)row * D_ + tid*2);
    if (add) {
        float2 a = *reinterpret_cast<const float2*>(add + (size_t)row * D_ + tid*2);
        v.x += a.x; v.y += a.y;
    }
    __shared__ float red[8];
    float s = v.x + v.y;
#pragma unroll
    for (int off = 32; off; off >>= 1) s += __shfl_xor(s, off, 64);
    if (lane == 0) red[wave] = s;
    __syncthreads();
    const float mean = (red[0]+red[1]+red[2]+red[3]) * (1.f/D_);
    const float d0 = v.x - mean, d1 = v.y - mean;
    float sq = d0*d0 + d1*d1;
#pragma unroll
    for (int off = 32; off; off >>= 1) sq += __shfl_xor(sq, off, 64);
    if (lane == 0) red[4+wave] = sq;
    __syncthreads();
    const float var = (red[4]+red[5]+red[6]+red[7]) * (1.f/D_);
    const float inv = rsqrtf(var + eps);
    *reinterpret_cast<float2*>(dst + (size_t)row * D_ + tid*2) =
        make_float2(d0*inv*w[tid*2] + b[tid*2], d1*inv*w[tid*2+1] + b[tid*2+1]);
}

// ---------------- patch mean-pool ----------------
__global__ __launch_bounds__(256) void meanpool_kernel(
    const float* __restrict__ x, float* __restrict__ query)
{
    const int bp = blockIdx.x;
    const int d = threadIdx.x * 2;
    const float* base = x + (size_t)bp * PLEN_ * D_ + d;
    float s0 = 0.f, s1 = 0.f;
    for (int l = 0; l < PLEN_; ++l) {
        float2 v = *reinterpret_cast<const float2*>(base + (size_t)l * D_);
        s0 += v.x; s1 += v.y;
    }
    query[(size_t)bp*D_ + d]     = s0 * (1.f/PLEN_);
    query[(size_t)bp*D_ + d + 1] = s1 * (1.f/PLEN_);
}

// ---------------- patch cross-attention, one wave per (b,p,h) -------------
__global__ __launch_bounds__(256) void patch_attn_kernel(
    const float* __restrict__ qbuf, const float* __restrict__ kv,
    float* __restrict__ o)
{
    const int wid  = blockIdx.x * 4 + (threadIdx.x >> 6);
    const int lane = threadIdx.x & 63;
    const int h  = wid % H_;
    const int bp = wid / H_;
    const float qv = qbuf[(size_t)bp*D_ + h*HD_ + lane] * 0.125f;
    const float* base = kv + (size_t)bp * PLEN_ * 1024 + h*HD_;

    float m = -INFINITY, l = 0.f, acc = 0.f;
    for (int t = 0; t < PLEN_; ++t) {
        const float* row = base + (size_t)t * 1024;
        float s = qv * row[lane];
#pragma unroll
        for (int off = 32; off; off >>= 1) s += __shfl_xor(s, off, 64);
        const float vv = row[512 + lane];
        const float nm = fmaxf(m, s);
        const float al = __expf(m - nm);
        const float p  = __expf(s - nm);
        l = l * al + p;
        acc = acc * al + p * vv;
        m = nm;
    }
    o[(size_t)bp*D_ + h*HD_ + lane] = acc / l;
}

extern "C" void kernel_launch(void* const* d_in, const int* in_sizes, int n_in,
                              void* d_out, int out_size, void* d_ws, size_t ws_size,
                              hipStream_t stream)
{
    const int*   byte_seq = (const int*)d_in[0];
    const float* byte_emb = (const float*)d_in[2];
    const float* ng_emb   = (const float*)d_in[3];
    const float* qkv_w = (const float*)d_in[4];
    const float* qkv_b = (const float*)d_in[5];
    const float* out_w = (const float*)d_in[6];
    const float* out_b = (const float*)d_in[7];
    const float* ln1_w = (const float*)d_in[8];
    const float* ln1_b = (const float*)d_in[9];
    const float* ln2_w = (const float*)d_in[10];
    const float* ln2_b = (const float*)d_in[11];
    const float* ff1_w = (const float*)d_in[12];
    const float* ff1_b = (const float*)d_in[13];
    const float* ff2_w = (const float*)d_in[14];
    const float* ff2_b = (const float*)d_in[15];
    const float* ca_qkv_w = (const float*)d_in[16];
    const float* ca_qkv_b = (const float*)d_in[17];
    const float* ca_out_w = (const float*)d_in[18];
    const float* ca_out_b = (const float*)d_in[19];
    const float* ca_ln_w  = (const float*)d_in[20];
    const float* ca_ln_b  = (const float*)d_in[21];
    const float* norm_w   = (const float*)d_in[22];
    const float* norm_b   = (const float*)d_in[23];
    float* out = (float*)d_out;

    char* ws = (char*)d_ws;
    float* x    = (float*)(ws);                                  // 8192x512   (16MB)
    float* bufA = (float*)(ws + (size_t)16*1024*1024);           // 64MB scratch
    float* bufB = (float*)(ws + (size_t)80*1024*1024);           // 8192x512   (16MB)
    float* query   = (float*)(ws + (size_t)96*1024*1024);
    float* qn      = query + 64*512;
    float* qsm     = qn + 64*512;
    float* oca     = qsm + 64*512;
    float* patches = oca + 64*512;

    unsigned short* qkvb = (unsigned short*)bufA;   // bf16 [8192][1536] (25MB of 64MB)

    const int M = B_ * S_;   // 8192

    // 1. byte embedding + n-gram hash adds
    embed_ngram_kernel<<<M, 128, 0, stream>>>(byte_seq, byte_emb, ng_emb, x);

    // 2. transformer layers
    for (int l = 0; l < L_; ++l) {
        // qkv = x @ Wqkv^T + b  -> bf16 in bufA
        gemm_kernel<true><<<dim3(1536/64, M/64), 256, 0, stream>>>(
            x, qkv_w + (size_t)l*1536*D_, qkv_b + l*1536, nullptr, qkvb, M, 1536, D_, 0);
        // causal MFMA flash attention -> bufB (f32)
        attn_mfma_kernel<<<dim3(S_/64, B_*H_), 256, 0, stream>>>(qkvb, bufB);
        // proj -> bufA (f32, overwrites qkvb which is now dead)
        gemm_kernel<false><<<dim3(D_/64, M/64), 256, 0, stream>>>(
            bufB, out_w + (size_t)l*D_*D_, out_b + l*D_, nullptr, bufA, M, D_, D_, 0);
        ln_kernel<<<M, 256, 0, stream>>>(x, x, bufA, ln1_w + l*D_, ln1_b + l*D_, 1e-5f);
        gemm_kernel<false><<<dim3(2048/64, M/64), 256, 0, stream>>>(
            x, ff1_w + (size_t)l*2048*D_, ff1_b + l*2048, nullptr, bufA, M, 2048, D_, 1);
        gemm_kernel<false><<<dim3(D_/64, M/64), 256, 0, stream>>>(
            bufA, ff2_w + (size_t)l*D_*2048, ff2_b + l*D_, nullptr, bufB, M, D_, 2048, 0);
        ln_kernel<<<M, 256, 0, stream>>>(x, x, bufB, ln2_w + l*D_, ln2_b + l*D_, 1e-5f);
    }

    // 3. patch cross-attention
    meanpool_kernel<<<B_*NPATCH_, 256, 0, stream>>>(x, query);
    ln_kernel<<<B_*NPATCH_, 256, 0, stream>>>(qn, query, nullptr, ca_ln_w, ca_ln_b, 1e-6f);
    ln_kernel<<<M, 256, 0, stream>>>(bufB, x, nullptr, ca_ln_w, ca_ln_b, 1e-6f);
    gemm_kernel<false><<<dim3(1024/64, M/64), 256, 0, stream>>>(
        bufB, ca_qkv_w + (size_t)512*D_, ca_qkv_b + 512, nullptr, bufA, M, 1024, D_, 0);
    gemm_kernel<false><<<dim3(D_/64, 1), 256, 0, stream>>>(
        qn, ca_qkv_w, ca_qkv_b, nullptr, qsm, 64, D_, D_, 0);
    patch_attn_kernel<<<B_*NPATCH_*H_/4, 256, 0, stream>>>(qsm, bufA, oca);
    gemm_kernel<false><<<dim3(D_/64, 1), 256, 0, stream>>>(
        oca, ca_out_w, ca_out_b, query, patches, 64, D_, D_, 0);

    // 4. final LayerNorms -> f32 outputs
    ln_kernel<<<M, 256, 0, stream>>>(out, x, nullptr, norm_w, norm_b, 1e-6f);
    ln_kernel<<<B_*NPATCH_, 256, 0, stream>>>(
        out + (size_t)M*D_, patches, nullptr, norm_w, norm_b, 1e-6f);
}

// Round 6
// 757.399 us; speedup vs baseline: 14.8022x; 2.6764x over previous
//
#include <hip/hip_runtime.h>
#include <hip/hip_bf16.h>

#define B_ 4
#define S_ 2048
#define D_ 512
#define H_ 8
#define HD_ 64
#define L_ 2
#define V_ 30000
#define NPATCH_ 16
#define PLEN_ 128

typedef short bf16x8 __attribute__((ext_vector_type(8)));
typedef float f32x4 __attribute__((ext_vector_type(4)));

__device__ __forceinline__ unsigned short f2bf(float f) {
    unsigned u = __float_as_uint(f);
    return (unsigned short)((u + 0x7FFFu + ((u >> 16) & 1u)) >> 16);   // RNE
}

// ---------------- f32 -> bf16 cast (weights) ----------------
__global__ __launch_bounds__(256) void cast_kernel(
    const float* __restrict__ src, unsigned short* __restrict__ dst, int n4)
{
    const int i = blockIdx.x * 256 + threadIdx.x;
    if (i >= n4) return;
    const float4 v = *reinterpret_cast<const float4*>(src + (size_t)i * 4);
    ushort4 o;
    o.x = f2bf(v.x); o.y = f2bf(v.y); o.z = f2bf(v.z); o.w = f2bf(v.w);
    *reinterpret_cast<ushort4*>(dst + (size_t)i * 4) = o;
}

// ---------------- embed + n-gram hash add (f32 + bf16 shadow) -------------
__global__ __launch_bounds__(128) void embed_ngram_kernel(
    const int* __restrict__ bytes, const float* __restrict__ byte_emb,
    const float* __restrict__ ng_emb, float* __restrict__ x,
    unsigned short* __restrict__ xb)
{
    const int bs = blockIdx.x;
    const int s  = bs % S_;
    const int b  = bs / S_;
    const int d  = threadIdx.x * 4;
    const int* brow = bytes + (size_t)b * S_;

    const int c = brow[s];
    float4 v = *reinterpret_cast<const float4*>(byte_emb + (size_t)c * D_ + d);

    if (s >= 2) {
        int h = (brow[s-2]*961 + brow[s-1]*31 + brow[s]) % V_;
        const float4 g = *reinterpret_cast<const float4*>(ng_emb + ((size_t)0*V_ + h)*D_ + d);
        v.x += 0.25f*g.x; v.y += 0.25f*g.y; v.z += 0.25f*g.z; v.w += 0.25f*g.w;
    }
    if (s >= 3) {
        int h = (brow[s-3]*29791 + brow[s-2]*961 + brow[s-1]*31 + brow[s]) % V_;
        const float4 g = *reinterpret_cast<const float4*>(ng_emb + ((size_t)1*V_ + h)*D_ + d);
        v.x += 0.25f*g.x; v.y += 0.25f*g.y; v.z += 0.25f*g.z; v.w += 0.25f*g.w;
    }
    if (s >= 4) {
        int h = (brow[s-4]*23521 + brow[s-3]*29791 + brow[s-2]*961 + brow[s-1]*31 + brow[s]) % V_;
        const float4 g = *reinterpret_cast<const float4*>(ng_emb + ((size_t)2*V_ + h)*D_ + d);
        v.x += 0.25f*g.x; v.y += 0.25f*g.y; v.z += 0.25f*g.z; v.w += 0.25f*g.w;
    }
    *reinterpret_cast<float4*>(x + (size_t)bs * D_ + d) = v;
    ushort4 o;
    o.x = f2bf(v.x); o.y = f2bf(v.y); o.z = f2bf(v.z); o.w = f2bf(v.w);
    *reinterpret_cast<ushort4*>(xb + (size_t)bs * D_ + d) = o;
}

// ---------------- MFMA bf16 GEMM: Y = X @ W^T + bias [,relu] --------------
// Xb [M,K], Wb [N,K] bf16 row-major. 128x128 tile, BK=64, 4 waves (2x2),
// each wave a 64x64 quadrant = 4x4 mfma_16x16x32 tiles.
// LDS written linearly by global_load_lds; XOR swizzle (col16 ^= row&7)
// applied on the GLOBAL source and on the ds_read (rule: both-sides-or-neither).
template<int DO_RELU, int BF16OUT>
__global__ __launch_bounds__(256) void mgemm_kernel(
    const unsigned short* __restrict__ Xb, const unsigned short* __restrict__ Wb,
    const float* __restrict__ bias, void* __restrict__ Yout,
    int M, int N, int K)
{
    __shared__ unsigned short As[128*64];   // 16 KB, 128B rows
    __shared__ unsigned short Bs[128*64];

    const int t    = threadIdx.x;
    const int lane = t & 63;
    const int w    = t >> 6;
    const int bm   = blockIdx.y * 128, bn = blockIdx.x * 128;
    const int l15  = lane & 15, lg = lane >> 4;
    const int wr   = w >> 1, wc = w & 1;

    // staging map: LDS byte off = w*1024 + i*4096 + lane*16 (linear dest)
    int srow[4], scol[4];
#pragma unroll
    for (int i = 0; i < 4; ++i) {
        const int off = w*1024 + i*4096 + lane*16;
        srow[i] = off >> 7;                         // 0..127
        scol[i] = ((off >> 4) & 7) ^ (srow[i] & 7); // pre-swizzled source chunk
    }

    f32x4 acc[4][4];
#pragma unroll
    for (int mt = 0; mt < 4; ++mt)
#pragma unroll
        for (int nt = 0; nt < 4; ++nt) acc[mt][nt] = (f32x4){0.f,0.f,0.f,0.f};

    for (int kt = 0; kt < K; kt += 64) {
#pragma unroll
        for (int i = 0; i < 4; ++i) {
            const unsigned short* gA = Xb + (size_t)(bm + srow[i]) * K + kt + scol[i]*8;
            const unsigned short* gB = Wb + (size_t)(bn + srow[i]) * K + kt + scol[i]*8;
            __builtin_amdgcn_global_load_lds(
                (const __attribute__((address_space(1))) void*)gA,
                (__attribute__((address_space(3))) void*)&As[w*512 + i*2048], 16, 0, 0);
            __builtin_amdgcn_global_load_lds(
                (const __attribute__((address_space(1))) void*)gB,
                (__attribute__((address_space(3))) void*)&Bs[w*512 + i*2048], 16, 0, 0);
        }
        __syncthreads();   // compiler drains vmcnt before s_barrier

#pragma unroll
        for (int ks = 0; ks < 2; ++ks) {
            const int c16 = (ks*4 + lg) ^ (l15 & 7);   // swizzled read chunk
            bf16x8 a[4], b[4];
#pragma unroll
            for (int mt = 0; mt < 4; ++mt)
                a[mt] = *reinterpret_cast<const bf16x8*>(&As[(wr*64 + mt*16 + l15)*64 + c16*8]);
#pragma unroll
            for (int nt = 0; nt < 4; ++nt)
                b[nt] = *reinterpret_cast<const bf16x8*>(&Bs[(wc*64 + nt*16 + l15)*64 + c16*8]);
#pragma unroll
            for (int mt = 0; mt < 4; ++mt)
#pragma unroll
                for (int nt = 0; nt < 4; ++nt)
                    acc[mt][nt] = __builtin_amdgcn_mfma_f32_16x16x32_bf16(
                        a[mt], b[nt], acc[mt][nt], 0, 0, 0);
        }
        __syncthreads();
    }

    float bv[4];
#pragma unroll
    for (int nt = 0; nt < 4; ++nt) bv[nt] = bias[bn + wc*64 + nt*16 + l15];

#pragma unroll
    for (int mt = 0; mt < 4; ++mt) {
#pragma unroll
        for (int nt = 0; nt < 4; ++nt) {
            const int n = bn + wc*64 + nt*16 + l15;
#pragma unroll
            for (int r = 0; r < 4; ++r) {
                const int m = bm + wr*64 + mt*16 + 4*lg + r;
                float v = acc[mt][nt][r] + bv[nt];
                if (DO_RELU) v = fmaxf(v, 0.f);
                if (BF16OUT)
                    ((unsigned short*)Yout)[(size_t)m * N + n] = f2bf(v);
                else
                    ((float*)Yout)[(size_t)m * N + n] = v;
            }
        }
    }
}

// ---------------- f32 vector GEMM (small M=64 cases only) ------------------
__global__ __launch_bounds__(256) void gemm_kernel(
    const float* __restrict__ X, const float* __restrict__ W,
    const float* __restrict__ bias, const float* __restrict__ resid,
    float* __restrict__ Y, int M, int N, int K, int do_relu)
{
    __shared__ float As[16][68];
    __shared__ float Bs[16][68];
    const int tid = threadIdx.x;
    const int bm = blockIdx.y * 64, bn = blockIdx.x * 64;
    const int ty = tid >> 4, tx = tid & 15;
    const int lrow = tid >> 2, lc4 = (tid & 3) * 4;

    float acc[4][4];
#pragma unroll
    for (int i = 0; i < 4; ++i)
#pragma unroll
        for (int j = 0; j < 4; ++j) acc[i][j] = 0.f;

    for (int k0 = 0; k0 < K; k0 += 16) {
        const float4 xv = *reinterpret_cast<const float4*>(X + (size_t)(bm + lrow) * K + k0 + lc4);
        const float4 wv = *reinterpret_cast<const float4*>(W + (size_t)(bn + lrow) * K + k0 + lc4);
        __syncthreads();
        As[lc4+0][lrow] = xv.x; As[lc4+1][lrow] = xv.y;
        As[lc4+2][lrow] = xv.z; As[lc4+3][lrow] = xv.w;
        Bs[lc4+0][lrow] = wv.x; Bs[lc4+1][lrow] = wv.y;
        Bs[lc4+2][lrow] = wv.z; Bs[lc4+3][lrow] = wv.w;
        __syncthreads();
#pragma unroll
        for (int kk = 0; kk < 16; ++kk) {
            float a0 = As[kk][ty*4+0], a1 = As[kk][ty*4+1], a2 = As[kk][ty*4+2], a3 = As[kk][ty*4+3];
            float b0 = Bs[kk][tx*4+0], b1 = Bs[kk][tx*4+1], b2 = Bs[kk][tx*4+2], b3 = Bs[kk][tx*4+3];
            acc[0][0] += a0*b0; acc[0][1] += a0*b1; acc[0][2] += a0*b2; acc[0][3] += a0*b3;
            acc[1][0] += a1*b0; acc[1][1] += a1*b1; acc[1][2] += a1*b2; acc[1][3] += a1*b3;
            acc[2][0] += a2*b0; acc[2][1] += a2*b1; acc[2][2] += a2*b2; acc[2][3] += a2*b3;
            acc[3][0] += a3*b0; acc[3][1] += a3*b1; acc[3][2] += a3*b2; acc[3][3] += a3*b3;
        }
    }

#pragma unroll
    for (int i = 0; i < 4; ++i) {
        const int m = bm + ty*4 + i;
#pragma unroll
        for (int j = 0; j < 4; ++j) {
            const int n = bn + tx*4 + j;
            float v = acc[i][j] + bias[n];
            if (do_relu) v = fmaxf(v, 0.f);
            if (resid) v += resid[(size_t)m * N + n];
            Y[(size_t)m * N + n] = v;
        }
    }
}

// ---------------- MFMA bf16 causal flash attention (bf16 out) --------------
__global__ __launch_bounds__(256) void attn_mfma_kernel(
    const unsigned short* __restrict__ qkvb, unsigned short* __restrict__ ob)
{
    __shared__ unsigned short Ks[64*72];
    __shared__ unsigned short Vt[64*72];
    __shared__ unsigned short Plds[4*16*72];

    const int t    = threadIdx.x;
    const int lane = t & 63;
    const int w    = t >> 6;
    const int qb   = blockIdx.x;
    const int bh   = blockIdx.y;
    const int h    = bh & 7;
    const int b    = bh >> 3;
    const int q0w  = qb * 64 + w * 16;

    const unsigned short* base = qkvb + (size_t)b * S_ * 1536;
    const int l15 = lane & 15, lg = lane >> 4;

    bf16x8 qf0, qf1;
    {
        const unsigned short* qr = base + (size_t)(q0w + l15) * 1536 + h*64 + lg*8;
        qf0 = *reinterpret_cast<const bf16x8*>(qr);
        qf1 = *reinterpret_cast<const bf16x8*>(qr + 32);
    }

    f32x4 oacc[4];
#pragma unroll
    for (int i = 0; i < 4; ++i) oacc[i] = (f32x4){0.f,0.f,0.f,0.f};
    float mrow[4] = {-INFINITY,-INFINITY,-INFINITY,-INFINITY};
    float lrow[4] = {0.f,0.f,0.f,0.f};

    const int ntiles = qb + 1;
    const int skey = t >> 2, sd0 = (t & 3) * 16;
    unsigned short* pw_base = Plds + w*16*72;

    for (int tile = 0; tile < ntiles; ++tile) {
        const int kt = tile * 64;
        __syncthreads();
        {
            const unsigned short* srcK = base + (size_t)(kt + skey) * 1536 + 512  + h*64 + sd0;
            const unsigned short* srcV = base + (size_t)(kt + skey) * 1536 + 1024 + h*64 + sd0;
            *reinterpret_cast<bf16x8*>(&Ks[skey*72 + sd0])     = *reinterpret_cast<const bf16x8*>(srcK);
            *reinterpret_cast<bf16x8*>(&Ks[skey*72 + sd0 + 8]) = *reinterpret_cast<const bf16x8*>(srcK + 8);
            bf16x8 v0 = *reinterpret_cast<const bf16x8*>(srcV);
            bf16x8 v1 = *reinterpret_cast<const bf16x8*>(srcV + 8);
#pragma unroll
            for (int j = 0; j < 8; ++j) Vt[(sd0+j)*72 + skey]   = (unsigned short)v0[j];
#pragma unroll
            for (int j = 0; j < 8; ++j) Vt[(sd0+8+j)*72 + skey] = (unsigned short)v1[j];
        }
        __syncthreads();

        f32x4 sacc[4];
#pragma unroll
        for (int kt16 = 0; kt16 < 4; ++kt16) {
            sacc[kt16] = (f32x4){0.f,0.f,0.f,0.f};
            const unsigned short* kp = &Ks[(kt16*16 + l15)*72 + lg*8];
            bf16x8 k0 = *reinterpret_cast<const bf16x8*>(kp);
            bf16x8 k1 = *reinterpret_cast<const bf16x8*>(kp + 32);
            sacc[kt16] = __builtin_amdgcn_mfma_f32_16x16x32_bf16(qf0, k0, sacc[kt16], 0, 0, 0);
            sacc[kt16] = __builtin_amdgcn_mfma_f32_16x16x32_bf16(qf1, k1, sacc[kt16], 0, 0, 0);
        }

        const bool diag = (tile == ntiles - 1);
        float sv[4][4];
#pragma unroll
        for (int kt16 = 0; kt16 < 4; ++kt16) {
#pragma unroll
            for (int r = 0; r < 4; ++r) {
                float s = sacc[kt16][r] * 0.125f;
                if (diag) {
                    const int key = kt + kt16*16 + l15;
                    const int q   = q0w + 4*lg + r;
                    if (key > q) s = -INFINITY;
                }
                sv[kt16][r] = s;
            }
        }
#pragma unroll
        for (int r = 0; r < 4; ++r) {
            float tm = fmaxf(fmaxf(sv[0][r], sv[1][r]), fmaxf(sv[2][r], sv[3][r]));
#pragma unroll
            for (int off = 8; off; off >>= 1) tm = fmaxf(tm, __shfl_xor(tm, off, 64));
            const float nm = fmaxf(mrow[r], tm);
            const float al = __expf(mrow[r] - nm);
            mrow[r] = nm;
            float ps = 0.f;
#pragma unroll
            for (int kt16 = 0; kt16 < 4; ++kt16) {
                const float p = __expf(sv[kt16][r] - nm);
                ps += p;
                pw_base[(4*lg + r)*72 + kt16*16 + l15] = f2bf(p);
            }
#pragma unroll
            for (int off = 8; off; off >>= 1) ps += __shfl_xor(ps, off, 64);
            lrow[r] = lrow[r]*al + ps;
#pragma unroll
            for (int dt = 0; dt < 4; ++dt) oacc[dt][r] *= al;
        }

        const unsigned short* pr = &pw_base[l15*72 + lg*8];
        bf16x8 pa0 = *reinterpret_cast<const bf16x8*>(pr);
        bf16x8 pa1 = *reinterpret_cast<const bf16x8*>(pr + 32);
#pragma unroll
        for (int dt = 0; dt < 4; ++dt) {
            const unsigned short* vp = &Vt[(dt*16 + l15)*72 + lg*8];
            bf16x8 v0 = *reinterpret_cast<const bf16x8*>(vp);
            bf16x8 v1 = *reinterpret_cast<const bf16x8*>(vp + 32);
            oacc[dt] = __builtin_amdgcn_mfma_f32_16x16x32_bf16(pa0, v0, oacc[dt], 0, 0, 0);
            oacc[dt] = __builtin_amdgcn_mfma_f32_16x16x32_bf16(pa1, v1, oacc[dt], 0, 0, 0);
        }
    }

#pragma unroll
    for (int dt = 0; dt < 4; ++dt) {
#pragma unroll
        for (int r = 0; r < 4; ++r) {
            const int q = q0w + 4*lg + r;
            ob[((size_t)b*S_ + q)*D_ + h*64 + dt*16 + l15] = f2bf(oacc[dt][r] / lrow[r]);
        }
    }
}

// ---------------- LayerNorm (residual add, optional bf16 shadow out) -------
__global__ __launch_bounds__(256) void ln_kernel(
    float* __restrict__ dst, unsigned short* __restrict__ dst2,
    const float* __restrict__ src, const float* __restrict__ add,
    const float* __restrict__ w, const float* __restrict__ b, float eps)
{
    const int row = blockIdx.x, tid = threadIdx.x;
    const int lane = tid & 63, wave = tid >> 6;
    float2 v = *reinterpret_cast<const float2*>(src + (size_t)row * D_ + tid*2);
    if (add) {
        float2 a = *reinterpret_cast<const float2*>(add + (size_t)row * D_ + tid*2);
        v.x += a.x; v.y += a.y;
    }
    __shared__ float red[8];
    float s = v.x + v.y;
#pragma unroll
    for (int off = 32; off; off >>= 1) s += __shfl_xor(s, off, 64);
    if (lane == 0) red[wave] = s;
    __syncthreads();
    const float mean = (red[0]+red[1]+red[2]+red[3]) * (1.f/D_);
    const float d0 = v.x - mean, d1 = v.y - mean;
    float sq = d0*d0 + d1*d1;
#pragma unroll
    for (int off = 32; off; off >>= 1) sq += __shfl_xor(sq, off, 64);
    if (lane == 0) red[4+wave] = sq;
    __syncthreads();
    const float var = (red[4]+red[5]+red[6]+red[7]) * (1.f/D_);
    const float inv = rsqrtf(var + eps);
    const float o0 = d0*inv*w[tid*2] + b[tid*2];
    const float o1 = d1*inv*w[tid*2+1] + b[tid*2+1];
    *reinterpret_cast<float2*>(dst + (size_t)row * D_ + tid*2) = make_float2(o0, o1);
    if (dst2) {
        ushort2 u; u.x = f2bf(o0); u.y = f2bf(o1);
        *reinterpret_cast<ushort2*>(dst2 + (size_t)row * D_ + tid*2) = u;
    }
}

// ---------------- patch mean-pool ----------------
__global__ __launch_bounds__(256) void meanpool_kernel(
    const float* __restrict__ x, float* __restrict__ query)
{
    const int bp = blockIdx.x;
    const int d = threadIdx.x * 2;
    const float* base = x + (size_t)bp * PLEN_ * D_ + d;
    float s0 = 0.f, s1 = 0.f;
    for (int l = 0; l < PLEN_; ++l) {
        float2 v = *reinterpret_cast<const float2*>(base + (size_t)l * D_);
        s0 += v.x; s1 += v.y;
    }
    query[(size_t)bp*D_ + d]     = s0 * (1.f/PLEN_);
    query[(size_t)bp*D_ + d + 1] = s1 * (1.f/PLEN_);
}

// ---------------- patch cross-attention, one wave per (b,p,h) -------------
__global__ __launch_bounds__(256) void patch_attn_kernel(
    const float* __restrict__ qbuf, const float* __restrict__ kv,
    float* __restrict__ o)
{
    const int wid  = blockIdx.x * 4 + (threadIdx.x >> 6);
    const int lane = threadIdx.x & 63;
    const int h  = wid % H_;
    const int bp = wid / H_;
    const float qv = qbuf[(size_t)bp*D_ + h*HD_ + lane] * 0.125f;
    const float* base = kv + (size_t)bp * PLEN_ * 1024 + h*HD_;

    float m = -INFINITY, l = 0.f, acc = 0.f;
    for (int t = 0; t < PLEN_; ++t) {
        const float* row = base + (size_t)t * 1024;
        float s = qv * row[lane];
#pragma unroll
        for (int off = 32; off; off >>= 1) s += __shfl_xor(s, off, 64);
        const float vv = row[512 + lane];
        const float nm = fmaxf(m, s);
        const float al = __expf(m - nm);
        const float p  = __expf(s - nm);
        l = l * al + p;
        acc = acc * al + p * vv;
        m = nm;
    }
    o[(size_t)bp*D_ + h*HD_ + lane] = acc / l;
}

extern "C" void kernel_launch(void* const* d_in, const int* in_sizes, int n_in,
                              void* d_out, int out_size, void* d_ws, size_t ws_size,
                              hipStream_t stream)
{
    const int*   byte_seq = (const int*)d_in[0];
    const float* byte_emb = (const float*)d_in[2];
    const float* ng_emb   = (const float*)d_in[3];
    const float* qkv_w = (const float*)d_in[4];
    const float* qkv_b = (const float*)d_in[5];
    const float* out_w = (const float*)d_in[6];
    const float* out_b = (const float*)d_in[7];
    const float* ln1_w = (const float*)d_in[8];
    const float* ln1_b = (const float*)d_in[9];
    const float* ln2_w = (const float*)d_in[10];
    const float* ln2_b = (const float*)d_in[11];
    const float* ff1_w = (const float*)d_in[12];
    const float* ff1_b = (const float*)d_in[13];
    const float* ff2_w = (const float*)d_in[14];
    const float* ff2_b = (const float*)d_in[15];
    const float* ca_qkv_w = (const float*)d_in[16];
    const float* ca_qkv_b = (const float*)d_in[17];
    const float* ca_out_w = (const float*)d_in[18];
    const float* ca_out_b = (const float*)d_in[19];
    const float* ca_ln_w  = (const float*)d_in[20];
    const float* ca_ln_b  = (const float*)d_in[21];
    const float* norm_w   = (const float*)d_in[22];
    const float* norm_b   = (const float*)d_in[23];
    float* out = (float*)d_out;

    char* ws = (char*)d_ws;
    const size_t MB = 1024*1024;
    float*          x     = (float*)(ws);                  // [0,16M)  8192x512 f32
    char*           bufA  = ws + 16*MB;                    // [16,48M) qkvb/ff1b bf16, kv f32
    float*          bufB  = (float*)(ws + 48*MB);          // [48,64M) 8192x512 f32
    unsigned short* ob    = (unsigned short*)(ws + 64*MB); // [64,72M) attn out bf16
    unsigned short* xb    = (unsigned short*)(ws + 72*MB); // [72,80M) x shadow bf16 / kvnb
    unsigned short* qkvw_b = (unsigned short*)(ws + 80*MB);
    unsigned short* outw_b = (unsigned short*)(ws + 83*MB);
    unsigned short* ff1w_b = (unsigned short*)(ws + 84*MB);
    unsigned short* ff2w_b = (unsigned short*)(ws + 88*MB);
    unsigned short* kvw_b  = (unsigned short*)(ws + 92*MB);
    float* query   = (float*)(ws + 93*MB);
    float* qn      = query + 64*512;
    float* qsm     = qn + 64*512;
    float* oca     = qsm + 64*512;
    float* patches = oca + 64*512;

    unsigned short* qkvb = (unsigned short*)bufA;   // bf16 [8192][1536]
    unsigned short* ff1b = (unsigned short*)bufA;   // bf16 [8192][2048]
    float*          kvf  = (float*)bufA;            // f32  [8192][1024]

    const int M = B_ * S_;   // 8192

    // 0. one-time weight casts to bf16
    cast_kernel<<<(2*1536*512/4)/256, 256, 0, stream>>>(qkv_w, qkvw_b, 2*1536*512/4);
    cast_kernel<<<(2*512*512/4)/256, 256, 0, stream>>>(out_w, outw_b, 2*512*512/4);
    cast_kernel<<<(2*2048*512/4)/256, 256, 0, stream>>>(ff1_w, ff1w_b, 2*2048*512/4);
    cast_kernel<<<(2*512*2048/4)/256, 256, 0, stream>>>(ff2_w, ff2w_b, 2*512*2048/4);
    cast_kernel<<<(1024*512/4)/256, 256, 0, stream>>>(ca_qkv_w + 512*512, kvw_b, 1024*512/4);

    // 1. byte embedding + n-gram hash adds (f32 + bf16 shadow)
    embed_ngram_kernel<<<M, 128, 0, stream>>>(byte_seq, byte_emb, ng_emb, x, xb);

    // 2. transformer layers
    for (int l = 0; l < L_; ++l) {
        mgemm_kernel<0,1><<<dim3(1536/128, M/128), 256, 0, stream>>>(
            xb, qkvw_b + (size_t)l*1536*D_, qkv_b + l*1536, qkvb, M, 1536, D_);
        attn_mfma_kernel<<<dim3(S_/64, B_*H_), 256, 0, stream>>>(qkvb, ob);
        mgemm_kernel<0,0><<<dim3(D_/128, M/128), 256, 0, stream>>>(
            ob, outw_b + (size_t)l*D_*D_, out_b + l*D_, bufB, M, D_, D_);
        ln_kernel<<<M, 256, 0, stream>>>(x, xb, x, bufB, ln1_w + l*D_, ln1_b + l*D_, 1e-5f);
        mgemm_kernel<1,1><<<dim3(2048/128, M/128), 256, 0, stream>>>(
            xb, ff1w_b + (size_t)l*2048*D_, ff1_b + l*2048, ff1b, M, 2048, D_);
        mgemm_kernel<0,0><<<dim3(D_/128, M/128), 256, 0, stream>>>(
            ff1b, ff2w_b + (size_t)l*D_*2048, ff2_b + l*D_, bufB, M, D_, 2048);
        ln_kernel<<<M, 256, 0, stream>>>(x, xb, x, bufB, ln2_w + l*D_, ln2_b + l*D_, 1e-5f);
    }

    // 3. patch cross-attention
    meanpool_kernel<<<B_*NPATCH_, 256, 0, stream>>>(x, query);
    ln_kernel<<<B_*NPATCH_, 256, 0, stream>>>(qn, nullptr, query, nullptr, ca_ln_w, ca_ln_b, 1e-6f);
    // kvn = LN(x): f32 -> bufB (unused), bf16 -> xb
    ln_kernel<<<M, 256, 0, stream>>>(bufB, xb, x, nullptr, ca_ln_w, ca_ln_b, 1e-6f);
    mgemm_kernel<0,0><<<dim3(1024/128, M/128), 256, 0, stream>>>(
        xb, kvw_b, ca_qkv_b + 512, kvf, M, 1024, D_);
    gemm_kernel<<<dim3(D_/64, 1), 256, 0, stream>>>(
        qn, ca_qkv_w, ca_qkv_b, nullptr, qsm, 64, D_, D_, 0);
    patch_attn_kernel<<<B_*NPATCH_*H_/4, 256, 0, stream>>>(qsm, kvf, oca);
    gemm_kernel<<<dim3(D_/64, 1), 256, 0, stream>>>(
        oca, ca_out_w, ca_out_b, query, patches, 64, D_, D_, 0);

    // 4. final LayerNorms -> f32 outputs
    ln_kernel<<<M, 256, 0, stream>>>(out, nullptr, x, nullptr, norm_w, norm_b, 1e-6f);
    ln_kernel<<<B_*NPATCH_, 256, 0, stream>>>(
        out + (size_t)M*D_, nullptr, patches, nullptr, norm_w, norm_b, 1e-6f);
}

// Round 7
// 620.834 us; speedup vs baseline: 18.0583x; 1.2200x over previous
//
#include <hip/hip_runtime.h>
#include <hip/hip_bf16.h>

#define B_ 4
#define S_ 2048
#define D_ 512
#define H_ 8
#define HD_ 64
#define L_ 2
#define V_ 30000
#define NPATCH_ 16
#define PLEN_ 128

typedef short bf16x8 __attribute__((ext_vector_type(8)));
typedef float f32x4 __attribute__((ext_vector_type(4)));

__device__ __forceinline__ unsigned short f2bf(float f) {
    unsigned u = __float_as_uint(f);
    return (unsigned short)((u + 0x7FFFu + ((u >> 16) & 1u)) >> 16);   // RNE
}

// ---------------- f32 -> bf16 cast (weights) ----------------
__global__ __launch_bounds__(256) void cast_kernel(
    const float* __restrict__ src, unsigned short* __restrict__ dst, int n4)
{
    const int i = blockIdx.x * 256 + threadIdx.x;
    if (i >= n4) return;
    const float4 v = *reinterpret_cast<const float4*>(src + (size_t)i * 4);
    ushort4 o;
    o.x = f2bf(v.x); o.y = f2bf(v.y); o.z = f2bf(v.z); o.w = f2bf(v.w);
    *reinterpret_cast<ushort4*>(dst + (size_t)i * 4) = o;
}

// ---------------- embed + n-gram hash add (f32 + bf16 shadow) -------------
__global__ __launch_bounds__(128) void embed_ngram_kernel(
    const int* __restrict__ bytes, const float* __restrict__ byte_emb,
    const float* __restrict__ ng_emb, float* __restrict__ x,
    unsigned short* __restrict__ xb)
{
    const int bs = blockIdx.x;
    const int s  = bs % S_;
    const int b  = bs / S_;
    const int d  = threadIdx.x * 4;
    const int* brow = bytes + (size_t)b * S_;

    const int c = brow[s];
    float4 v = *reinterpret_cast<const float4*>(byte_emb + (size_t)c * D_ + d);

    if (s >= 2) {
        int h = (brow[s-2]*961 + brow[s-1]*31 + brow[s]) % V_;
        const float4 g = *reinterpret_cast<const float4*>(ng_emb + ((size_t)0*V_ + h)*D_ + d);
        v.x += 0.25f*g.x; v.y += 0.25f*g.y; v.z += 0.25f*g.z; v.w += 0.25f*g.w;
    }
    if (s >= 3) {
        int h = (brow[s-3]*29791 + brow[s-2]*961 + brow[s-1]*31 + brow[s]) % V_;
        const float4 g = *reinterpret_cast<const float4*>(ng_emb + ((size_t)1*V_ + h)*D_ + d);
        v.x += 0.25f*g.x; v.y += 0.25f*g.y; v.z += 0.25f*g.z; v.w += 0.25f*g.w;
    }
    if (s >= 4) {
        int h = (brow[s-4]*23521 + brow[s-3]*29791 + brow[s-2]*961 + brow[s-1]*31 + brow[s]) % V_;
        const float4 g = *reinterpret_cast<const float4*>(ng_emb + ((size_t)2*V_ + h)*D_ + d);
        v.x += 0.25f*g.x; v.y += 0.25f*g.y; v.z += 0.25f*g.z; v.w += 0.25f*g.w;
    }
    *reinterpret_cast<float4*>(x + (size_t)bs * D_ + d) = v;
    ushort4 o;
    o.x = f2bf(v.x); o.y = f2bf(v.y); o.z = f2bf(v.z); o.w = f2bf(v.w);
    *reinterpret_cast<ushort4*>(xb + (size_t)bs * D_ + d) = o;
}

// ---------------- MFMA bf16 GEMM: Y = X @ W^T + bias [,relu] --------------
template<int DO_RELU, int BF16OUT>
__global__ __launch_bounds__(256) void mgemm_kernel(
    const unsigned short* __restrict__ Xb, const unsigned short* __restrict__ Wb,
    const float* __restrict__ bias, void* __restrict__ Yout,
    int M, int N, int K)
{
    __shared__ unsigned short As[128*64];
    __shared__ unsigned short Bs[128*64];

    const int t    = threadIdx.x;
    const int lane = t & 63;
    const int w    = t >> 6;
    const int bm   = blockIdx.y * 128, bn = blockIdx.x * 128;
    const int l15  = lane & 15, lg = lane >> 4;
    const int wr   = w >> 1, wc = w & 1;

    int srow[4], scol[4];
#pragma unroll
    for (int i = 0; i < 4; ++i) {
        const int off = w*1024 + i*4096 + lane*16;
        srow[i] = off >> 7;
        scol[i] = ((off >> 4) & 7) ^ (srow[i] & 7);
    }

    f32x4 acc[4][4];
#pragma unroll
    for (int mt = 0; mt < 4; ++mt)
#pragma unroll
        for (int nt = 0; nt < 4; ++nt) acc[mt][nt] = (f32x4){0.f,0.f,0.f,0.f};

    for (int kt = 0; kt < K; kt += 64) {
#pragma unroll
        for (int i = 0; i < 4; ++i) {
            const unsigned short* gA = Xb + (size_t)(bm + srow[i]) * K + kt + scol[i]*8;
            const unsigned short* gB = Wb + (size_t)(bn + srow[i]) * K + kt + scol[i]*8;
            __builtin_amdgcn_global_load_lds(
                (const __attribute__((address_space(1))) void*)gA,
                (__attribute__((address_space(3))) void*)&As[w*512 + i*2048], 16, 0, 0);
            __builtin_amdgcn_global_load_lds(
                (const __attribute__((address_space(1))) void*)gB,
                (__attribute__((address_space(3))) void*)&Bs[w*512 + i*2048], 16, 0, 0);
        }
        __syncthreads();

#pragma unroll
        for (int ks = 0; ks < 2; ++ks) {
            const int c16 = (ks*4 + lg) ^ (l15 & 7);
            bf16x8 a[4], b[4];
#pragma unroll
            for (int mt = 0; mt < 4; ++mt)
                a[mt] = *reinterpret_cast<const bf16x8*>(&As[(wr*64 + mt*16 + l15)*64 + c16*8]);
#pragma unroll
            for (int nt = 0; nt < 4; ++nt)
                b[nt] = *reinterpret_cast<const bf16x8*>(&Bs[(wc*64 + nt*16 + l15)*64 + c16*8]);
#pragma unroll
            for (int mt = 0; mt < 4; ++mt)
#pragma unroll
                for (int nt = 0; nt < 4; ++nt)
                    acc[mt][nt] = __builtin_amdgcn_mfma_f32_16x16x32_bf16(
                        a[mt], b[nt], acc[mt][nt], 0, 0, 0);
        }
        __syncthreads();
    }

    float bv[4];
#pragma unroll
    for (int nt = 0; nt < 4; ++nt) bv[nt] = bias[bn + wc*64 + nt*16 + l15];

#pragma unroll
    for (int mt = 0; mt < 4; ++mt) {
#pragma unroll
        for (int nt = 0; nt < 4; ++nt) {
            const int n = bn + wc*64 + nt*16 + l15;
#pragma unroll
            for (int r = 0; r < 4; ++r) {
                const int m = bm + wr*64 + mt*16 + 4*lg + r;
                float v = acc[mt][nt][r] + bv[nt];
                if (DO_RELU) v = fmaxf(v, 0.f);
                if (BF16OUT)
                    ((unsigned short*)Yout)[(size_t)m * N + n] = f2bf(v);
                else
                    ((float*)Yout)[(size_t)m * N + n] = v;
            }
        }
    }
}

// ---------------- f32 vector GEMM (small M=64 cases only) ------------------
__global__ __launch_bounds__(256) void gemm_kernel(
    const float* __restrict__ X, const float* __restrict__ W,
    const float* __restrict__ bias, const float* __restrict__ resid,
    float* __restrict__ Y, int M, int N, int K, int do_relu)
{
    __shared__ float As[16][68];
    __shared__ float Bs[16][68];
    const int tid = threadIdx.x;
    const int bm = blockIdx.y * 64, bn = blockIdx.x * 64;
    const int ty = tid >> 4, tx = tid & 15;
    const int lrow = tid >> 2, lc4 = (tid & 3) * 4;

    float acc[4][4];
#pragma unroll
    for (int i = 0; i < 4; ++i)
#pragma unroll
        for (int j = 0; j < 4; ++j) acc[i][j] = 0.f;

    for (int k0 = 0; k0 < K; k0 += 16) {
        const float4 xv = *reinterpret_cast<const float4*>(X + (size_t)(bm + lrow) * K + k0 + lc4);
        const float4 wv = *reinterpret_cast<const float4*>(W + (size_t)(bn + lrow) * K + k0 + lc4);
        __syncthreads();
        As[lc4+0][lrow] = xv.x; As[lc4+1][lrow] = xv.y;
        As[lc4+2][lrow] = xv.z; As[lc4+3][lrow] = xv.w;
        Bs[lc4+0][lrow] = wv.x; Bs[lc4+1][lrow] = wv.y;
        Bs[lc4+2][lrow] = wv.z; Bs[lc4+3][lrow] = wv.w;
        __syncthreads();
#pragma unroll
        for (int kk = 0; kk < 16; ++kk) {
            float a0 = As[kk][ty*4+0], a1 = As[kk][ty*4+1], a2 = As[kk][ty*4+2], a3 = As[kk][ty*4+3];
            float b0 = Bs[kk][tx*4+0], b1 = Bs[kk][tx*4+1], b2 = Bs[kk][tx*4+2], b3 = Bs[kk][tx*4+3];
            acc[0][0] += a0*b0; acc[0][1] += a0*b1; acc[0][2] += a0*b2; acc[0][3] += a0*b3;
            acc[1][0] += a1*b0; acc[1][1] += a1*b1; acc[1][2] += a1*b2; acc[1][3] += a1*b3;
            acc[2][0] += a2*b0; acc[2][1] += a2*b1; acc[2][2] += a2*b2; acc[2][3] += a2*b3;
            acc[3][0] += a3*b0; acc[3][1] += a3*b1; acc[3][2] += a3*b2; acc[3][3] += a3*b3;
        }
    }

#pragma unroll
    for (int i = 0; i < 4; ++i) {
        const int m = bm + ty*4 + i;
#pragma unroll
        for (int j = 0; j < 4; ++j) {
            const int n = bn + tx*4 + j;
            float v = acc[i][j] + bias[n];
            if (do_relu) v = fmaxf(v, 0.f);
            if (resid) v += resid[(size_t)m * N + n];
            Y[(size_t)m * N + n] = v;
        }
    }
}

// ---------------- MFMA bf16 causal flash attention (folded triangle) -------
// Each block handles q-block pair {qp, 31-qp}: exactly 33 KV tiles of work,
// eliminating the triangular tail (was 1..32 tiles -> 13.8% occupancy).
// V^T staging: col-chunk XOR-swizzled by (row>>4) on BOTH write and read
// (4 staging rows {j,j+16,j+32,j+48} otherwise alias to one bank: 4-way).
__global__ __launch_bounds__(256) void attn_mfma_kernel(
    const unsigned short* __restrict__ qkvb, unsigned short* __restrict__ ob)
{
    __shared__ unsigned short Ks[64*72];
    __shared__ unsigned short Vt[64*72];
    __shared__ unsigned short Plds[4*16*72];

    const int t    = threadIdx.x;
    const int lane = t & 63;
    const int w    = t >> 6;
    const int qp   = blockIdx.x;          // 0..15 (pair index)
    const int bh   = blockIdx.y;          // 0..31
    const int h    = bh & 7;
    const int b    = bh >> 3;

    const unsigned short* base = qkvb + (size_t)b * S_ * 1536;
    const int l15 = lane & 15, lg = lane >> 4;
    const int skey = t >> 2, sd0 = (t & 3) * 16;
    const int sg = sd0 >> 4;              // row>>4 for this thread's V rows
    const int scs = ((skey >> 3) ^ sg) * 8 + (skey & 7);  // swizzled V^T col
    unsigned short* pw_base = Plds + w*16*72;

#pragma unroll
    for (int half = 0; half < 2; ++half) {
        const int qb  = half ? (31 - qp) : qp;
        const int q0w = qb * 64 + w * 16;

        bf16x8 qf0, qf1;
        {
            const unsigned short* qr = base + (size_t)(q0w + l15) * 1536 + h*64 + lg*8;
            qf0 = *reinterpret_cast<const bf16x8*>(qr);
            qf1 = *reinterpret_cast<const bf16x8*>(qr + 32);
        }

        f32x4 oacc[4];
#pragma unroll
        for (int i = 0; i < 4; ++i) oacc[i] = (f32x4){0.f,0.f,0.f,0.f};
        float mrow[4] = {-INFINITY,-INFINITY,-INFINITY,-INFINITY};
        float lrow[4] = {0.f,0.f,0.f,0.f};

        const int ntiles = qb + 1;
        for (int tile = 0; tile < ntiles; ++tile) {
            const int kt = tile * 64;
            __syncthreads();   // previous tile (or previous half) fully consumed
            {
                const unsigned short* srcK = base + (size_t)(kt + skey) * 1536 + 512  + h*64 + sd0;
                const unsigned short* srcV = base + (size_t)(kt + skey) * 1536 + 1024 + h*64 + sd0;
                *reinterpret_cast<bf16x8*>(&Ks[skey*72 + sd0])     = *reinterpret_cast<const bf16x8*>(srcK);
                *reinterpret_cast<bf16x8*>(&Ks[skey*72 + sd0 + 8]) = *reinterpret_cast<const bf16x8*>(srcK + 8);
                bf16x8 v0 = *reinterpret_cast<const bf16x8*>(srcV);
                bf16x8 v1 = *reinterpret_cast<const bf16x8*>(srcV + 8);
#pragma unroll
                for (int j = 0; j < 8; ++j) Vt[(sd0+j)*72 + scs]   = (unsigned short)v0[j];
#pragma unroll
                for (int j = 0; j < 8; ++j) Vt[(sd0+8+j)*72 + scs] = (unsigned short)v1[j];
            }
            __syncthreads();

            // ---- QK^T ----
            f32x4 sacc[4];
#pragma unroll
            for (int kt16 = 0; kt16 < 4; ++kt16) {
                sacc[kt16] = (f32x4){0.f,0.f,0.f,0.f};
                const unsigned short* kp = &Ks[(kt16*16 + l15)*72 + lg*8];
                bf16x8 k0 = *reinterpret_cast<const bf16x8*>(kp);
                bf16x8 k1 = *reinterpret_cast<const bf16x8*>(kp + 32);
                sacc[kt16] = __builtin_amdgcn_mfma_f32_16x16x32_bf16(qf0, k0, sacc[kt16], 0, 0, 0);
                sacc[kt16] = __builtin_amdgcn_mfma_f32_16x16x32_bf16(qf1, k1, sacc[kt16], 0, 0, 0);
            }

            // ---- scale + causal mask + online softmax ----
            const bool diag = (tile == ntiles - 1);
            float sv[4][4];
#pragma unroll
            for (int kt16 = 0; kt16 < 4; ++kt16) {
#pragma unroll
                for (int r = 0; r < 4; ++r) {
                    float s = sacc[kt16][r] * 0.125f;
                    if (diag) {
                        const int key = kt + kt16*16 + l15;
                        const int q   = q0w + 4*lg + r;
                        if (key > q) s = -INFINITY;
                    }
                    sv[kt16][r] = s;
                }
            }
#pragma unroll
            for (int r = 0; r < 4; ++r) {
                float tm = fmaxf(fmaxf(sv[0][r], sv[1][r]), fmaxf(sv[2][r], sv[3][r]));
#pragma unroll
                for (int off = 8; off; off >>= 1) tm = fmaxf(tm, __shfl_xor(tm, off, 64));
                const float nm = fmaxf(mrow[r], tm);
                const float al = __expf(mrow[r] - nm);
                mrow[r] = nm;
                float ps = 0.f;
#pragma unroll
                for (int kt16 = 0; kt16 < 4; ++kt16) {
                    const float p = __expf(sv[kt16][r] - nm);
                    ps += p;
                    pw_base[(4*lg + r)*72 + kt16*16 + l15] = f2bf(p);
                }
#pragma unroll
                for (int off = 8; off; off >>= 1) ps += __shfl_xor(ps, off, 64);
                lrow[r] = lrow[r]*al + ps;
#pragma unroll
                for (int dt = 0; dt < 4; ++dt) oacc[dt][r] *= al;
            }

            // ---- PV ----
            const unsigned short* pr = &pw_base[l15*72 + lg*8];
            bf16x8 pa0 = *reinterpret_cast<const bf16x8*>(pr);
            bf16x8 pa1 = *reinterpret_cast<const bf16x8*>(pr + 32);
#pragma unroll
            for (int dt = 0; dt < 4; ++dt) {
                const unsigned short* vp = &Vt[(dt*16 + l15)*72 + (lg ^ dt)*8];
                bf16x8 v0 = *reinterpret_cast<const bf16x8*>(vp);
                bf16x8 v1 = *reinterpret_cast<const bf16x8*>(vp + 32);
                oacc[dt] = __builtin_amdgcn_mfma_f32_16x16x32_bf16(pa0, v0, oacc[dt], 0, 0, 0);
                oacc[dt] = __builtin_amdgcn_mfma_f32_16x16x32_bf16(pa1, v1, oacc[dt], 0, 0, 0);
            }
        }

        // ---- epilogue for this half ----
#pragma unroll
        for (int dt = 0; dt < 4; ++dt) {
#pragma unroll
            for (int r = 0; r < 4; ++r) {
                const int q = q0w + 4*lg + r;
                ob[((size_t)b*S_ + q)*D_ + h*64 + dt*16 + l15] = f2bf(oacc[dt][r] / lrow[r]);
            }
        }
    }
}

// ---------------- LayerNorm (residual add, optional bf16 shadow out) -------
__global__ __launch_bounds__(256) void ln_kernel(
    float* __restrict__ dst, unsigned short* __restrict__ dst2,
    const float* __restrict__ src, const float* __restrict__ add,
    const float* __restrict__ w, const float* __restrict__ b, float eps)
{
    const int row = blockIdx.x, tid = threadIdx.x;
    const int lane = tid & 63, wave = tid >> 6;
    float2 v = *reinterpret_cast<const float2*>(src + (size_t)row * D_ + tid*2);
    if (add) {
        float2 a = *reinterpret_cast<const float2*>(add + (size_t)row * D_ + tid*2);
        v.x += a.x; v.y += a.y;
    }
    __shared__ float red[8];
    float s = v.x + v.y;
#pragma unroll
    for (int off = 32; off; off >>= 1) s += __shfl_xor(s, off, 64);
    if (lane == 0) red[wave] = s;
    __syncthreads();
    const float mean = (red[0]+red[1]+red[2]+red[3]) * (1.f/D_);
    const float d0 = v.x - mean, d1 = v.y - mean;
    float sq = d0*d0 + d1*d1;
#pragma unroll
    for (int off = 32; off; off >>= 1) sq += __shfl_xor(sq, off, 64);
    if (lane == 0) red[4+wave] = sq;
    __syncthreads();
    const float var = (red[4]+red[5]+red[6]+red[7]) * (1.f/D_);
    const float inv = rsqrtf(var + eps);
    const float o0 = d0*inv*w[tid*2] + b[tid*2];
    const float o1 = d1*inv*w[tid*2+1] + b[tid*2+1];
    *reinterpret_cast<float2*>(dst + (size_t)row * D_ + tid*2) = make_float2(o0, o1);
    if (dst2) {
        ushort2 u; u.x = f2bf(o0); u.y = f2bf(o1);
        *reinterpret_cast<ushort2*>(dst2 + (size_t)row * D_ + tid*2) = u;
    }
}

// ---------------- patch mean-pool ----------------
__global__ __launch_bounds__(256) void meanpool_kernel(
    const float* __restrict__ x, float* __restrict__ query)
{
    const int bp = blockIdx.x;
    const int d = threadIdx.x * 2;
    const float* base = x + (size_t)bp * PLEN_ * D_ + d;
    float s0 = 0.f, s1 = 0.f;
    for (int l = 0; l < PLEN_; ++l) {
        float2 v = *reinterpret_cast<const float2*>(base + (size_t)l * D_);
        s0 += v.x; s1 += v.y;
    }
    query[(size_t)bp*D_ + d]     = s0 * (1.f/PLEN_);
    query[(size_t)bp*D_ + d + 1] = s1 * (1.f/PLEN_);
}

// ---------------- patch cross-attention, one wave per (b,p,h) -------------
__global__ __launch_bounds__(256) void patch_attn_kernel(
    const float* __restrict__ qbuf, const float* __restrict__ kv,
    float* __restrict__ o)
{
    const int wid  = blockIdx.x * 4 + (threadIdx.x >> 6);
    const int lane = threadIdx.x & 63;
    const int h  = wid % H_;
    const int bp = wid / H_;
    const float qv = qbuf[(size_t)bp*D_ + h*HD_ + lane] * 0.125f;
    const float* base = kv + (size_t)bp * PLEN_ * 1024 + h*HD_;

    float m = -INFINITY, l = 0.f, acc = 0.f;
    for (int t = 0; t < PLEN_; ++t) {
        const float* row = base + (size_t)t * 1024;
        float s = qv * row[lane];
#pragma unroll
        for (int off = 32; off; off >>= 1) s += __shfl_xor(s, off, 64);
        const float vv = row[512 + lane];
        const float nm = fmaxf(m, s);
        const float al = __expf(m - nm);
        const float p  = __expf(s - nm);
        l = l * al + p;
        acc = acc * al + p * vv;
        m = nm;
    }
    o[(size_t)bp*D_ + h*HD_ + lane] = acc / l;
}

extern "C" void kernel_launch(void* const* d_in, const int* in_sizes, int n_in,
                              void* d_out, int out_size, void* d_ws, size_t ws_size,
                              hipStream_t stream)
{
    const int*   byte_seq = (const int*)d_in[0];
    const float* byte_emb = (const float*)d_in[2];
    const float* ng_emb   = (const float*)d_in[3];
    const float* qkv_w = (const float*)d_in[4];
    const float* qkv_b = (const float*)d_in[5];
    const float* out_w = (const float*)d_in[6];
    const float* out_b = (const float*)d_in[7];
    const float* ln1_w = (const float*)d_in[8];
    const float* ln1_b = (const float*)d_in[9];
    const float* ln2_w = (const float*)d_in[10];
    const float* ln2_b = (const float*)d_in[11];
    const float* ff1_w = (const float*)d_in[12];
    const float* ff1_b = (const float*)d_in[13];
    const float* ff2_w = (const float*)d_in[14];
    const float* ff2_b = (const float*)d_in[15];
    const float* ca_qkv_w = (const float*)d_in[16];
    const float* ca_qkv_b = (const float*)d_in[17];
    const float* ca_out_w = (const float*)d_in[18];
    const float* ca_out_b = (const float*)d_in[19];
    const float* ca_ln_w  = (const float*)d_in[20];
    const float* ca_ln_b  = (const float*)d_in[21];
    const float* norm_w   = (const float*)d_in[22];
    const float* norm_b   = (const float*)d_in[23];
    float* out = (float*)d_out;

    char* ws = (char*)d_ws;
    const size_t MB = 1024*1024;
    float*          x     = (float*)(ws);
    char*           bufA  = ws + 16*MB;
    float*          bufB  = (float*)(ws + 48*MB);
    unsigned short* ob    = (unsigned short*)(ws + 64*MB);
    unsigned short* xb    = (unsigned short*)(ws + 72*MB);
    unsigned short* qkvw_b = (unsigned short*)(ws + 80*MB);
    unsigned short* outw_b = (unsigned short*)(ws + 83*MB);
    unsigned short* ff1w_b = (unsigned short*)(ws + 84*MB);
    unsigned short* ff2w_b = (unsigned short*)(ws + 88*MB);
    unsigned short* kvw_b  = (unsigned short*)(ws + 92*MB);
    float* query   = (float*)(ws + 93*MB);
    float* qn      = query + 64*512;
    float* qsm     = qn + 64*512;
    float* oca     = qsm + 64*512;
    float* patches = oca + 64*512;

    unsigned short* qkvb = (unsigned short*)bufA;
    unsigned short* ff1b = (unsigned short*)bufA;
    float*          kvf  = (float*)bufA;

    const int M = B_ * S_;

    // 0. one-time weight casts to bf16
    cast_kernel<<<(2*1536*512/4)/256, 256, 0, stream>>>(qkv_w, qkvw_b, 2*1536*512/4);
    cast_kernel<<<(2*512*512/4)/256, 256, 0, stream>>>(out_w, outw_b, 2*512*512/4);
    cast_kernel<<<(2*2048*512/4)/256, 256, 0, stream>>>(ff1_w, ff1w_b, 2*2048*512/4);
    cast_kernel<<<(2*512*2048/4)/256, 256, 0, stream>>>(ff2_w, ff2w_b, 2*512*2048/4);
    cast_kernel<<<(1024*512/4)/256, 256, 0, stream>>>(ca_qkv_w + 512*512, kvw_b, 1024*512/4);

    // 1. byte embedding + n-gram hash adds
    embed_ngram_kernel<<<M, 128, 0, stream>>>(byte_seq, byte_emb, ng_emb, x, xb);

    // 2. transformer layers
    for (int l = 0; l < L_; ++l) {
        mgemm_kernel<0,1><<<dim3(1536/128, M/128), 256, 0, stream>>>(
            xb, qkvw_b + (size_t)l*1536*D_, qkv_b + l*1536, qkvb, M, 1536, D_);
        attn_mfma_kernel<<<dim3(S_/128, B_*H_), 256, 0, stream>>>(qkvb, ob);
        mgemm_kernel<0,0><<<dim3(D_/128, M/128), 256, 0, stream>>>(
            ob, outw_b + (size_t)l*D_*D_, out_b + l*D_, bufB, M, D_, D_);
        ln_kernel<<<M, 256, 0, stream>>>(x, xb, x, bufB, ln1_w + l*D_, ln1_b + l*D_, 1e-5f);
        mgemm_kernel<1,1><<<dim3(2048/128, M/128), 256, 0, stream>>>(
            xb, ff1w_b + (size_t)l*2048*D_, ff1_b + l*2048, ff1b, M, 2048, D_);
        mgemm_kernel<0,0><<<dim3(D_/128, M/128), 256, 0, stream>>>(
            ff1b, ff2w_b + (size_t)l*D_*2048, ff2_b + l*D_, bufB, M, D_, 2048);
        ln_kernel<<<M, 256, 0, stream>>>(x, xb, x, bufB, ln2_w + l*D_, ln2_b + l*D_, 1e-5f);
    }

    // 3. patch cross-attention
    meanpool_kernel<<<B_*NPATCH_, 256, 0, stream>>>(x, query);
    ln_kernel<<<B_*NPATCH_, 256, 0, stream>>>(qn, nullptr, query, nullptr, ca_ln_w, ca_ln_b, 1e-6f);
    ln_kernel<<<M, 256, 0, stream>>>(bufB, xb, x, nullptr, ca_ln_w, ca_ln_b, 1e-6f);
    mgemm_kernel<0,0><<<dim3(1024/128, M/128), 256, 0, stream>>>(
        xb, kvw_b, ca_qkv_b + 512, kvf, M, 1024, D_);
    gemm_kernel<<<dim3(D_/64, 1), 256, 0, stream>>>(
        qn, ca_qkv_w, ca_qkv_b, nullptr, qsm, 64, D_, D_, 0);
    patch_attn_kernel<<<B_*NPATCH_*H_/4, 256, 0, stream>>>(qsm, kvf, oca);
    gemm_kernel<<<dim3(D_/64, 1), 256, 0, stream>>>(
        oca, ca_out_w, ca_out_b, query, patches, 64, D_, D_, 0);

    // 4. final LayerNorms -> f32 outputs
    ln_kernel<<<M, 256, 0, stream>>>(out, nullptr, x, nullptr, norm_w, norm_b, 1e-6f);
    ln_kernel<<<B_*NPATCH_, 256, 0, stream>>>(
        out + (size_t)M*D_, nullptr, patches, nullptr, norm_w, norm_b, 1e-6f);
}

// Round 8
// 570.610 us; speedup vs baseline: 19.6477x; 1.0880x over previous
//
#include <hip/hip_runtime.h>
#include <hip/hip_bf16.h>

#define B_ 4
#define S_ 2048
#define D_ 512
#define H_ 8
#define HD_ 64
#define L_ 2
#define V_ 30000
#define NPATCH_ 16
#define PLEN_ 128

typedef short bf16x8 __attribute__((ext_vector_type(8)));
typedef float f32x4 __attribute__((ext_vector_type(4)));

__device__ __forceinline__ unsigned short f2bf(float f) {
    unsigned u = __float_as_uint(f);
    return (unsigned short)((u + 0x7FFFu + ((u >> 16) & 1u)) >> 16);   // RNE
}

// ---------------- merged f32 -> bf16 weight casts (1 launch) ----------------
#define C0_ (2*1536*512/4)
#define C1_ (2*512*512/4)
#define C2_ (2*2048*512/4)
#define C3_ (2*512*2048/4)
#define C4_ (1024*512/4)
__global__ __launch_bounds__(256) void cast5_kernel(
    const float* __restrict__ s0, const float* __restrict__ s1,
    const float* __restrict__ s2, const float* __restrict__ s3,
    const float* __restrict__ s4,
    unsigned short* __restrict__ d0, unsigned short* __restrict__ d1,
    unsigned short* __restrict__ d2, unsigned short* __restrict__ d3,
    unsigned short* __restrict__ d4)
{
    int i = blockIdx.x * 256 + threadIdx.x;
    const float* s; unsigned short* d;
    if      (i < C0_)                  { s = s0; d = d0; }
    else if ((i -= C0_) < C1_)         { s = s1; d = d1; }
    else if ((i -= C1_) < C2_)         { s = s2; d = d2; }
    else if ((i -= C2_) < C3_)         { s = s3; d = d3; }
    else if ((i -= C3_) < C4_)         { s = s4; d = d4; }
    else return;
    const float4 v = *reinterpret_cast<const float4*>(s + (size_t)i * 4);
    ushort4 o;
    o.x = f2bf(v.x); o.y = f2bf(v.y); o.z = f2bf(v.z); o.w = f2bf(v.w);
    *reinterpret_cast<ushort4*>(d + (size_t)i * 4) = o;
}

// ---------------- embed + n-gram hash add (f32 + bf16 shadow) -------------
__global__ __launch_bounds__(128) void embed_ngram_kernel(
    const int* __restrict__ bytes, const float* __restrict__ byte_emb,
    const float* __restrict__ ng_emb, float* __restrict__ x,
    unsigned short* __restrict__ xb)
{
    const int bs = blockIdx.x;
    const int s  = bs % S_;
    const int b  = bs / S_;
    const int d  = threadIdx.x * 4;
    const int* brow = bytes + (size_t)b * S_;

    const int c = brow[s];
    float4 v = *reinterpret_cast<const float4*>(byte_emb + (size_t)c * D_ + d);

    if (s >= 2) {
        int h = (brow[s-2]*961 + brow[s-1]*31 + brow[s]) % V_;
        const float4 g = *reinterpret_cast<const float4*>(ng_emb + ((size_t)0*V_ + h)*D_ + d);
        v.x += 0.25f*g.x; v.y += 0.25f*g.y; v.z += 0.25f*g.z; v.w += 0.25f*g.w;
    }
    if (s >= 3) {
        int h = (brow[s-3]*29791 + brow[s-2]*961 + brow[s-1]*31 + brow[s]) % V_;
        const float4 g = *reinterpret_cast<const float4*>(ng_emb + ((size_t)1*V_ + h)*D_ + d);
        v.x += 0.25f*g.x; v.y += 0.25f*g.y; v.z += 0.25f*g.z; v.w += 0.25f*g.w;
    }
    if (s >= 4) {
        int h = (brow[s-4]*23521 + brow[s-3]*29791 + brow[s-2]*961 + brow[s-1]*31 + brow[s]) % V_;
        const float4 g = *reinterpret_cast<const float4*>(ng_emb + ((size_t)2*V_ + h)*D_ + d);
        v.x += 0.25f*g.x; v.y += 0.25f*g.y; v.z += 0.25f*g.z; v.w += 0.25f*g.w;
    }
    *reinterpret_cast<float4*>(x + (size_t)bs * D_ + d) = v;
    ushort4 o;
    o.x = f2bf(v.x); o.y = f2bf(v.y); o.z = f2bf(v.z); o.w = f2bf(v.w);
    *reinterpret_cast<ushort4*>(xb + (size_t)bs * D_ + d) = o;
}

// ---------------- MFMA bf16 GEMM: Y = X @ W^T + bias [,relu] --------------
// BN=128: 128x128 tile (N>=1024 shapes). BN=64: 128x64 tile so N=512 shapes
// get 512 blocks = 2 blocks/CU (vs 1: no wave overlap).
template<int DO_RELU, int BF16OUT, int BN>
__global__ __launch_bounds__(256) void mgemm_kernel(
    const unsigned short* __restrict__ Xb, const unsigned short* __restrict__ Wb,
    const float* __restrict__ bias, void* __restrict__ Yout,
    int M, int N, int K)
{
    constexpr int NT  = BN / 32;       // B-subtiles per wave (4 or 2)
    constexpr int NLB = BN / 32;       // B staging iterations (4 or 2)
    __shared__ unsigned short As[128*64];
    __shared__ unsigned short Bs[BN*64];

    const int t    = threadIdx.x;
    const int lane = t & 63;
    const int w    = t >> 6;
    const int bm   = blockIdx.y * 128, bn = blockIdx.x * BN;
    const int l15  = lane & 15, lg = lane >> 4;
    const int wr   = w >> 1, wc = w & 1;

    int srow[4], scol[4];
#pragma unroll
    for (int i = 0; i < 4; ++i) {
        const int off = w*1024 + i*4096 + lane*16;
        srow[i] = off >> 7;
        scol[i] = ((off >> 4) & 7) ^ (srow[i] & 7);
    }

    f32x4 acc[4][NT];
#pragma unroll
    for (int mt = 0; mt < 4; ++mt)
#pragma unroll
        for (int nt = 0; nt < NT; ++nt) acc[mt][nt] = (f32x4){0.f,0.f,0.f,0.f};

    for (int kt = 0; kt < K; kt += 64) {
#pragma unroll
        for (int i = 0; i < 4; ++i) {
            const unsigned short* gA = Xb + (size_t)(bm + srow[i]) * K + kt + scol[i]*8;
            __builtin_amdgcn_global_load_lds(
                (const __attribute__((address_space(1))) void*)gA,
                (__attribute__((address_space(3))) void*)&As[w*512 + i*2048], 16, 0, 0);
        }
#pragma unroll
        for (int i = 0; i < NLB; ++i) {
            const unsigned short* gB = Wb + (size_t)(bn + srow[i]) * K + kt + scol[i]*8;
            __builtin_amdgcn_global_load_lds(
                (const __attribute__((address_space(1))) void*)gB,
                (__attribute__((address_space(3))) void*)&Bs[w*512 + i*2048], 16, 0, 0);
        }
        __syncthreads();

#pragma unroll
        for (int ks = 0; ks < 2; ++ks) {
            const int c16 = (ks*4 + lg) ^ (l15 & 7);
            bf16x8 a[4], b[NT];
#pragma unroll
            for (int mt = 0; mt < 4; ++mt)
                a[mt] = *reinterpret_cast<const bf16x8*>(&As[(wr*64 + mt*16 + l15)*64 + c16*8]);
#pragma unroll
            for (int nt = 0; nt < NT; ++nt)
                b[nt] = *reinterpret_cast<const bf16x8*>(&Bs[(wc*(BN/2) + nt*16 + l15)*64 + c16*8]);
#pragma unroll
            for (int mt = 0; mt < 4; ++mt)
#pragma unroll
                for (int nt = 0; nt < NT; ++nt)
                    acc[mt][nt] = __builtin_amdgcn_mfma_f32_16x16x32_bf16(
                        a[mt], b[nt], acc[mt][nt], 0, 0, 0);
        }
        __syncthreads();
    }

    float bv[NT];
#pragma unroll
    for (int nt = 0; nt < NT; ++nt) bv[nt] = bias[bn + wc*(BN/2) + nt*16 + l15];

#pragma unroll
    for (int mt = 0; mt < 4; ++mt) {
#pragma unroll
        for (int nt = 0; nt < NT; ++nt) {
            const int n = bn + wc*(BN/2) + nt*16 + l15;
#pragma unroll
            for (int r = 0; r < 4; ++r) {
                const int m = bm + wr*64 + mt*16 + 4*lg + r;
                float v = acc[mt][nt][r] + bv[nt];
                if (DO_RELU) v = fmaxf(v, 0.f);
                if (BF16OUT)
                    ((unsigned short*)Yout)[(size_t)m * N + n] = f2bf(v);
                else
                    ((float*)Yout)[(size_t)m * N + n] = v;
            }
        }
    }
}

// ---------------- f32 vector GEMM (small M=64 cases only) ------------------
__global__ __launch_bounds__(256) void gemm_kernel(
    const float* __restrict__ X, const float* __restrict__ W,
    const float* __restrict__ bias, const float* __restrict__ resid,
    float* __restrict__ Y, int M, int N, int K, int do_relu)
{
    __shared__ float As[16][68];
    __shared__ float Bs[16][68];
    const int tid = threadIdx.x;
    const int bm = blockIdx.y * 64, bn = blockIdx.x * 64;
    const int ty = tid >> 4, tx = tid & 15;
    const int lrow = tid >> 2, lc4 = (tid & 3) * 4;

    float acc[4][4];
#pragma unroll
    for (int i = 0; i < 4; ++i)
#pragma unroll
        for (int j = 0; j < 4; ++j) acc[i][j] = 0.f;

    for (int k0 = 0; k0 < K; k0 += 16) {
        const float4 xv = *reinterpret_cast<const float4*>(X + (size_t)(bm + lrow) * K + k0 + lc4);
        const float4 wv = *reinterpret_cast<const float4*>(W + (size_t)(bn + lrow) * K + k0 + lc4);
        __syncthreads();
        As[lc4+0][lrow] = xv.x; As[lc4+1][lrow] = xv.y;
        As[lc4+2][lrow] = xv.z; As[lc4+3][lrow] = xv.w;
        Bs[lc4+0][lrow] = wv.x; Bs[lc4+1][lrow] = wv.y;
        Bs[lc4+2][lrow] = wv.z; Bs[lc4+3][lrow] = wv.w;
        __syncthreads();
#pragma unroll
        for (int kk = 0; kk < 16; ++kk) {
            float a0 = As[kk][ty*4+0], a1 = As[kk][ty*4+1], a2 = As[kk][ty*4+2], a3 = As[kk][ty*4+3];
            float b0 = Bs[kk][tx*4+0], b1 = Bs[kk][tx*4+1], b2 = Bs[kk][tx*4+2], b3 = Bs[kk][tx*4+3];
            acc[0][0] += a0*b0; acc[0][1] += a0*b1; acc[0][2] += a0*b2; acc[0][3] += a0*b3;
            acc[1][0] += a1*b0; acc[1][1] += a1*b1; acc[1][2] += a1*b2; acc[1][3] += a1*b3;
            acc[2][0] += a2*b0; acc[2][1] += a2*b1; acc[2][2] += a2*b2; acc[2][3] += a2*b3;
            acc[3][0] += a3*b0; acc[3][1] += a3*b1; acc[3][2] += a3*b2; acc[3][3] += a3*b3;
        }
    }

#pragma unroll
    for (int i = 0; i < 4; ++i) {
        const int m = bm + ty*4 + i;
#pragma unroll
        for (int j = 0; j < 4; ++j) {
            const int n = bn + tx*4 + j;
            float v = acc[i][j] + bias[n];
            if (do_relu) v = fmaxf(v, 0.f);
            if (resid) v += resid[(size_t)m * N + n];
            Y[(size_t)m * N + n] = v;
        }
    }
}

// ---------------- MFMA bf16 causal flash attention ------------------------
// Folded triangle (pair {qp, 31-qp} = uniform 33 tiles/block) + async-STAGE:
// K/V of tile t+1 loaded to REGISTERS right after the "LDS ready" barrier,
// so global latency hides under QK^T/softmax/PV compute (T14).
__global__ __launch_bounds__(256) void attn_mfma_kernel(
    const unsigned short* __restrict__ qkvb, unsigned short* __restrict__ ob)
{
    __shared__ unsigned short Ks[64*72];
    __shared__ unsigned short Vt[64*72];
    __shared__ unsigned short Plds[4*16*72];

    const int t    = threadIdx.x;
    const int lane = t & 63;
    const int w    = t >> 6;
    const int qp   = blockIdx.x;          // 0..15 (pair index)
    const int bh   = blockIdx.y;          // 0..31
    const int h    = bh & 7;
    const int b    = bh >> 3;

    const unsigned short* base = qkvb + (size_t)b * S_ * 1536;
    const int l15 = lane & 15, lg = lane >> 4;
    const int skey = t >> 2, sd0 = (t & 3) * 16;
    const int sg = sd0 >> 4;
    const int scs = ((skey >> 3) ^ sg) * 8 + (skey & 7);  // swizzled V^T col
    unsigned short* pw_base = Plds + w*16*72;

    bf16x8 k0r, k1r, v0r, v1r;
#define LOADREG(KT) { \
        const unsigned short* srcK_ = base + (size_t)((KT) + skey) * 1536 + 512 + h*64 + sd0; \
        k0r = *reinterpret_cast<const bf16x8*>(srcK_); \
        k1r = *reinterpret_cast<const bf16x8*>(srcK_ + 8); \
        v0r = *reinterpret_cast<const bf16x8*>(srcK_ + 512); \
        v1r = *reinterpret_cast<const bf16x8*>(srcK_ + 520); }

    LOADREG(0);

#pragma unroll
    for (int half = 0; half < 2; ++half) {
        const int qb  = half ? (31 - qp) : qp;
        const int q0w = qb * 64 + w * 16;

        bf16x8 qf0, qf1;
        {
            const unsigned short* qr = base + (size_t)(q0w + l15) * 1536 + h*64 + lg*8;
            qf0 = *reinterpret_cast<const bf16x8*>(qr);
            qf1 = *reinterpret_cast<const bf16x8*>(qr + 32);
        }

        f32x4 oacc[4];
#pragma unroll
        for (int i = 0; i < 4; ++i) oacc[i] = (f32x4){0.f,0.f,0.f,0.f};
        float mrow[4] = {-INFINITY,-INFINITY,-INFINITY,-INFINITY};
        float lrow[4] = {0.f,0.f,0.f,0.f};

        const int ntiles = qb + 1;
        for (int tile = 0; tile < ntiles; ++tile) {
            const int kt = tile * 64;
            __syncthreads();   // LDS consumed by previous compute
            // ---- write prefetched regs to LDS ----
            *reinterpret_cast<bf16x8*>(&Ks[skey*72 + sd0])     = k0r;
            *reinterpret_cast<bf16x8*>(&Ks[skey*72 + sd0 + 8]) = k1r;
#pragma unroll
            for (int j = 0; j < 8; ++j) Vt[(sd0+j)*72 + scs]   = (unsigned short)v0r[j];
#pragma unroll
            for (int j = 0; j < 8; ++j) Vt[(sd0+8+j)*72 + scs] = (unsigned short)v1r[j];
            __syncthreads();   // LDS ready
            // ---- prefetch next tile (this half or start of next half) ----
            const int nkt = (tile + 1 < ntiles) ? (kt + 64) : 0;
            LOADREG(nkt);

            // ---- QK^T ----
            f32x4 sacc[4];
#pragma unroll
            for (int kt16 = 0; kt16 < 4; ++kt16) {
                sacc[kt16] = (f32x4){0.f,0.f,0.f,0.f};
                const unsigned short* kp = &Ks[(kt16*16 + l15)*72 + lg*8];
                bf16x8 k0 = *reinterpret_cast<const bf16x8*>(kp);
                bf16x8 k1 = *reinterpret_cast<const bf16x8*>(kp + 32);
                sacc[kt16] = __builtin_amdgcn_mfma_f32_16x16x32_bf16(qf0, k0, sacc[kt16], 0, 0, 0);
                sacc[kt16] = __builtin_amdgcn_mfma_f32_16x16x32_bf16(qf1, k1, sacc[kt16], 0, 0, 0);
            }

            // ---- scale + causal mask + online softmax ----
            const bool diag = (tile == ntiles - 1);
            float sv[4][4];
#pragma unroll
            for (int kt16 = 0; kt16 < 4; ++kt16) {
#pragma unroll
                for (int r = 0; r < 4; ++r) {
                    float s = sacc[kt16][r] * 0.125f;
                    if (diag) {
                        const int key = kt + kt16*16 + l15;
                        const int q   = q0w + 4*lg + r;
                        if (key > q) s = -INFINITY;
                    }
                    sv[kt16][r] = s;
                }
            }
#pragma unroll
            for (int r = 0; r < 4; ++r) {
                float tm = fmaxf(fmaxf(sv[0][r], sv[1][r]), fmaxf(sv[2][r], sv[3][r]));
#pragma unroll
                for (int off = 8; off; off >>= 1) tm = fmaxf(tm, __shfl_xor(tm, off, 64));
                const float nm = fmaxf(mrow[r], tm);
                const float al = __expf(mrow[r] - nm);
                mrow[r] = nm;
                float ps = 0.f;
#pragma unroll
                for (int kt16 = 0; kt16 < 4; ++kt16) {
                    const float p = __expf(sv[kt16][r] - nm);
                    ps += p;
                    pw_base[(4*lg + r)*72 + kt16*16 + l15] = f2bf(p);
                }
#pragma unroll
                for (int off = 8; off; off >>= 1) ps += __shfl_xor(ps, off, 64);
                lrow[r] = lrow[r]*al + ps;
#pragma unroll
                for (int dt = 0; dt < 4; ++dt) oacc[dt][r] *= al;
            }

            // ---- PV ----
            const unsigned short* pr = &pw_base[l15*72 + lg*8];
            bf16x8 pa0 = *reinterpret_cast<const bf16x8*>(pr);
            bf16x8 pa1 = *reinterpret_cast<const bf16x8*>(pr + 32);
#pragma unroll
            for (int dt = 0; dt < 4; ++dt) {
                const unsigned short* vp = &Vt[(dt*16 + l15)*72 + (lg ^ dt)*8];
                bf16x8 v0 = *reinterpret_cast<const bf16x8*>(vp);
                bf16x8 v1 = *reinterpret_cast<const bf16x8*>(vp + 32);
                oacc[dt] = __builtin_amdgcn_mfma_f32_16x16x32_bf16(pa0, v0, oacc[dt], 0, 0, 0);
                oacc[dt] = __builtin_amdgcn_mfma_f32_16x16x32_bf16(pa1, v1, oacc[dt], 0, 0, 0);
            }
        }

        // ---- epilogue for this half ----
#pragma unroll
        for (int dt = 0; dt < 4; ++dt) {
#pragma unroll
            for (int r = 0; r < 4; ++r) {
                const int q = q0w + 4*lg + r;
                ob[((size_t)b*S_ + q)*D_ + h*64 + dt*16 + l15] = f2bf(oacc[dt][r] / lrow[r]);
            }
        }
    }
#undef LOADREG
}

// ---------------- LayerNorm (residual add, optional bf16 shadow out) -------
__global__ __launch_bounds__(256) void ln_kernel(
    float* __restrict__ dst, unsigned short* __restrict__ dst2,
    const float* __restrict__ src, const float* __restrict__ add,
    const float* __restrict__ w, const float* __restrict__ b, float eps)
{
    const int row = blockIdx.x, tid = threadIdx.x;
    const int lane = tid & 63, wave = tid >> 6;
    float2 v = *reinterpret_cast<const float2*>(src + (size_t)row * D_ + tid*2);
    if (add) {
        float2 a = *reinterpret_cast<const float2*>(add + (size_t)row * D_ + tid*2);
        v.x += a.x; v.y += a.y;
    }
    __shared__ float red[8];
    float s = v.x + v.y;
#pragma unroll
    for (int off = 32; off; off >>= 1) s += __shfl_xor(s, off, 64);
    if (lane == 0) red[wave] = s;
    __syncthreads();
    const float mean = (red[0]+red[1]+red[2]+red[3]) * (1.f/D_);
    const float d0 = v.x - mean, d1 = v.y - mean;
    float sq = d0*d0 + d1*d1;
#pragma unroll
    for (int off = 32; off; off >>= 1) sq += __shfl_xor(sq, off, 64);
    if (lane == 0) red[4+wave] = sq;
    __syncthreads();
    const float var = (red[4]+red[5]+red[6]+red[7]) * (1.f/D_);
    const float inv = rsqrtf(var + eps);
    const float o0 = d0*inv*w[tid*2] + b[tid*2];
    const float o1 = d1*inv*w[tid*2+1] + b[tid*2+1];
    *reinterpret_cast<float2*>(dst + (size_t)row * D_ + tid*2) = make_float2(o0, o1);
    if (dst2) {
        ushort2 u; u.x = f2bf(o0); u.y = f2bf(o1);
        *reinterpret_cast<ushort2*>(dst2 + (size_t)row * D_ + tid*2) = u;
    }
}

// ---------------- patch mean-pool ----------------
__global__ __launch_bounds__(256) void meanpool_kernel(
    const float* __restrict__ x, float* __restrict__ query)
{
    const int bp = blockIdx.x;
    const int d = threadIdx.x * 2;
    const float* base = x + (size_t)bp * PLEN_ * D_ + d;
    float s0 = 0.f, s1 = 0.f;
    for (int l = 0; l < PLEN_; ++l) {
        float2 v = *reinterpret_cast<const float2*>(base + (size_t)l * D_);
        s0 += v.x; s1 += v.y;
    }
    query[(size_t)bp*D_ + d]     = s0 * (1.f/PLEN_);
    query[(size_t)bp*D_ + d + 1] = s1 * (1.f/PLEN_);
}

// ---------------- patch cross-attention, one wave per (b,p,h) -------------
__global__ __launch_bounds__(256) void patch_attn_kernel(
    const float* __restrict__ qbuf, const float* __restrict__ kv,
    float* __restrict__ o)
{
    const int wid  = blockIdx.x * 4 + (threadIdx.x >> 6);
    const int lane = threadIdx.x & 63;
    const int h  = wid % H_;
    const int bp = wid / H_;
    const float qv = qbuf[(size_t)bp*D_ + h*HD_ + lane] * 0.125f;
    const float* base = kv + (size_t)bp * PLEN_ * 1024 + h*HD_;

    float m = -INFINITY, l = 0.f, acc = 0.f;
    for (int t = 0; t < PLEN_; ++t) {
        const float* row = base + (size_t)t * 1024;
        float s = qv * row[lane];
#pragma unroll
        for (int off = 32; off; off >>= 1) s += __shfl_xor(s, off, 64);
        const float vv = row[512 + lane];
        const float nm = fmaxf(m, s);
        const float al = __expf(m - nm);
        const float p  = __expf(s - nm);
        l = l * al + p;
        acc = acc * al + p * vv;
        m = nm;
    }
    o[(size_t)bp*D_ + h*HD_ + lane] = acc / l;
}

extern "C" void kernel_launch(void* const* d_in, const int* in_sizes, int n_in,
                              void* d_out, int out_size, void* d_ws, size_t ws_size,
                              hipStream_t stream)
{
    const int*   byte_seq = (const int*)d_in[0];
    const float* byte_emb = (const float*)d_in[2];
    const float* ng_emb   = (const float*)d_in[3];
    const float* qkv_w = (const float*)d_in[4];
    const float* qkv_b = (const float*)d_in[5];
    const float* out_w = (const float*)d_in[6];
    const float* out_b = (const float*)d_in[7];
    const float* ln1_w = (const float*)d_in[8];
    const float* ln1_b = (const float*)d_in[9];
    const float* ln2_w = (const float*)d_in[10];
    const float* ln2_b = (const float*)d_in[11];
    const float* ff1_w = (const float*)d_in[12];
    const float* ff1_b = (const float*)d_in[13];
    const float* ff2_w = (const float*)d_in[14];
    const float* ff2_b = (const float*)d_in[15];
    const float* ca_qkv_w = (const float*)d_in[16];
    const float* ca_qkv_b = (const float*)d_in[17];
    const float* ca_out_w = (const float*)d_in[18];
    const float* ca_out_b = (const float*)d_in[19];
    const float* ca_ln_w  = (const float*)d_in[20];
    const float* ca_ln_b  = (const float*)d_in[21];
    const float* norm_w   = (const float*)d_in[22];
    const float* norm_b   = (const float*)d_in[23];
    float* out = (float*)d_out;

    char* ws = (char*)d_ws;
    const size_t MB = 1024*1024;
    float*          x     = (float*)(ws);
    char*           bufA  = ws + 16*MB;
    float*          bufB  = (float*)(ws + 48*MB);
    unsigned short* ob    = (unsigned short*)(ws + 64*MB);
    unsigned short* xb    = (unsigned short*)(ws + 72*MB);
    unsigned short* qkvw_b = (unsigned short*)(ws + 80*MB);
    unsigned short* outw_b = (unsigned short*)(ws + 83*MB);
    unsigned short* ff1w_b = (unsigned short*)(ws + 84*MB);
    unsigned short* ff2w_b = (unsigned short*)(ws + 88*MB);
    unsigned short* kvw_b  = (unsigned short*)(ws + 92*MB);
    float* query   = (float*)(ws + 93*MB);
    float* qn      = query + 64*512;
    float* qsm     = qn + 64*512;
    float* oca     = qsm + 64*512;
    float* patches = oca + 64*512;

    unsigned short* qkvb = (unsigned short*)bufA;
    unsigned short* ff1b = (unsigned short*)bufA;
    float*          kvf  = (float*)bufA;

    const int M = B_ * S_;

    // 0. one-time weight casts to bf16 (single launch)
    cast5_kernel<<<(C0_+C1_+C2_+C3_+C4_+255)/256, 256, 0, stream>>>(
        qkv_w, out_w, ff1_w, ff2_w, ca_qkv_w + 512*512,
        qkvw_b, outw_b, ff1w_b, ff2w_b, kvw_b);

    // 1. byte embedding + n-gram hash adds
    embed_ngram_kernel<<<M, 128, 0, stream>>>(byte_seq, byte_emb, ng_emb, x, xb);

    // 2. transformer layers
    for (int l = 0; l < L_; ++l) {
        mgemm_kernel<0,1,128><<<dim3(1536/128, M/128), 256, 0, stream>>>(
            xb, qkvw_b + (size_t)l*1536*D_, qkv_b + l*1536, qkvb, M, 1536, D_);
        attn_mfma_kernel<<<dim3(S_/128, B_*H_), 256, 0, stream>>>(qkvb, ob);
        mgemm_kernel<0,0,64><<<dim3(D_/64, M/128), 256, 0, stream>>>(
            ob, outw_b + (size_t)l*D_*D_, out_b + l*D_, bufB, M, D_, D_);
        ln_kernel<<<M, 256, 0, stream>>>(x, xb, x, bufB, ln1_w + l*D_, ln1_b + l*D_, 1e-5f);
        mgemm_kernel<1,1,128><<<dim3(2048/128, M/128), 256, 0, stream>>>(
            xb, ff1w_b + (size_t)l*2048*D_, ff1_b + l*2048, ff1b, M, 2048, D_);
        mgemm_kernel<0,0,64><<<dim3(D_/64, M/128), 256, 0, stream>>>(
            ff1b, ff2w_b + (size_t)l*D_*2048, ff2_b + l*D_, bufB, M, D_, 2048);
        ln_kernel<<<M, 256, 0, stream>>>(x, xb, x, bufB, ln2_w + l*D_, ln2_b + l*D_, 1e-5f);
    }

    // 3. patch cross-attention
    meanpool_kernel<<<B_*NPATCH_, 256, 0, stream>>>(x, query);
    ln_kernel<<<B_*NPATCH_, 256, 0, stream>>>(qn, nullptr, query, nullptr, ca_ln_w, ca_ln_b, 1e-6f);
    ln_kernel<<<M, 256, 0, stream>>>(bufB, xb, x, nullptr, ca_ln_w, ca_ln_b, 1e-6f);
    mgemm_kernel<0,0,128><<<dim3(1024/128, M/128), 256, 0, stream>>>(
        xb, kvw_b, ca_qkv_b + 512, kvf, M, 1024, D_);
    gemm_kernel<<<dim3(D_/64, 1), 256, 0, stream>>>(
        qn, ca_qkv_w, ca_qkv_b, nullptr, qsm, 64, D_, D_, 0);
    patch_attn_kernel<<<B_*NPATCH_*H_/4, 256, 0, stream>>>(qsm, kvf, oca);
    gemm_kernel<<<dim3(D_/64, 1), 256, 0, stream>>>(
        oca, ca_out_w, ca_out_b, query, patches, 64, D_, D_, 0);

    // 4. final LayerNorms -> f32 outputs
    ln_kernel<<<M, 256, 0, stream>>>(out, nullptr, x, nullptr, norm_w, norm_b, 1e-6f);
    ln_kernel<<<B_*NPATCH_, 256, 0, stream>>>(
        out + (size_t)M*D_, nullptr, patches, nullptr, norm_w, norm_b, 1e-6f);
}

// Round 9
// 567.974 us; speedup vs baseline: 19.7389x; 1.0046x over previous
//
#include <hip/hip_runtime.h>
#include <hip/hip_bf16.h>

#define B_ 4
#define S_ 2048
#define D_ 512
#define H_ 8
#define HD_ 64
#define L_ 2
#define V_ 30000
#define NPATCH_ 16
#define PLEN_ 128

typedef short bf16x8 __attribute__((ext_vector_type(8)));
typedef float f32x4 __attribute__((ext_vector_type(4)));

__device__ __forceinline__ unsigned short f2bf(float f) {
    unsigned u = __float_as_uint(f);
    return (unsigned short)((u + 0x7FFFu + ((u >> 16) & 1u)) >> 16);   // RNE
}

// ---------------- merged f32 -> bf16 weight casts (1 launch) ----------------
#define C0_ (2*1536*512/4)
#define C1_ (2*512*512/4)
#define C2_ (2*2048*512/4)
#define C3_ (2*512*2048/4)
#define C4_ (1024*512/4)
__global__ __launch_bounds__(256) void cast5_kernel(
    const float* __restrict__ s0, const float* __restrict__ s1,
    const float* __restrict__ s2, const float* __restrict__ s3,
    const float* __restrict__ s4,
    unsigned short* __restrict__ d0, unsigned short* __restrict__ d1,
    unsigned short* __restrict__ d2, unsigned short* __restrict__ d3,
    unsigned short* __restrict__ d4)
{
    int i = blockIdx.x * 256 + threadIdx.x;
    const float* s; unsigned short* d;
    if      (i < C0_)                  { s = s0; d = d0; }
    else if ((i -= C0_) < C1_)         { s = s1; d = d1; }
    else if ((i -= C1_) < C2_)         { s = s2; d = d2; }
    else if ((i -= C2_) < C3_)         { s = s3; d = d3; }
    else if ((i -= C3_) < C4_)         { s = s4; d = d4; }
    else return;
    const float4 v = *reinterpret_cast<const float4*>(s + (size_t)i * 4);
    ushort4 o;
    o.x = f2bf(v.x); o.y = f2bf(v.y); o.z = f2bf(v.z); o.w = f2bf(v.w);
    *reinterpret_cast<ushort4*>(d + (size_t)i * 4) = o;
}

// ---------------- embed + n-gram hash add (f32 + bf16 shadow) -------------
__global__ __launch_bounds__(128) void embed_ngram_kernel(
    const int* __restrict__ bytes, const float* __restrict__ byte_emb,
    const float* __restrict__ ng_emb, float* __restrict__ x,
    unsigned short* __restrict__ xb)
{
    const int bs = blockIdx.x;
    const int s  = bs % S_;
    const int b  = bs / S_;
    const int d  = threadIdx.x * 4;
    const int* brow = bytes + (size_t)b * S_;

    const int c = brow[s];
    float4 v = *reinterpret_cast<const float4*>(byte_emb + (size_t)c * D_ + d);

    if (s >= 2) {
        int h = (brow[s-2]*961 + brow[s-1]*31 + brow[s]) % V_;
        const float4 g = *reinterpret_cast<const float4*>(ng_emb + ((size_t)0*V_ + h)*D_ + d);
        v.x += 0.25f*g.x; v.y += 0.25f*g.y; v.z += 0.25f*g.z; v.w += 0.25f*g.w;
    }
    if (s >= 3) {
        int h = (brow[s-3]*29791 + brow[s-2]*961 + brow[s-1]*31 + brow[s]) % V_;
        const float4 g = *reinterpret_cast<const float4*>(ng_emb + ((size_t)1*V_ + h)*D_ + d);
        v.x += 0.25f*g.x; v.y += 0.25f*g.y; v.z += 0.25f*g.z; v.w += 0.25f*g.w;
    }
    if (s >= 4) {
        int h = (brow[s-4]*23521 + brow[s-3]*29791 + brow[s-2]*961 + brow[s-1]*31 + brow[s]) % V_;
        const float4 g = *reinterpret_cast<const float4*>(ng_emb + ((size_t)2*V_ + h)*D_ + d);
        v.x += 0.25f*g.x; v.y += 0.25f*g.y; v.z += 0.25f*g.z; v.w += 0.25f*g.w;
    }
    *reinterpret_cast<float4*>(x + (size_t)bs * D_ + d) = v;
    ushort4 o;
    o.x = f2bf(v.x); o.y = f2bf(v.y); o.z = f2bf(v.z); o.w = f2bf(v.w);
    *reinterpret_cast<ushort4*>(xb + (size_t)bs * D_ + d) = o;
}

// ---------------- MFMA bf16 GEMM: Y = X @ W^T + bias [,relu] --------------
template<int DO_RELU, int BF16OUT, int BN>
__global__ __launch_bounds__(256) void mgemm_kernel(
    const unsigned short* __restrict__ Xb, const unsigned short* __restrict__ Wb,
    const float* __restrict__ bias, void* __restrict__ Yout,
    int M, int N, int K)
{
    constexpr int NT  = BN / 32;
    constexpr int NLB = BN / 32;
    __shared__ unsigned short As[128*64];
    __shared__ unsigned short Bs[BN*64];

    const int t    = threadIdx.x;
    const int lane = t & 63;
    const int w    = t >> 6;
    const int bm   = blockIdx.y * 128, bn = blockIdx.x * BN;
    const int l15  = lane & 15, lg = lane >> 4;
    const int wr   = w >> 1, wc = w & 1;

    int srow[4], scol[4];
#pragma unroll
    for (int i = 0; i < 4; ++i) {
        const int off = w*1024 + i*4096 + lane*16;
        srow[i] = off >> 7;
        scol[i] = ((off >> 4) & 7) ^ (srow[i] & 7);
    }

    f32x4 acc[4][NT];
#pragma unroll
    for (int mt = 0; mt < 4; ++mt)
#pragma unroll
        for (int nt = 0; nt < NT; ++nt) acc[mt][nt] = (f32x4){0.f,0.f,0.f,0.f};

    for (int kt = 0; kt < K; kt += 64) {
#pragma unroll
        for (int i = 0; i < 4; ++i) {
            const unsigned short* gA = Xb + (size_t)(bm + srow[i]) * K + kt + scol[i]*8;
            __builtin_amdgcn_global_load_lds(
                (const __attribute__((address_space(1))) void*)gA,
                (__attribute__((address_space(3))) void*)&As[w*512 + i*2048], 16, 0, 0);
        }
#pragma unroll
        for (int i = 0; i < NLB; ++i) {
            const unsigned short* gB = Wb + (size_t)(bn + srow[i]) * K + kt + scol[i]*8;
            __builtin_amdgcn_global_load_lds(
                (const __attribute__((address_space(1))) void*)gB,
                (__attribute__((address_space(3))) void*)&Bs[w*512 + i*2048], 16, 0, 0);
        }
        __syncthreads();

#pragma unroll
        for (int ks = 0; ks < 2; ++ks) {
            const int c16 = (ks*4 + lg) ^ (l15 & 7);
            bf16x8 a[4], b[NT];
#pragma unroll
            for (int mt = 0; mt < 4; ++mt)
                a[mt] = *reinterpret_cast<const bf16x8*>(&As[(wr*64 + mt*16 + l15)*64 + c16*8]);
#pragma unroll
            for (int nt = 0; nt < NT; ++nt)
                b[nt] = *reinterpret_cast<const bf16x8*>(&Bs[(wc*(BN/2) + nt*16 + l15)*64 + c16*8]);
#pragma unroll
            for (int mt = 0; mt < 4; ++mt)
#pragma unroll
                for (int nt = 0; nt < NT; ++nt)
                    acc[mt][nt] = __builtin_amdgcn_mfma_f32_16x16x32_bf16(
                        a[mt], b[nt], acc[mt][nt], 0, 0, 0);
        }
        __syncthreads();
    }

    float bv[NT];
#pragma unroll
    for (int nt = 0; nt < NT; ++nt) bv[nt] = bias[bn + wc*(BN/2) + nt*16 + l15];

#pragma unroll
    for (int mt = 0; mt < 4; ++mt) {
#pragma unroll
        for (int nt = 0; nt < NT; ++nt) {
            const int n = bn + wc*(BN/2) + nt*16 + l15;
#pragma unroll
            for (int r = 0; r < 4; ++r) {
                const int m = bm + wr*64 + mt*16 + 4*lg + r;
                float v = acc[mt][nt][r] + bv[nt];
                if (DO_RELU) v = fmaxf(v, 0.f);
                if (BF16OUT)
                    ((unsigned short*)Yout)[(size_t)m * N + n] = f2bf(v);
                else
                    ((float*)Yout)[(size_t)m * N + n] = v;
            }
        }
    }
}

// ---------------- f32 vector GEMM (small M=64 cases only) ------------------
__global__ __launch_bounds__(256) void gemm_kernel(
    const float* __restrict__ X, const float* __restrict__ W,
    const float* __restrict__ bias, const float* __restrict__ resid,
    float* __restrict__ Y, int M, int N, int K, int do_relu)
{
    __shared__ float As[16][68];
    __shared__ float Bs[16][68];
    const int tid = threadIdx.x;
    const int bm = blockIdx.y * 64, bn = blockIdx.x * 64;
    const int ty = tid >> 4, tx = tid & 15;
    const int lrow = tid >> 2, lc4 = (tid & 3) * 4;

    float acc[4][4];
#pragma unroll
    for (int i = 0; i < 4; ++i)
#pragma unroll
        for (int j = 0; j < 4; ++j) acc[i][j] = 0.f;

    for (int k0 = 0; k0 < K; k0 += 16) {
        const float4 xv = *reinterpret_cast<const float4*>(X + (size_t)(bm + lrow) * K + k0 + lc4);
        const float4 wv = *reinterpret_cast<const float4*>(W + (size_t)(bn + lrow) * K + k0 + lc4);
        __syncthreads();
        As[lc4+0][lrow] = xv.x; As[lc4+1][lrow] = xv.y;
        As[lc4+2][lrow] = xv.z; As[lc4+3][lrow] = xv.w;
        Bs[lc4+0][lrow] = wv.x; Bs[lc4+1][lrow] = wv.y;
        Bs[lc4+2][lrow] = wv.z; Bs[lc4+3][lrow] = wv.w;
        __syncthreads();
#pragma unroll
        for (int kk = 0; kk < 16; ++kk) {
            float a0 = As[kk][ty*4+0], a1 = As[kk][ty*4+1], a2 = As[kk][ty*4+2], a3 = As[kk][ty*4+3];
            float b0 = Bs[kk][tx*4+0], b1 = Bs[kk][tx*4+1], b2 = Bs[kk][tx*4+2], b3 = Bs[kk][tx*4+3];
            acc[0][0] += a0*b0; acc[0][1] += a0*b1; acc[0][2] += a0*b2; acc[0][3] += a0*b3;
            acc[1][0] += a1*b0; acc[1][1] += a1*b1; acc[1][2] += a1*b2; acc[1][3] += a1*b3;
            acc[2][0] += a2*b0; acc[2][1] += a2*b1; acc[2][2] += a2*b2; acc[2][3] += a2*b3;
            acc[3][0] += a3*b0; acc[3][1] += a3*b1; acc[3][2] += a3*b2; acc[3][3] += a3*b3;
        }
    }

#pragma unroll
    for (int i = 0; i < 4; ++i) {
        const int m = bm + ty*4 + i;
#pragma unroll
        for (int j = 0; j < 4; ++j) {
            const int n = bn + tx*4 + j;
            float v = acc[i][j] + bias[n];
            if (do_relu) v = fmaxf(v, 0.f);
            if (resid) v += resid[(size_t)m * N + n];
            Y[(size_t)m * N + n] = v;
        }
    }
}

// ---------------- MFMA bf16 causal flash attention v3 ----------------------
// KVBLK=128 (halves barriers / softmax-reduce / stage iterations per key).
// Folded triangle: tiles(qb) = (qb+2)>>1; pair {qp, 31-qp} = 17 tiles uniform.
// Mask only on last tile (covers both parities). Async register prefetch.
__global__ __launch_bounds__(256) void attn_mfma_kernel(
    const unsigned short* __restrict__ qkvb, unsigned short* __restrict__ ob)
{
    __shared__ unsigned short Ks[128*72];     // [key][d]   18.4 KB
    __shared__ unsigned short Vt[64*136];     // [d][key]   17.4 KB (transposed)
    __shared__ unsigned short Plds[4*16*136]; // per-wave [16 q][128 key]

    const int t    = threadIdx.x;
    const int lane = t & 63;
    const int w    = t >> 6;
    const int qp   = blockIdx.x;          // 0..15 (pair index)
    const int bh   = blockIdx.y;          // 0..31
    const int h    = bh & 7;
    const int b    = bh >> 3;

    const unsigned short* base = qkvb + (size_t)b * S_ * 1536;
    const int l15 = lane & 15, lg = lane >> 4;
    const int skey = t >> 1;              // staging key 0..127
    const int sd0  = (t & 1) * 32;        // staging d-range base
    // V^T col swizzle: pos = ((key>>3) ^ ((d&32)>>4))*8 + (key&7)
    const int scs  = (((skey >> 3) ^ ((t & 1) << 1)) << 3) + (skey & 7);
    unsigned short* pw_base = Plds + w*16*136;

    bf16x8 kr0, kr1, kr2, kr3, vr0, vr1, vr2, vr3;
#define LOADREG(KT) { \
        const unsigned short* p_ = base + (size_t)((KT) + skey) * 1536 + 512 + h*64 + sd0; \
        kr0 = *reinterpret_cast<const bf16x8*>(p_);       \
        kr1 = *reinterpret_cast<const bf16x8*>(p_ + 8);   \
        kr2 = *reinterpret_cast<const bf16x8*>(p_ + 16);  \
        kr3 = *reinterpret_cast<const bf16x8*>(p_ + 24);  \
        vr0 = *reinterpret_cast<const bf16x8*>(p_ + 512); \
        vr1 = *reinterpret_cast<const bf16x8*>(p_ + 520); \
        vr2 = *reinterpret_cast<const bf16x8*>(p_ + 528); \
        vr3 = *reinterpret_cast<const bf16x8*>(p_ + 536); }

    LOADREG(0);

#pragma unroll
    for (int half = 0; half < 2; ++half) {
        const int qb  = half ? (31 - qp) : qp;
        const int q0w = qb * 64 + w * 16;

        bf16x8 qf0, qf1;
        {
            const unsigned short* qr = base + (size_t)(q0w + l15) * 1536 + h*64 + lg*8;
            qf0 = *reinterpret_cast<const bf16x8*>(qr);
            qf1 = *reinterpret_cast<const bf16x8*>(qr + 32);
        }

        f32x4 oacc[4];
#pragma unroll
        for (int i = 0; i < 4; ++i) oacc[i] = (f32x4){0.f,0.f,0.f,0.f};
        float mrow[4] = {-INFINITY,-INFINITY,-INFINITY,-INFINITY};
        float lrow[4] = {0.f,0.f,0.f,0.f};

        const int ntiles = (qb + 2) >> 1;
        for (int tile = 0; tile < ntiles; ++tile) {
            const int kt = tile * 128;
            __syncthreads();   // LDS consumed by previous compute
            // ---- write prefetched regs to LDS ----
            *reinterpret_cast<bf16x8*>(&Ks[skey*72 + sd0])      = kr0;
            *reinterpret_cast<bf16x8*>(&Ks[skey*72 + sd0 + 8])  = kr1;
            *reinterpret_cast<bf16x8*>(&Ks[skey*72 + sd0 + 16]) = kr2;
            *reinterpret_cast<bf16x8*>(&Ks[skey*72 + sd0 + 24]) = kr3;
#pragma unroll
            for (int j = 0; j < 8; ++j) Vt[(sd0+j)*136    + scs] = (unsigned short)vr0[j];
#pragma unroll
            for (int j = 0; j < 8; ++j) Vt[(sd0+8+j)*136  + scs] = (unsigned short)vr1[j];
#pragma unroll
            for (int j = 0; j < 8; ++j) Vt[(sd0+16+j)*136 + scs] = (unsigned short)vr2[j];
#pragma unroll
            for (int j = 0; j < 8; ++j) Vt[(sd0+24+j)*136 + scs] = (unsigned short)vr3[j];
            __syncthreads();   // LDS ready
            // ---- prefetch next tile ----
            const int nkt = (tile + 1 < ntiles) ? (kt + 128) : 0;
            LOADREG(nkt);

            // ---- QK^T: S[16q x 128key] in 8 subtiles ----
            f32x4 sacc[8];
            __builtin_amdgcn_s_setprio(1);
#pragma unroll
            for (int kt16 = 0; kt16 < 8; ++kt16) {
                sacc[kt16] = (f32x4){0.f,0.f,0.f,0.f};
                const unsigned short* kp = &Ks[(kt16*16 + l15)*72 + lg*8];
                bf16x8 k0 = *reinterpret_cast<const bf16x8*>(kp);
                bf16x8 k1 = *reinterpret_cast<const bf16x8*>(kp + 32);
                sacc[kt16] = __builtin_amdgcn_mfma_f32_16x16x32_bf16(qf0, k0, sacc[kt16], 0, 0, 0);
                sacc[kt16] = __builtin_amdgcn_mfma_f32_16x16x32_bf16(qf1, k1, sacc[kt16], 0, 0, 0);
            }
            __builtin_amdgcn_s_setprio(0);

            // ---- scale + causal mask (in place) ----
            const bool diag = (tile == ntiles - 1);
#pragma unroll
            for (int kt16 = 0; kt16 < 8; ++kt16) {
#pragma unroll
                for (int r = 0; r < 4; ++r) {
                    float s = sacc[kt16][r] * 0.125f;
                    if (diag) {
                        const int key = kt + kt16*16 + l15;
                        const int q   = q0w + 4*lg + r;
                        if (key > q) s = -INFINITY;
                    }
                    sacc[kt16][r] = s;
                }
            }
            // ---- online softmax over 128 keys ----
#pragma unroll
            for (int r = 0; r < 4; ++r) {
                float tm = fmaxf(
                    fmaxf(fmaxf(sacc[0][r], sacc[1][r]), fmaxf(sacc[2][r], sacc[3][r])),
                    fmaxf(fmaxf(sacc[4][r], sacc[5][r]), fmaxf(sacc[6][r], sacc[7][r])));
#pragma unroll
                for (int off = 8; off; off >>= 1) tm = fmaxf(tm, __shfl_xor(tm, off, 64));
                const float nm = fmaxf(mrow[r], tm);
                const float al = __expf(mrow[r] - nm);
                mrow[r] = nm;
                float ps = 0.f;
#pragma unroll
                for (int kt16 = 0; kt16 < 8; ++kt16) {
                    const float p = __expf(sacc[kt16][r] - nm);
                    ps += p;
                    pw_base[(4*lg + r)*136 + kt16*16 + l15] = f2bf(p);
                }
#pragma unroll
                for (int off = 8; off; off >>= 1) ps += __shfl_xor(ps, off, 64);
                lrow[r] = lrow[r]*al + ps;
#pragma unroll
                for (int dt = 0; dt < 4; ++dt) oacc[dt][r] *= al;
            }

            // ---- PV: O[16q x 64d] += P @ V (K=128 in 4 steps) ----
            const unsigned short* pr = &pw_base[l15*136 + lg*8];
            bf16x8 pa0 = *reinterpret_cast<const bf16x8*>(pr);
            bf16x8 pa1 = *reinterpret_cast<const bf16x8*>(pr + 32);
            bf16x8 pa2 = *reinterpret_cast<const bf16x8*>(pr + 64);
            bf16x8 pa3 = *reinterpret_cast<const bf16x8*>(pr + 96);
            __builtin_amdgcn_s_setprio(1);
#pragma unroll
            for (int dt = 0; dt < 4; ++dt) {
                const unsigned short* vrow = &Vt[(dt*16 + l15)*136];
                bf16x8 v0 = *reinterpret_cast<const bf16x8*>(&vrow[(( 0 + lg) ^ (dt & 2))*8]);
                bf16x8 v1 = *reinterpret_cast<const bf16x8*>(&vrow[(( 4 + lg) ^ (dt & 2))*8]);
                bf16x8 v2 = *reinterpret_cast<const bf16x8*>(&vrow[(( 8 + lg) ^ (dt & 2))*8]);
                bf16x8 v3 = *reinterpret_cast<const bf16x8*>(&vrow[((12 + lg) ^ (dt & 2))*8]);
                oacc[dt] = __builtin_amdgcn_mfma_f32_16x16x32_bf16(pa0, v0, oacc[dt], 0, 0, 0);
                oacc[dt] = __builtin_amdgcn_mfma_f32_16x16x32_bf16(pa1, v1, oacc[dt], 0, 0, 0);
                oacc[dt] = __builtin_amdgcn_mfma_f32_16x16x32_bf16(pa2, v2, oacc[dt], 0, 0, 0);
                oacc[dt] = __builtin_amdgcn_mfma_f32_16x16x32_bf16(pa3, v3, oacc[dt], 0, 0, 0);
            }
            __builtin_amdgcn_s_setprio(0);
        }

        // ---- epilogue for this half ----
#pragma unroll
        for (int dt = 0; dt < 4; ++dt) {
#pragma unroll
            for (int r = 0; r < 4; ++r) {
                const int q = q0w + 4*lg + r;
                ob[((size_t)b*S_ + q)*D_ + h*64 + dt*16 + l15] = f2bf(oacc[dt][r] / lrow[r]);
            }
        }
    }
#undef LOADREG
}

// ---------------- LayerNorm (residual add, optional bf16 shadow out) -------
__global__ __launch_bounds__(256) void ln_kernel(
    float* __restrict__ dst, unsigned short* __restrict__ dst2,
    const float* __restrict__ src, const float* __restrict__ add,
    const float* __restrict__ w, const float* __restrict__ b, float eps)
{
    const int row = blockIdx.x, tid = threadIdx.x;
    const int lane = tid & 63, wave = tid >> 6;
    float2 v = *reinterpret_cast<const float2*>(src + (size_t)row * D_ + tid*2);
    if (add) {
        float2 a = *reinterpret_cast<const float2*>(add + (size_t)row * D_ + tid*2);
        v.x += a.x; v.y += a.y;
    }
    __shared__ float red[8];
    float s = v.x + v.y;
#pragma unroll
    for (int off = 32; off; off >>= 1) s += __shfl_xor(s, off, 64);
    if (lane == 0) red[wave] = s;
    __syncthreads();
    const float mean = (red[0]+red[1]+red[2]+red[3]) * (1.f/D_);
    const float d0 = v.x - mean, d1 = v.y - mean;
    float sq = d0*d0 + d1*d1;
#pragma unroll
    for (int off = 32; off; off >>= 1) sq += __shfl_xor(sq, off, 64);
    if (lane == 0) red[4+wave] = sq;
    __syncthreads();
    const float var = (red[4]+red[5]+red[6]+red[7]) * (1.f/D_);
    const float inv = rsqrtf(var + eps);
    const float o0 = d0*inv*w[tid*2] + b[tid*2];
    const float o1 = d1*inv*w[tid*2+1] + b[tid*2+1];
    *reinterpret_cast<float2*>(dst + (size_t)row * D_ + tid*2) = make_float2(o0, o1);
    if (dst2) {
        ushort2 u; u.x = f2bf(o0); u.y = f2bf(o1);
        *reinterpret_cast<ushort2*>(dst2 + (size_t)row * D_ + tid*2) = u;
    }
}

// ---------------- patch mean-pool ----------------
__global__ __launch_bounds__(256) void meanpool_kernel(
    const float* __restrict__ x, float* __restrict__ query)
{
    const int bp = blockIdx.x;
    const int d = threadIdx.x * 2;
    const float* base = x + (size_t)bp * PLEN_ * D_ + d;
    float s0 = 0.f, s1 = 0.f;
    for (int l = 0; l < PLEN_; ++l) {
        float2 v = *reinterpret_cast<const float2*>(base + (size_t)l * D_);
        s0 += v.x; s1 += v.y;
    }
    query[(size_t)bp*D_ + d]     = s0 * (1.f/PLEN_);
    query[(size_t)bp*D_ + d + 1] = s1 * (1.f/PLEN_);
}

// ---------------- patch cross-attention, one wave per (b,p,h) -------------
__global__ __launch_bounds__(256) void patch_attn_kernel(
    const float* __restrict__ qbuf, const float* __restrict__ kv,
    float* __restrict__ o)
{
    const int wid  = blockIdx.x * 4 + (threadIdx.x >> 6);
    const int lane = threadIdx.x & 63;
    const int h  = wid % H_;
    const int bp = wid / H_;
    const float qv = qbuf[(size_t)bp*D_ + h*HD_ + lane] * 0.125f;
    const float* base = kv + (size_t)bp * PLEN_ * 1024 + h*HD_;

    float m = -INFINITY, l = 0.f, acc = 0.f;
    for (int t = 0; t < PLEN_; ++t) {
        const float* row = base + (size_t)t * 1024;
        float s = qv * row[lane];
#pragma unroll
        for (int off = 32; off; off >>= 1) s += __shfl_xor(s, off, 64);
        const float vv = row[512 + lane];
        const float nm = fmaxf(m, s);
        const float al = __expf(m - nm);
        const float p  = __expf(s - nm);
        l = l * al + p;
        acc = acc * al + p * vv;
        m = nm;
    }
    o[(size_t)bp*D_ + h*HD_ + lane] = acc / l;
}

extern "C" void kernel_launch(void* const* d_in, const int* in_sizes, int n_in,
                              void* d_out, int out_size, void* d_ws, size_t ws_size,
                              hipStream_t stream)
{
    const int*   byte_seq = (const int*)d_in[0];
    const float* byte_emb = (const float*)d_in[2];
    const float* ng_emb   = (const float*)d_in[3];
    const float* qkv_w = (const float*)d_in[4];
    const float* qkv_b = (const float*)d_in[5];
    const float* out_w = (const float*)d_in[6];
    const float* out_b = (const float*)d_in[7];
    const float* ln1_w = (const float*)d_in[8];
    const float* ln1_b = (const float*)d_in[9];
    const float* ln2_w = (const float*)d_in[10];
    const float* ln2_b = (const float*)d_in[11];
    const float* ff1_w = (const float*)d_in[12];
    const float* ff1_b = (const float*)d_in[13];
    const float* ff2_w = (const float*)d_in[14];
    const float* ff2_b = (const float*)d_in[15];
    const float* ca_qkv_w = (const float*)d_in[16];
    const float* ca_qkv_b = (const float*)d_in[17];
    const float* ca_out_w = (const float*)d_in[18];
    const float* ca_out_b = (const float*)d_in[19];
    const float* ca_ln_w  = (const float*)d_in[20];
    const float* ca_ln_b  = (const float*)d_in[21];
    const float* norm_w   = (const float*)d_in[22];
    const float* norm_b   = (const float*)d_in[23];
    float* out = (float*)d_out;

    char* ws = (char*)d_ws;
    const size_t MB = 1024*1024;
    float*          x     = (float*)(ws);
    char*           bufA  = ws + 16*MB;
    float*          bufB  = (float*)(ws + 48*MB);
    unsigned short* ob    = (unsigned short*)(ws + 64*MB);
    unsigned short* xb    = (unsigned short*)(ws + 72*MB);
    unsigned short* qkvw_b = (unsigned short*)(ws + 80*MB);
    unsigned short* outw_b = (unsigned short*)(ws + 83*MB);
    unsigned short* ff1w_b = (unsigned short*)(ws + 84*MB);
    unsigned short* ff2w_b = (unsigned short*)(ws + 88*MB);
    unsigned short* kvw_b  = (unsigned short*)(ws + 92*MB);
    float* query   = (float*)(ws + 93*MB);
    float* qn      = query + 64*512;
    float* qsm     = qn + 64*512;
    float* oca     = qsm + 64*512;
    float* patches = oca + 64*512;

    unsigned short* qkvb = (unsigned short*)bufA;
    unsigned short* ff1b = (unsigned short*)bufA;
    float*          kvf  = (float*)bufA;

    const int M = B_ * S_;

    // 0. one-time weight casts to bf16 (single launch)
    cast5_kernel<<<(C0_+C1_+C2_+C3_+C4_+255)/256, 256, 0, stream>>>(
        qkv_w, out_w, ff1_w, ff2_w, ca_qkv_w + 512*512,
        qkvw_b, outw_b, ff1w_b, ff2w_b, kvw_b);

    // 1. byte embedding + n-gram hash adds
    embed_ngram_kernel<<<M, 128, 0, stream>>>(byte_seq, byte_emb, ng_emb, x, xb);

    // 2. transformer layers
    for (int l = 0; l < L_; ++l) {
        mgemm_kernel<0,1,128><<<dim3(1536/128, M/128), 256, 0, stream>>>(
            xb, qkvw_b + (size_t)l*1536*D_, qkv_b + l*1536, qkvb, M, 1536, D_);
        attn_mfma_kernel<<<dim3(S_/128, B_*H_), 256, 0, stream>>>(qkvb, ob);
        mgemm_kernel<0,0,64><<<dim3(D_/64, M/128), 256, 0, stream>>>(
            ob, outw_b + (size_t)l*D_*D_, out_b + l*D_, bufB, M, D_, D_);
        ln_kernel<<<M, 256, 0, stream>>>(x, xb, x, bufB, ln1_w + l*D_, ln1_b + l*D_, 1e-5f);
        mgemm_kernel<1,1,128><<<dim3(2048/128, M/128), 256, 0, stream>>>(
            xb, ff1w_b + (size_t)l*2048*D_, ff1_b + l*2048, ff1b, M, 2048, D_);
        mgemm_kernel<0,0,64><<<dim3(D_/64, M/128), 256, 0, stream>>>(
            ff1b, ff2w_b + (size_t)l*D_*2048, ff2_b + l*D_, bufB, M, D_, 2048);
        ln_kernel<<<M, 256, 0, stream>>>(x, xb, x, bufB, ln2_w + l*D_, ln2_b + l*D_, 1e-5f);
    }

    // 3. patch cross-attention
    meanpool_kernel<<<B_*NPATCH_, 256, 0, stream>>>(x, query);
    ln_kernel<<<B_*NPATCH_, 256, 0, stream>>>(qn, nullptr, query, nullptr, ca_ln_w, ca_ln_b, 1e-6f);
    ln_kernel<<<M, 256, 0, stream>>>(bufB, xb, x, nullptr, ca_ln_w, ca_ln_b, 1e-6f);
    mgemm_kernel<0,0,128><<<dim3(1024/128, M/128), 256, 0, stream>>>(
        xb, kvw_b, ca_qkv_b + 512, kvf, M, 1024, D_);
    gemm_kernel<<<dim3(D_/64, 1), 256, 0, stream>>>(
        qn, ca_qkv_w, ca_qkv_b, nullptr, qsm, 64, D_, D_, 0);
    patch_attn_kernel<<<B_*NPATCH_*H_/4, 256, 0, stream>>>(qsm, kvf, oca);
    gemm_kernel<<<dim3(D_/64, 1), 256, 0, stream>>>(
        oca, ca_out_w, ca_out_b, query, patches, 64, D_, D_, 0);

    // 4. final LayerNorms -> f32 outputs
    ln_kernel<<<M, 256, 0, stream>>>(out, nullptr, x, nullptr, norm_w, norm_b, 1e-6f);
    ln_kernel<<<B_*NPATCH_, 256, 0, stream>>>(
        out + (size_t)M*D_, nullptr, patches, nullptr, norm_w, norm_b, 1e-6f);
}

// Round 10
// 513.400 us; speedup vs baseline: 21.8371x; 1.1063x over previous
//
#include <hip/hip_runtime.h>
#include <hip/hip_bf16.h>

#define B_ 4
#define S_ 2048
#define D_ 512
#define H_ 8
#define HD_ 64
#define L_ 2
#define V_ 30000
#define NPATCH_ 16
#define PLEN_ 128

typedef short bf16x8 __attribute__((ext_vector_type(8)));
typedef float f32x4 __attribute__((ext_vector_type(4)));

__device__ __forceinline__ unsigned short f2bf(float f) {
    unsigned u = __float_as_uint(f);
    return (unsigned short)((u + 0x7FFFu + ((u >> 16) & 1u)) >> 16);   // RNE
}

// ---------------- merged f32 -> bf16 weight casts (1 launch) ----------------
#define C0_ (2*1536*512/4)
#define C1_ (2*512*512/4)
#define C2_ (2*2048*512/4)
#define C3_ (2*512*2048/4)
#define C4_ (1024*512/4)
__global__ __launch_bounds__(256) void cast5_kernel(
    const float* __restrict__ s0, const float* __restrict__ s1,
    const float* __restrict__ s2, const float* __restrict__ s3,
    const float* __restrict__ s4,
    unsigned short* __restrict__ d0, unsigned short* __restrict__ d1,
    unsigned short* __restrict__ d2, unsigned short* __restrict__ d3,
    unsigned short* __restrict__ d4)
{
    int i = blockIdx.x * 256 + threadIdx.x;
    const float* s; unsigned short* d;
    if      (i < C0_)                  { s = s0; d = d0; }
    else if ((i -= C0_) < C1_)         { s = s1; d = d1; }
    else if ((i -= C1_) < C2_)         { s = s2; d = d2; }
    else if ((i -= C2_) < C3_)         { s = s3; d = d3; }
    else if ((i -= C3_) < C4_)         { s = s4; d = d4; }
    else return;
    const float4 v = *reinterpret_cast<const float4*>(s + (size_t)i * 4);
    ushort4 o;
    o.x = f2bf(v.x); o.y = f2bf(v.y); o.z = f2bf(v.z); o.w = f2bf(v.w);
    *reinterpret_cast<ushort4*>(d + (size_t)i * 4) = o;
}

// ---------------- embed + n-gram hash add (f32 + bf16 shadow) -------------
__global__ __launch_bounds__(128) void embed_ngram_kernel(
    const int* __restrict__ bytes, const float* __restrict__ byte_emb,
    const float* __restrict__ ng_emb, float* __restrict__ x,
    unsigned short* __restrict__ xb)
{
    const int bs = blockIdx.x;
    const int s  = bs % S_;
    const int b  = bs / S_;
    const int d  = threadIdx.x * 4;
    const int* brow = bytes + (size_t)b * S_;

    const int c = brow[s];
    float4 v = *reinterpret_cast<const float4*>(byte_emb + (size_t)c * D_ + d);

    if (s >= 2) {
        int h = (brow[s-2]*961 + brow[s-1]*31 + brow[s]) % V_;
        const float4 g = *reinterpret_cast<const float4*>(ng_emb + ((size_t)0*V_ + h)*D_ + d);
        v.x += 0.25f*g.x; v.y += 0.25f*g.y; v.z += 0.25f*g.z; v.w += 0.25f*g.w;
    }
    if (s >= 3) {
        int h = (brow[s-3]*29791 + brow[s-2]*961 + brow[s-1]*31 + brow[s]) % V_;
        const float4 g = *reinterpret_cast<const float4*>(ng_emb + ((size_t)1*V_ + h)*D_ + d);
        v.x += 0.25f*g.x; v.y += 0.25f*g.y; v.z += 0.25f*g.z; v.w += 0.25f*g.w;
    }
    if (s >= 4) {
        int h = (brow[s-4]*23521 + brow[s-3]*29791 + brow[s-2]*961 + brow[s-1]*31 + brow[s]) % V_;
        const float4 g = *reinterpret_cast<const float4*>(ng_emb + ((size_t)2*V_ + h)*D_ + d);
        v.x += 0.25f*g.x; v.y += 0.25f*g.y; v.z += 0.25f*g.z; v.w += 0.25f*g.w;
    }
    *reinterpret_cast<float4*>(x + (size_t)bs * D_ + d) = v;
    ushort4 o;
    o.x = f2bf(v.x); o.y = f2bf(v.y); o.z = f2bf(v.z); o.w = f2bf(v.w);
    *reinterpret_cast<ushort4*>(xb + (size_t)bs * D_ + d) = o;
}

// ---------------- MFMA bf16 GEMM: Y = X @ W^T + bias [,relu] --------------
// XCD-aware chunked block swizzle (bijective: all call-site grids %8==0).
template<int DO_RELU, int BF16OUT, int BN>
__global__ __launch_bounds__(256) void mgemm_kernel(
    const unsigned short* __restrict__ Xb, const unsigned short* __restrict__ Wb,
    const float* __restrict__ bias, void* __restrict__ Yout,
    int M, int N, int K)
{
    constexpr int NT  = BN / 32;
    constexpr int NLB = BN / 32;
    __shared__ unsigned short As[128*64];
    __shared__ unsigned short Bs[BN*64];

    const int t    = threadIdx.x;
    const int lane = t & 63;
    const int w    = t >> 6;

    // XCD swizzle: each XCD gets a contiguous chunk of flat block ids.
    const int nwg = gridDim.x * gridDim.y;
    const int bid = blockIdx.y * gridDim.x + blockIdx.x;
    const int swz = (bid & 7) * (nwg >> 3) + (bid >> 3);
    const int bx  = swz % gridDim.x, by = swz / gridDim.x;

    const int bm   = by * 128, bn = bx * BN;
    const int l15  = lane & 15, lg = lane >> 4;
    const int wr   = w >> 1, wc = w & 1;

    int srow[4], scol[4];
#pragma unroll
    for (int i = 0; i < 4; ++i) {
        const int off = w*1024 + i*4096 + lane*16;
        srow[i] = off >> 7;
        scol[i] = ((off >> 4) & 7) ^ (srow[i] & 7);
    }

    f32x4 acc[4][NT];
#pragma unroll
    for (int mt = 0; mt < 4; ++mt)
#pragma unroll
        for (int nt = 0; nt < NT; ++nt) acc[mt][nt] = (f32x4){0.f,0.f,0.f,0.f};

    for (int kt = 0; kt < K; kt += 64) {
#pragma unroll
        for (int i = 0; i < 4; ++i) {
            const unsigned short* gA = Xb + (size_t)(bm + srow[i]) * K + kt + scol[i]*8;
            __builtin_amdgcn_global_load_lds(
                (const __attribute__((address_space(1))) void*)gA,
                (__attribute__((address_space(3))) void*)&As[w*512 + i*2048], 16, 0, 0);
        }
#pragma unroll
        for (int i = 0; i < NLB; ++i) {
            const unsigned short* gB = Wb + (size_t)(bn + srow[i]) * K + kt + scol[i]*8;
            __builtin_amdgcn_global_load_lds(
                (const __attribute__((address_space(1))) void*)gB,
                (__attribute__((address_space(3))) void*)&Bs[w*512 + i*2048], 16, 0, 0);
        }
        __syncthreads();

#pragma unroll
        for (int ks = 0; ks < 2; ++ks) {
            const int c16 = (ks*4 + lg) ^ (l15 & 7);
            bf16x8 a[4], b[NT];
#pragma unroll
            for (int mt = 0; mt < 4; ++mt)
                a[mt] = *reinterpret_cast<const bf16x8*>(&As[(wr*64 + mt*16 + l15)*64 + c16*8]);
#pragma unroll
            for (int nt = 0; nt < NT; ++nt)
                b[nt] = *reinterpret_cast<const bf16x8*>(&Bs[(wc*(BN/2) + nt*16 + l15)*64 + c16*8]);
#pragma unroll
            for (int mt = 0; mt < 4; ++mt)
#pragma unroll
                for (int nt = 0; nt < NT; ++nt)
                    acc[mt][nt] = __builtin_amdgcn_mfma_f32_16x16x32_bf16(
                        a[mt], b[nt], acc[mt][nt], 0, 0, 0);
        }
        __syncthreads();
    }

    float bv[NT];
#pragma unroll
    for (int nt = 0; nt < NT; ++nt) bv[nt] = bias[bn + wc*(BN/2) + nt*16 + l15];

#pragma unroll
    for (int mt = 0; mt < 4; ++mt) {
#pragma unroll
        for (int nt = 0; nt < NT; ++nt) {
            const int n = bn + wc*(BN/2) + nt*16 + l15;
#pragma unroll
            for (int r = 0; r < 4; ++r) {
                const int m = bm + wr*64 + mt*16 + 4*lg + r;
                float v = acc[mt][nt][r] + bv[nt];
                if (DO_RELU) v = fmaxf(v, 0.f);
                if (BF16OUT)
                    ((unsigned short*)Yout)[(size_t)m * N + n] = f2bf(v);
                else
                    ((float*)Yout)[(size_t)m * N + n] = v;
            }
        }
    }
}

// ---------------- MFMA bf16 causal flash attention (KVBLK=128) -------------
__global__ __launch_bounds__(256) void attn_mfma_kernel(
    const unsigned short* __restrict__ qkvb, unsigned short* __restrict__ ob)
{
    __shared__ unsigned short Ks[128*72];
    __shared__ unsigned short Vt[64*136];
    __shared__ unsigned short Plds[4*16*136];

    const int t    = threadIdx.x;
    const int lane = t & 63;
    const int w    = t >> 6;
    const int qp   = blockIdx.x;
    const int bh   = blockIdx.y;
    const int h    = bh & 7;
    const int b    = bh >> 3;

    const unsigned short* base = qkvb + (size_t)b * S_ * 1536;
    const int l15 = lane & 15, lg = lane >> 4;
    const int skey = t >> 1;
    const int sd0  = (t & 1) * 32;
    const int scs  = (((skey >> 3) ^ ((t & 1) << 1)) << 3) + (skey & 7);
    unsigned short* pw_base = Plds + w*16*136;

    bf16x8 kr0, kr1, kr2, kr3, vr0, vr1, vr2, vr3;
#define LOADREG(KT) { \
        const unsigned short* p_ = base + (size_t)((KT) + skey) * 1536 + 512 + h*64 + sd0; \
        kr0 = *reinterpret_cast<const bf16x8*>(p_);       \
        kr1 = *reinterpret_cast<const bf16x8*>(p_ + 8);   \
        kr2 = *reinterpret_cast<const bf16x8*>(p_ + 16);  \
        kr3 = *reinterpret_cast<const bf16x8*>(p_ + 24);  \
        vr0 = *reinterpret_cast<const bf16x8*>(p_ + 512); \
        vr1 = *reinterpret_cast<const bf16x8*>(p_ + 520); \
        vr2 = *reinterpret_cast<const bf16x8*>(p_ + 528); \
        vr3 = *reinterpret_cast<const bf16x8*>(p_ + 536); }

    LOADREG(0);

#pragma unroll
    for (int half = 0; half < 2; ++half) {
        const int qb  = half ? (31 - qp) : qp;
        const int q0w = qb * 64 + w * 16;

        bf16x8 qf0, qf1;
        {
            const unsigned short* qr = base + (size_t)(q0w + l15) * 1536 + h*64 + lg*8;
            qf0 = *reinterpret_cast<const bf16x8*>(qr);
            qf1 = *reinterpret_cast<const bf16x8*>(qr + 32);
        }

        f32x4 oacc[4];
#pragma unroll
        for (int i = 0; i < 4; ++i) oacc[i] = (f32x4){0.f,0.f,0.f,0.f};
        float mrow[4] = {-INFINITY,-INFINITY,-INFINITY,-INFINITY};
        float lrow[4] = {0.f,0.f,0.f,0.f};

        const int ntiles = (qb + 2) >> 1;
        for (int tile = 0; tile < ntiles; ++tile) {
            const int kt = tile * 128;
            __syncthreads();
            *reinterpret_cast<bf16x8*>(&Ks[skey*72 + sd0])      = kr0;
            *reinterpret_cast<bf16x8*>(&Ks[skey*72 + sd0 + 8])  = kr1;
            *reinterpret_cast<bf16x8*>(&Ks[skey*72 + sd0 + 16]) = kr2;
            *reinterpret_cast<bf16x8*>(&Ks[skey*72 + sd0 + 24]) = kr3;
#pragma unroll
            for (int j = 0; j < 8; ++j) Vt[(sd0+j)*136    + scs] = (unsigned short)vr0[j];
#pragma unroll
            for (int j = 0; j < 8; ++j) Vt[(sd0+8+j)*136  + scs] = (unsigned short)vr1[j];
#pragma unroll
            for (int j = 0; j < 8; ++j) Vt[(sd0+16+j)*136 + scs] = (unsigned short)vr2[j];
#pragma unroll
            for (int j = 0; j < 8; ++j) Vt[(sd0+24+j)*136 + scs] = (unsigned short)vr3[j];
            __syncthreads();
            const int nkt = (tile + 1 < ntiles) ? (kt + 128) : 0;
            LOADREG(nkt);

            f32x4 sacc[8];
            __builtin_amdgcn_s_setprio(1);
#pragma unroll
            for (int kt16 = 0; kt16 < 8; ++kt16) {
                sacc[kt16] = (f32x4){0.f,0.f,0.f,0.f};
                const unsigned short* kp = &Ks[(kt16*16 + l15)*72 + lg*8];
                bf16x8 k0 = *reinterpret_cast<const bf16x8*>(kp);
                bf16x8 k1 = *reinterpret_cast<const bf16x8*>(kp + 32);
                sacc[kt16] = __builtin_amdgcn_mfma_f32_16x16x32_bf16(qf0, k0, sacc[kt16], 0, 0, 0);
                sacc[kt16] = __builtin_amdgcn_mfma_f32_16x16x32_bf16(qf1, k1, sacc[kt16], 0, 0, 0);
            }
            __builtin_amdgcn_s_setprio(0);

            const bool diag = (tile == ntiles - 1);
#pragma unroll
            for (int kt16 = 0; kt16 < 8; ++kt16) {
#pragma unroll
                for (int r = 0; r < 4; ++r) {
                    float s = sacc[kt16][r] * 0.125f;
                    if (diag) {
                        const int key = kt + kt16*16 + l15;
                        const int q   = q0w + 4*lg + r;
                        if (key > q) s = -INFINITY;
                    }
                    sacc[kt16][r] = s;
                }
            }
#pragma unroll
            for (int r = 0; r < 4; ++r) {
                float tm = fmaxf(
                    fmaxf(fmaxf(sacc[0][r], sacc[1][r]), fmaxf(sacc[2][r], sacc[3][r])),
                    fmaxf(fmaxf(sacc[4][r], sacc[5][r]), fmaxf(sacc[6][r], sacc[7][r])));
#pragma unroll
                for (int off = 8; off; off >>= 1) tm = fmaxf(tm, __shfl_xor(tm, off, 64));
                const float nm = fmaxf(mrow[r], tm);
                const float al = __expf(mrow[r] - nm);
                mrow[r] = nm;
                float ps = 0.f;
#pragma unroll
                for (int kt16 = 0; kt16 < 8; ++kt16) {
                    const float p = __expf(sacc[kt16][r] - nm);
                    ps += p;
                    pw_base[(4*lg + r)*136 + kt16*16 + l15] = f2bf(p);
                }
#pragma unroll
                for (int off = 8; off; off >>= 1) ps += __shfl_xor(ps, off, 64);
                lrow[r] = lrow[r]*al + ps;
#pragma unroll
                for (int dt = 0; dt < 4; ++dt) oacc[dt][r] *= al;
            }

            const unsigned short* pr = &pw_base[l15*136 + lg*8];
            bf16x8 pa0 = *reinterpret_cast<const bf16x8*>(pr);
            bf16x8 pa1 = *reinterpret_cast<const bf16x8*>(pr + 32);
            bf16x8 pa2 = *reinterpret_cast<const bf16x8*>(pr + 64);
            bf16x8 pa3 = *reinterpret_cast<const bf16x8*>(pr + 96);
            __builtin_amdgcn_s_setprio(1);
#pragma unroll
            for (int dt = 0; dt < 4; ++dt) {
                const unsigned short* vrow = &Vt[(dt*16 + l15)*136];
                bf16x8 v0 = *reinterpret_cast<const bf16x8*>(&vrow[(( 0 + lg) ^ (dt & 2))*8]);
                bf16x8 v1 = *reinterpret_cast<const bf16x8*>(&vrow[(( 4 + lg) ^ (dt & 2))*8]);
                bf16x8 v2 = *reinterpret_cast<const bf16x8*>(&vrow[(( 8 + lg) ^ (dt & 2))*8]);
                bf16x8 v3 = *reinterpret_cast<const bf16x8*>(&vrow[((12 + lg) ^ (dt & 2))*8]);
                oacc[dt] = __builtin_amdgcn_mfma_f32_16x16x32_bf16(pa0, v0, oacc[dt], 0, 0, 0);
                oacc[dt] = __builtin_amdgcn_mfma_f32_16x16x32_bf16(pa1, v1, oacc[dt], 0, 0, 0);
                oacc[dt] = __builtin_amdgcn_mfma_f32_16x16x32_bf16(pa2, v2, oacc[dt], 0, 0, 0);
                oacc[dt] = __builtin_amdgcn_mfma_f32_16x16x32_bf16(pa3, v3, oacc[dt], 0, 0, 0);
            }
            __builtin_amdgcn_s_setprio(0);
        }

#pragma unroll
        for (int dt = 0; dt < 4; ++dt) {
#pragma unroll
            for (int r = 0; r < 4; ++r) {
                const int q = q0w + 4*lg + r;
                ob[((size_t)b*S_ + q)*D_ + h*64 + dt*16 + l15] = f2bf(oacc[dt][r] / lrow[r]);
            }
        }
    }
#undef LOADREG
}

// ---------------- LayerNorm (residual add, nullable outputs) ---------------
__global__ __launch_bounds__(256) void ln_kernel(
    float* __restrict__ dst, unsigned short* __restrict__ dst2,
    const float* __restrict__ src, const float* __restrict__ add,
    const float* __restrict__ w, const float* __restrict__ b, float eps)
{
    const int row = blockIdx.x, tid = threadIdx.x;
    const int lane = tid & 63, wave = tid >> 6;
    float2 v = *reinterpret_cast<const float2*>(src + (size_t)row * D_ + tid*2);
    if (add) {
        float2 a = *reinterpret_cast<const float2*>(add + (size_t)row * D_ + tid*2);
        v.x += a.x; v.y += a.y;
    }
    __shared__ float red[8];
    float s = v.x + v.y;
#pragma unroll
    for (int off = 32; off; off >>= 1) s += __shfl_xor(s, off, 64);
    if (lane == 0) red[wave] = s;
    __syncthreads();
    const float mean = (red[0]+red[1]+red[2]+red[3]) * (1.f/D_);
    const float d0 = v.x - mean, d1 = v.y - mean;
    float sq = d0*d0 + d1*d1;
#pragma unroll
    for (int off = 32; off; off >>= 1) sq += __shfl_xor(sq, off, 64);
    if (lane == 0) red[4+wave] = sq;
    __syncthreads();
    const float var = (red[4]+red[5]+red[6]+red[7]) * (1.f/D_);
    const float inv = rsqrtf(var + eps);
    const float o0 = d0*inv*w[tid*2] + b[tid*2];
    const float o1 = d1*inv*w[tid*2+1] + b[tid*2+1];
    if (dst)
        *reinterpret_cast<float2*>(dst + (size_t)row * D_ + tid*2) = make_float2(o0, o1);
    if (dst2) {
        ushort2 u; u.x = f2bf(o0); u.y = f2bf(o1);
        *reinterpret_cast<ushort2*>(dst2 + (size_t)row * D_ + tid*2) = u;
    }
}

// ---------------- fused patch-CA tail ----------------
// One block per (b,p): meanpool -> LN(q) -> q-proj -> 8-head x 128-kv attn
// -> out-proj + residual -> final LN -> out[M + bp].
// kvf rows (width 1024): [k(512) | v(512)], from the kv mgemm.
__global__ __launch_bounds__(256) void patch_tail_kernel(
    const float* __restrict__ x, const float* __restrict__ kvf,
    const float* __restrict__ ca_qkv_w, const float* __restrict__ ca_qkv_b,
    const float* __restrict__ ca_out_w, const float* __restrict__ ca_out_b,
    const float* __restrict__ ca_ln_w, const float* __restrict__ ca_ln_b,
    const float* __restrict__ norm_w, const float* __restrict__ norm_b,
    float* __restrict__ out)
{
    __shared__ float query[512];   // raw mean (residual)
    __shared__ float qs[512];      // scaled projected q
    __shared__ float ps[8*128];    // scores -> probs
    __shared__ float os[512];      // attention output
    __shared__ float red[64];
    __shared__ float mred[8], sred[8];

    const int t  = threadIdx.x;
    const int bp = blockIdx.x;     // 0..63
    const int d0 = t * 2;
    const int lane = t & 63, wave = t >> 6;

    // --- 1. mean-pool over 128 rows ---
    {
        const float* base = x + (size_t)bp * PLEN_ * D_ + d0;
        float s0 = 0.f, s1 = 0.f;
        for (int l = 0; l < PLEN_; ++l) {
            float2 v = *reinterpret_cast<const float2*>(base + (size_t)l * D_);
            s0 += v.x; s1 += v.y;
        }
        query[d0] = s0 * (1.f/PLEN_);
        query[d0+1] = s1 * (1.f/PLEN_);
    }
    __syncthreads();

    // --- 2. LN(query) -> qn (kept in registers + LDS via qs temporarily) ---
    float qv0 = query[d0], qv1 = query[d0+1];
    {
        float s = qv0 + qv1;
#pragma unroll
        for (int off = 32; off; off >>= 1) s += __shfl_xor(s, off, 64);
        if (lane == 0) red[wave] = s;
        __syncthreads();
        const float mean = (red[0]+red[1]+red[2]+red[3]) * (1.f/D_);
        const float e0 = qv0 - mean, e1 = qv1 - mean;
        float sq = e0*e0 + e1*e1;
#pragma unroll
        for (int off = 32; off; off >>= 1) sq += __shfl_xor(sq, off, 64);
        if (lane == 0) red[4+wave] = sq;
        __syncthreads();
        const float var = (red[4]+red[5]+red[6]+red[7]) * (1.f/D_);
        const float inv = rsqrtf(var + 1e-6f);
        qs[d0]   = e0*inv*ca_ln_w[d0]   + ca_ln_b[d0];     // qn
        qs[d0+1] = e1*inv*ca_ln_w[d0+1] + ca_ln_b[d0+1];
    }
    __syncthreads();

    // --- 3. q = qn @ Wq^T + bq, scaled by 0.125, into registers then qs ---
    float qp0, qp1;
    {
        const float* w0 = ca_qkv_w + (size_t)d0 * D_;
        float a0 = ca_qkv_b[d0], a1 = ca_qkv_b[d0+1];
        for (int e = 0; e < D_; e += 4) {
            const float4 qn4 = *reinterpret_cast<const float4*>(&qs[e]);
            const float4 wa = *reinterpret_cast<const float4*>(w0 + e);
            const float4 wb = *reinterpret_cast<const float4*>(w0 + D_ + e);
            a0 += qn4.x*wa.x + qn4.y*wa.y + qn4.z*wa.z + qn4.w*wa.w;
            a1 += qn4.x*wb.x + qn4.y*wb.y + qn4.z*wb.z + qn4.w*wb.w;
        }
        qp0 = a0 * 0.125f; qp1 = a1 * 0.125f;
    }
    __syncthreads();   // all reads of qs (qn) done
    qs[d0] = qp0; qs[d0+1] = qp1;
    __syncthreads();

    // --- 4. scores: s[h][l] = q[h]·k[l][h] ---
    {
        const int h = t >> 5, c = t & 31;           // 32 threads per head
        const float* qh = &qs[h*64];
#pragma unroll
        for (int j = 0; j < 4; ++j) {
            const int l = c*4 + j;
            const float* krow = kvf + ((size_t)bp*PLEN_ + l)*1024 + h*64;
            float acc = 0.f;
            for (int e = 0; e < 64; e += 4) {
                const float4 qe = *reinterpret_cast<const float4*>(qh + e);
                const float4 ke = *reinterpret_cast<const float4*>(krow + e);
                acc += qe.x*ke.x + qe.y*ke.y + qe.z*ke.z + qe.w*ke.w;
            }
            ps[h*128 + l] = acc;
        }
    }
    __syncthreads();

    // --- 5. softmax per head over 128 ---
    {
        const int h = t >> 5, c = t & 31;
        float m4 = fmaxf(fmaxf(ps[h*128+c*4], ps[h*128+c*4+1]),
                         fmaxf(ps[h*128+c*4+2], ps[h*128+c*4+3]));
        red[h*8 + (c>>2)] = 0.f;   // init (will be overwritten below safely)
        // group-of-32 shfl max (c within wave half: use LDS 8x32 instead)
        // simple: per-thread -> LDS, then 8 threads reduce
        __syncthreads();
        // store partial maxes
        float mt_ = m4;
#pragma unroll
        for (int off = 1; off < 4; off <<= 1) mt_ = fmaxf(mt_, __shfl_xor(mt_, off, 64));
        // lanes with c%4==0 hold max of 16 l's
        if ((c & 3) == 0) red[h*8 + (c>>2)] = mt_;
        __syncthreads();
        if (t < 8) {
            float m = red[t*8];
#pragma unroll
            for (int j = 1; j < 8; ++j) m = fmaxf(m, red[t*8+j]);
            mred[t] = m;
        }
        __syncthreads();
        const float mh = mred[h];
        float ssum = 0.f;
#pragma unroll
        for (int j = 0; j < 4; ++j) {
            const float p = __expf(ps[h*128 + c*4 + j] - mh);
            ps[h*128 + c*4 + j] = p;
            ssum += p;
        }
#pragma unroll
        for (int off = 1; off < 4; off <<= 1) ssum += __shfl_xor(ssum, off, 64);
        if ((c & 3) == 0) red[h*8 + (c>>2)] = ssum;
        __syncthreads();
        if (t < 8) {
            float s = 0.f;
#pragma unroll
            for (int j = 0; j < 8; ++j) s += red[t*8+j];
            sred[t] = 1.f / s;
        }
    }
    __syncthreads();

    // --- 6. o[d] = (Σ_l p[l] v[l][d]) / sum ---
    {
        const int h = t >> 5;                        // d0 = t*2 -> head t>>5
        const float* vbase = kvf + (size_t)bp*PLEN_*1024 + 512 + d0;
        float a0 = 0.f, a1 = 0.f;
        const float* ph = &ps[h*128];
        for (int l = 0; l < PLEN_; ++l) {
            const float p = ph[l];
            const float2 vv = *reinterpret_cast<const float2*>(vbase + (size_t)l*1024);
            a0 += p * vv.x; a1 += p * vv.y;
        }
        os[d0]   = a0 * sred[h];
        os[d0+1] = a1 * sred[h];
    }
    __syncthreads();

    // --- 7. patches = query + o @ Wout^T + bout; final LN -> out ---
    float r0, r1;
    {
        const float* w0 = ca_out_w + (size_t)d0 * D_;
        float a0 = ca_out_b[d0], a1 = ca_out_b[d0+1];
        for (int e = 0; e < D_; e += 4) {
            const float4 oe = *reinterpret_cast<const float4*>(&os[e]);
            const float4 wa = *reinterpret_cast<const float4*>(w0 + e);
            const float4 wb = *reinterpret_cast<const float4*>(w0 + D_ + e);
            a0 += oe.x*wa.x + oe.y*wa.y + oe.z*wa.z + oe.w*wa.w;
            a1 += oe.x*wb.x + oe.y*wb.y + oe.z*wb.z + oe.w*wb.w;
        }
        r0 = query[d0] + a0;
        r1 = query[d0+1] + a1;
    }
    // final LN (eps 1e-6, norm_w/b)
    {
        float s = r0 + r1;
#pragma unroll
        for (int off = 32; off; off >>= 1) s += __shfl_xor(s, off, 64);
        __syncthreads();   // red reuse safe
        if (lane == 0) red[wave] = s;
        __syncthreads();
        const float mean = (red[0]+red[1]+red[2]+red[3]) * (1.f/D_);
        const float e0 = r0 - mean, e1 = r1 - mean;
        float sq = e0*e0 + e1*e1;
#pragma unroll
        for (int off = 32; off; off >>= 1) sq += __shfl_xor(sq, off, 64);
        if (lane == 0) red[4+wave] = sq;
        __syncthreads();
        const float var = (red[4]+red[5]+red[6]+red[7]) * (1.f/D_);
        const float inv = rsqrtf(var + 1e-6f);
        float* orow = out + ((size_t)(B_*S_) + bp) * D_;
        orow[d0]   = e0*inv*norm_w[d0]   + norm_b[d0];
        orow[d0+1] = e1*inv*norm_w[d0+1] + norm_b[d0+1];
    }
}

extern "C" void kernel_launch(void* const* d_in, const int* in_sizes, int n_in,
                              void* d_out, int out_size, void* d_ws, size_t ws_size,
                              hipStream_t stream)
{
    const int*   byte_seq = (const int*)d_in[0];
    const float* byte_emb = (const float*)d_in[2];
    const float* ng_emb   = (const float*)d_in[3];
    const float* qkv_w = (const float*)d_in[4];
    const float* qkv_b = (const float*)d_in[5];
    const float* out_w = (const float*)d_in[6];
    const float* out_b = (const float*)d_in[7];
    const float* ln1_w = (const float*)d_in[8];
    const float* ln1_b = (const float*)d_in[9];
    const float* ln2_w = (const float*)d_in[10];
    const float* ln2_b = (const float*)d_in[11];
    const float* ff1_w = (const float*)d_in[12];
    const float* ff1_b = (const float*)d_in[13];
    const float* ff2_w = (const float*)d_in[14];
    const float* ff2_b = (const float*)d_in[15];
    const float* ca_qkv_w = (const float*)d_in[16];
    const float* ca_qkv_b = (const float*)d_in[17];
    const float* ca_out_w = (const float*)d_in[18];
    const float* ca_out_b = (const float*)d_in[19];
    const float* ca_ln_w  = (const float*)d_in[20];
    const float* ca_ln_b  = (const float*)d_in[21];
    const float* norm_w   = (const float*)d_in[22];
    const float* norm_b   = (const float*)d_in[23];
    float* out = (float*)d_out;

    char* ws = (char*)d_ws;
    const size_t MB = 1024*1024;
    float*          x     = (float*)(ws);
    char*           bufA  = ws + 16*MB;
    float*          bufB  = (float*)(ws + 48*MB);
    unsigned short* ob    = (unsigned short*)(ws + 64*MB);
    unsigned short* xb    = (unsigned short*)(ws + 72*MB);
    unsigned short* qkvw_b = (unsigned short*)(ws + 80*MB);
    unsigned short* outw_b = (unsigned short*)(ws + 83*MB);
    unsigned short* ff1w_b = (unsigned short*)(ws + 84*MB);
    unsigned short* ff2w_b = (unsigned short*)(ws + 88*MB);
    unsigned short* kvw_b  = (unsigned short*)(ws + 92*MB);

    unsigned short* qkvb = (unsigned short*)bufA;
    unsigned short* ff1b = (unsigned short*)bufA;
    float*          kvf  = (float*)bufA;

    const int M = B_ * S_;

    // 0. one-time weight casts to bf16 (single launch)
    cast5_kernel<<<(C0_+C1_+C2_+C3_+C4_+255)/256, 256, 0, stream>>>(
        qkv_w, out_w, ff1_w, ff2_w, ca_qkv_w + 512*512,
        qkvw_b, outw_b, ff1w_b, ff2w_b, kvw_b);

    // 1. byte embedding + n-gram hash adds
    embed_ngram_kernel<<<M, 128, 0, stream>>>(byte_seq, byte_emb, ng_emb, x, xb);

    // 2. transformer layers
    for (int l = 0; l < L_; ++l) {
        mgemm_kernel<0,1,128><<<dim3(1536/128, M/128), 256, 0, stream>>>(
            xb, qkvw_b + (size_t)l*1536*D_, qkv_b + l*1536, qkvb, M, 1536, D_);
        attn_mfma_kernel<<<dim3(S_/128, B_*H_), 256, 0, stream>>>(qkvb, ob);
        mgemm_kernel<0,0,64><<<dim3(D_/64, M/128), 256, 0, stream>>>(
            ob, outw_b + (size_t)l*D_*D_, out_b + l*D_, bufB, M, D_, D_);
        ln_kernel<<<M, 256, 0, stream>>>(x, xb, x, bufB, ln1_w + l*D_, ln1_b + l*D_, 1e-5f);
        mgemm_kernel<1,1,128><<<dim3(2048/128, M/128), 256, 0, stream>>>(
            xb, ff1w_b + (size_t)l*2048*D_, ff1_b + l*2048, ff1b, M, 2048, D_);
        mgemm_kernel<0,0,64><<<dim3(D_/64, M/128), 256, 0, stream>>>(
            ff1b, ff2w_b + (size_t)l*D_*2048, ff2_b + l*D_, bufB, M, D_, 2048);
        ln_kernel<<<M, 256, 0, stream>>>(x, xb, x, bufB, ln2_w + l*D_, ln2_b + l*D_, 1e-5f);
    }

    // 3. patch cross-attention: kvn LN (bf16 only) -> kv mgemm -> fused tail
    ln_kernel<<<M, 256, 0, stream>>>(nullptr, xb, x, nullptr, ca_ln_w, ca_ln_b, 1e-6f);
    mgemm_kernel<0,0,128><<<dim3(1024/128, M/128), 256, 0, stream>>>(
        xb, kvw_b, ca_qkv_b + 512, kvf, M, 1024, D_);
    patch_tail_kernel<<<B_*NPATCH_, 256, 0, stream>>>(
        x, kvf, ca_qkv_w, ca_qkv_b, ca_out_w, ca_out_b,
        ca_ln_w, ca_ln_b, norm_w, norm_b, out);

    // 4. final LayerNorm of x -> f32 outputs
    ln_kernel<<<M, 256, 0, stream>>>(out, nullptr, x, nullptr, norm_w, norm_b, 1e-6f);
}

// Round 11
// 502.380 us; speedup vs baseline: 22.3162x; 1.0219x over previous
//
#include <hip/hip_runtime.h>
#include <hip/hip_bf16.h>

#define B_ 4
#define S_ 2048
#define D_ 512
#define H_ 8
#define HD_ 64
#define L_ 2
#define V_ 30000
#define NPATCH_ 16
#define PLEN_ 128

typedef short bf16x8 __attribute__((ext_vector_type(8)));
typedef float f32x4 __attribute__((ext_vector_type(4)));

__device__ __forceinline__ unsigned short f2bf(float f) {
    unsigned u = __float_as_uint(f);
    return (unsigned short)((u + 0x7FFFu + ((u >> 16) & 1u)) >> 16);   // RNE
}

// ---------------- merged f32 -> bf16 weight casts (1 launch) ----------------
#define C0_ (2*1536*512/4)
#define C1_ (2*512*512/4)
#define C2_ (2*2048*512/4)
#define C3_ (2*512*2048/4)
#define C4_ (1024*512/4)
__global__ __launch_bounds__(256) void cast5_kernel(
    const float* __restrict__ s0, const float* __restrict__ s1,
    const float* __restrict__ s2, const float* __restrict__ s3,
    const float* __restrict__ s4,
    unsigned short* __restrict__ d0, unsigned short* __restrict__ d1,
    unsigned short* __restrict__ d2, unsigned short* __restrict__ d3,
    unsigned short* __restrict__ d4)
{
    int i = blockIdx.x * 256 + threadIdx.x;
    const float* s; unsigned short* d;
    if      (i < C0_)                  { s = s0; d = d0; }
    else if ((i -= C0_) < C1_)         { s = s1; d = d1; }
    else if ((i -= C1_) < C2_)         { s = s2; d = d2; }
    else if ((i -= C2_) < C3_)         { s = s3; d = d3; }
    else if ((i -= C3_) < C4_)         { s = s4; d = d4; }
    else return;
    const float4 v = *reinterpret_cast<const float4*>(s + (size_t)i * 4);
    ushort4 o;
    o.x = f2bf(v.x); o.y = f2bf(v.y); o.z = f2bf(v.z); o.w = f2bf(v.w);
    *reinterpret_cast<ushort4*>(d + (size_t)i * 4) = o;
}

// ---------------- embed + n-gram hash add (f32 + bf16 shadow) -------------
__global__ __launch_bounds__(128) void embed_ngram_kernel(
    const int* __restrict__ bytes, const float* __restrict__ byte_emb,
    const float* __restrict__ ng_emb, float* __restrict__ x,
    unsigned short* __restrict__ xb)
{
    const int bs = blockIdx.x;
    const int s  = bs % S_;
    const int b  = bs / S_;
    const int d  = threadIdx.x * 4;
    const int* brow = bytes + (size_t)b * S_;

    const int c = brow[s];
    float4 v = *reinterpret_cast<const float4*>(byte_emb + (size_t)c * D_ + d);

    if (s >= 2) {
        int h = (brow[s-2]*961 + brow[s-1]*31 + brow[s]) % V_;
        const float4 g = *reinterpret_cast<const float4*>(ng_emb + ((size_t)0*V_ + h)*D_ + d);
        v.x += 0.25f*g.x; v.y += 0.25f*g.y; v.z += 0.25f*g.z; v.w += 0.25f*g.w;
    }
    if (s >= 3) {
        int h = (brow[s-3]*29791 + brow[s-2]*961 + brow[s-1]*31 + brow[s]) % V_;
        const float4 g = *reinterpret_cast<const float4*>(ng_emb + ((size_t)1*V_ + h)*D_ + d);
        v.x += 0.25f*g.x; v.y += 0.25f*g.y; v.z += 0.25f*g.z; v.w += 0.25f*g.w;
    }
    if (s >= 4) {
        int h = (brow[s-4]*23521 + brow[s-3]*29791 + brow[s-2]*961 + brow[s-1]*31 + brow[s]) % V_;
        const float4 g = *reinterpret_cast<const float4*>(ng_emb + ((size_t)2*V_ + h)*D_ + d);
        v.x += 0.25f*g.x; v.y += 0.25f*g.y; v.z += 0.25f*g.z; v.w += 0.25f*g.w;
    }
    *reinterpret_cast<float4*>(x + (size_t)bs * D_ + d) = v;
    ushort4 o;
    o.x = f2bf(v.x); o.y = f2bf(v.y); o.z = f2bf(v.z); o.w = f2bf(v.w);
    *reinterpret_cast<ushort4*>(xb + (size_t)bs * D_ + d) = o;
}

// ---------------- MFMA bf16 GEMM: Y = X @ W^T + bias [,relu] --------------
// VT=1 (qkv GEMM): n<1024 -> qkvb rows [q|k] (stride 1024); n>=1024 -> V
// written TRANSPOSED to vtb[b][d][s] so attention needs no LDS transpose.
template<int DO_RELU, int BF16OUT, int BN, int VT>
__global__ __launch_bounds__(256) void mgemm_kernel(
    const unsigned short* __restrict__ Xb, const unsigned short* __restrict__ Wb,
    const float* __restrict__ bias, void* __restrict__ Yout,
    unsigned short* __restrict__ vtb, int M, int N, int K)
{
    constexpr int NT  = BN / 32;
    constexpr int NLB = BN / 32;
    __shared__ unsigned short As[128*64];
    __shared__ unsigned short Bs[BN*64];

    const int t    = threadIdx.x;
    const int lane = t & 63;
    const int w    = t >> 6;

    const int nwg = gridDim.x * gridDim.y;
    const int bid = blockIdx.y * gridDim.x + blockIdx.x;
    const int swz = (bid & 7) * (nwg >> 3) + (bid >> 3);
    const int bx  = swz % gridDim.x, by = swz / gridDim.x;

    const int bm   = by * 128, bn = bx * BN;
    const int l15  = lane & 15, lg = lane >> 4;
    const int wr   = w >> 1, wc = w & 1;

    int srow[4], scol[4];
#pragma unroll
    for (int i = 0; i < 4; ++i) {
        const int off = w*1024 + i*4096 + lane*16;
        srow[i] = off >> 7;
        scol[i] = ((off >> 4) & 7) ^ (srow[i] & 7);
    }

    f32x4 acc[4][NT];
#pragma unroll
    for (int mt = 0; mt < 4; ++mt)
#pragma unroll
        for (int nt = 0; nt < NT; ++nt) acc[mt][nt] = (f32x4){0.f,0.f,0.f,0.f};

    for (int kt = 0; kt < K; kt += 64) {
#pragma unroll
        for (int i = 0; i < 4; ++i) {
            const unsigned short* gA = Xb + (size_t)(bm + srow[i]) * K + kt + scol[i]*8;
            __builtin_amdgcn_global_load_lds(
                (const __attribute__((address_space(1))) void*)gA,
                (__attribute__((address_space(3))) void*)&As[w*512 + i*2048], 16, 0, 0);
        }
#pragma unroll
        for (int i = 0; i < NLB; ++i) {
            const unsigned short* gB = Wb + (size_t)(bn + srow[i]) * K + kt + scol[i]*8;
            __builtin_amdgcn_global_load_lds(
                (const __attribute__((address_space(1))) void*)gB,
                (__attribute__((address_space(3))) void*)&Bs[w*512 + i*2048], 16, 0, 0);
        }
        __syncthreads();

#pragma unroll
        for (int ks = 0; ks < 2; ++ks) {
            const int c16 = (ks*4 + lg) ^ (l15 & 7);
            bf16x8 a[4], b[NT];
#pragma unroll
            for (int mt = 0; mt < 4; ++mt)
                a[mt] = *reinterpret_cast<const bf16x8*>(&As[(wr*64 + mt*16 + l15)*64 + c16*8]);
#pragma unroll
            for (int nt = 0; nt < NT; ++nt)
                b[nt] = *reinterpret_cast<const bf16x8*>(&Bs[(wc*(BN/2) + nt*16 + l15)*64 + c16*8]);
#pragma unroll
            for (int mt = 0; mt < 4; ++mt)
#pragma unroll
                for (int nt = 0; nt < NT; ++nt)
                    acc[mt][nt] = __builtin_amdgcn_mfma_f32_16x16x32_bf16(
                        a[mt], b[nt], acc[mt][nt], 0, 0, 0);
        }
        __syncthreads();
    }

    float bv[NT];
#pragma unroll
    for (int nt = 0; nt < NT; ++nt) bv[nt] = bias[bn + wc*(BN/2) + nt*16 + l15];

#pragma unroll
    for (int mt = 0; mt < 4; ++mt) {
#pragma unroll
        for (int nt = 0; nt < NT; ++nt) {
            const int n = bn + wc*(BN/2) + nt*16 + l15;
#pragma unroll
            for (int r = 0; r < 4; ++r) {
                const int m = bm + wr*64 + mt*16 + 4*lg + r;
                float v = acc[mt][nt][r] + bv[nt];
                if (DO_RELU) v = fmaxf(v, 0.f);
                if constexpr (VT) {
                    if (n < 1024)
                        ((unsigned short*)Yout)[(size_t)m * 1024 + n] = f2bf(v);
                    else
                        vtb[((size_t)(m >> 11) * 512 + (n - 1024)) * 2048 + (m & 2047)] = f2bf(v);
                } else if constexpr (BF16OUT) {
                    ((unsigned short*)Yout)[(size_t)m * N + n] = f2bf(v);
                } else {
                    ((float*)Yout)[(size_t)m * N + n] = v;
                }
            }
        }
    }
}

// ---------------- MFMA bf16 causal flash attention (V^T global) ------------
// qkvb rows [q|k] stride 1024; vtb[b][d(512)][s(2048)] pre-transposed V.
// V staging is now 4 vector b128 LDS writes/thread (was 32 conflicted b16).
// P LDS swizzled: col ^= (q>>3 &1)<<4 (write); chunk ^= (l15>>3 &1)<<1 (read).
__global__ __launch_bounds__(256) void attn_mfma_kernel(
    const unsigned short* __restrict__ qkvb, const unsigned short* __restrict__ vtb,
    unsigned short* __restrict__ ob)
{
    __shared__ unsigned short Ks[128*72];
    __shared__ unsigned short Vt[64*136];
    __shared__ unsigned short Plds[4*16*136];

    const int t    = threadIdx.x;
    const int lane = t & 63;
    const int w    = t >> 6;
    const int qp   = blockIdx.x;
    const int bh   = blockIdx.y;
    const int h    = bh & 7;
    const int b    = bh >> 3;

    const unsigned short* base = qkvb + (size_t)b * S_ * 1024;
    const int l15 = lane & 15, lg = lane >> 4;
    const int skey = t >> 1;              // K staging key 0..127
    const int sd0  = (t & 1) * 32;        // K staging d-range
    const int sdv  = t >> 2;              // V staging d-row 0..63
    const int skc  = (t & 3) * 32;        // V staging k-range
    const unsigned short* vbase = vtb + ((size_t)b * 512 + h*64 + sdv) * 2048;
    unsigned short* pw_base = Plds + w*16*136;
    const int pxor = ((l15 >> 3) & 1) << 1;   // P read chunk xor

    bf16x8 kr0, kr1, kr2, kr3, vr0, vr1, vr2, vr3;
#define LOADREG(KT) { \
        const unsigned short* pk_ = base + (size_t)((KT) + skey) * 1024 + 512 + h*64 + sd0; \
        kr0 = *reinterpret_cast<const bf16x8*>(pk_);       \
        kr1 = *reinterpret_cast<const bf16x8*>(pk_ + 8);   \
        kr2 = *reinterpret_cast<const bf16x8*>(pk_ + 16);  \
        kr3 = *reinterpret_cast<const bf16x8*>(pk_ + 24);  \
        const unsigned short* pv_ = vbase + (KT) + skc;    \
        vr0 = *reinterpret_cast<const bf16x8*>(pv_);       \
        vr1 = *reinterpret_cast<const bf16x8*>(pv_ + 8);   \
        vr2 = *reinterpret_cast<const bf16x8*>(pv_ + 16);  \
        vr3 = *reinterpret_cast<const bf16x8*>(pv_ + 24); }

    LOADREG(0);

#pragma unroll
    for (int half = 0; half < 2; ++half) {
        const int qb  = half ? (31 - qp) : qp;
        const int q0w = qb * 64 + w * 16;

        bf16x8 qf0, qf1;
        {
            const unsigned short* qr = base + (size_t)(q0w + l15) * 1024 + h*64 + lg*8;
            qf0 = *reinterpret_cast<const bf16x8*>(qr);
            qf1 = *reinterpret_cast<const bf16x8*>(qr + 32);
        }

        f32x4 oacc[4];
#pragma unroll
        for (int i = 0; i < 4; ++i) oacc[i] = (f32x4){0.f,0.f,0.f,0.f};
        float mrow[4] = {-INFINITY,-INFINITY,-INFINITY,-INFINITY};
        float lrow[4] = {0.f,0.f,0.f,0.f};

        const int ntiles = (qb + 2) >> 1;
        for (int tile = 0; tile < ntiles; ++tile) {
            const int kt = tile * 128;
            __syncthreads();
            // ---- write prefetched regs to LDS (all vector b128) ----
            *reinterpret_cast<bf16x8*>(&Ks[skey*72 + sd0])      = kr0;
            *reinterpret_cast<bf16x8*>(&Ks[skey*72 + sd0 + 8])  = kr1;
            *reinterpret_cast<bf16x8*>(&Ks[skey*72 + sd0 + 16]) = kr2;
            *reinterpret_cast<bf16x8*>(&Ks[skey*72 + sd0 + 24]) = kr3;
            *reinterpret_cast<bf16x8*>(&Vt[sdv*136 + skc])      = vr0;
            *reinterpret_cast<bf16x8*>(&Vt[sdv*136 + skc + 8])  = vr1;
            *reinterpret_cast<bf16x8*>(&Vt[sdv*136 + skc + 16]) = vr2;
            *reinterpret_cast<bf16x8*>(&Vt[sdv*136 + skc + 24]) = vr3;
            __syncthreads();
            const int nkt = (tile + 1 < ntiles) ? (kt + 128) : 0;
            LOADREG(nkt);

            // ---- QK^T ----
            f32x4 sacc[8];
            __builtin_amdgcn_s_setprio(1);
#pragma unroll
            for (int kt16 = 0; kt16 < 8; ++kt16) {
                sacc[kt16] = (f32x4){0.f,0.f,0.f,0.f};
                const unsigned short* kp = &Ks[(kt16*16 + l15)*72 + lg*8];
                bf16x8 k0 = *reinterpret_cast<const bf16x8*>(kp);
                bf16x8 k1 = *reinterpret_cast<const bf16x8*>(kp + 32);
                sacc[kt16] = __builtin_amdgcn_mfma_f32_16x16x32_bf16(qf0, k0, sacc[kt16], 0, 0, 0);
                sacc[kt16] = __builtin_amdgcn_mfma_f32_16x16x32_bf16(qf1, k1, sacc[kt16], 0, 0, 0);
            }
            __builtin_amdgcn_s_setprio(0);

            // ---- scale + causal mask ----
            const bool diag = (tile == ntiles - 1);
#pragma unroll
            for (int kt16 = 0; kt16 < 8; ++kt16) {
#pragma unroll
                for (int r = 0; r < 4; ++r) {
                    float s = sacc[kt16][r] * 0.125f;
                    if (diag) {
                        const int key = kt + kt16*16 + l15;
                        const int q   = q0w + 4*lg + r;
                        if (key > q) s = -INFINITY;
                    }
                    sacc[kt16][r] = s;
                }
            }
            // ---- online softmax over 128 keys ----
#pragma unroll
            for (int r = 0; r < 4; ++r) {
                float tm = fmaxf(
                    fmaxf(fmaxf(sacc[0][r], sacc[1][r]), fmaxf(sacc[2][r], sacc[3][r])),
                    fmaxf(fmaxf(sacc[4][r], sacc[5][r]), fmaxf(sacc[6][r], sacc[7][r])));
#pragma unroll
                for (int off = 8; off; off >>= 1) tm = fmaxf(tm, __shfl_xor(tm, off, 64));
                const float nm = fmaxf(mrow[r], tm);
                const float al = __expf(mrow[r] - nm);
                mrow[r] = nm;
                float ps = 0.f;
                const int prow = (4*lg + r)*136;
                const int cswz = ((lg & 2) << 3);     // q-bit3 keyed col xor
#pragma unroll
                for (int kt16 = 0; kt16 < 8; ++kt16) {
                    const float p = __expf(sacc[kt16][r] - nm);
                    ps += p;
                    pw_base[prow + ((kt16*16 + l15) ^ cswz)] = f2bf(p);
                }
#pragma unroll
                for (int off = 8; off; off >>= 1) ps += __shfl_xor(ps, off, 64);
                lrow[r] = lrow[r]*al + ps;
#pragma unroll
                for (int dt = 0; dt < 4; ++dt) oacc[dt][r] *= al;
            }

            // ---- PV: O[16q x 64d] += P @ V ----
            const unsigned short* pr = &pw_base[l15*136];
            bf16x8 pa0 = *reinterpret_cast<const bf16x8*>(&pr[(( 0 + lg) ^ pxor)*8]);
            bf16x8 pa1 = *reinterpret_cast<const bf16x8*>(&pr[(( 4 + lg) ^ pxor)*8]);
            bf16x8 pa2 = *reinterpret_cast<const bf16x8*>(&pr[(( 8 + lg) ^ pxor)*8]);
            bf16x8 pa3 = *reinterpret_cast<const bf16x8*>(&pr[((12 + lg) ^ pxor)*8]);
            __builtin_amdgcn_s_setprio(1);
#pragma unroll
            for (int dt = 0; dt < 4; ++dt) {
                const unsigned short* vrow = &Vt[(dt*16 + l15)*136];
                bf16x8 v0 = *reinterpret_cast<const bf16x8*>(&vrow[( 0 + lg)*8]);
                bf16x8 v1 = *reinterpret_cast<const bf16x8*>(&vrow[( 4 + lg)*8]);
                bf16x8 v2 = *reinterpret_cast<const bf16x8*>(&vrow[( 8 + lg)*8]);
                bf16x8 v3 = *reinterpret_cast<const bf16x8*>(&vrow[(12 + lg)*8]);
                oacc[dt] = __builtin_amdgcn_mfma_f32_16x16x32_bf16(pa0, v0, oacc[dt], 0, 0, 0);
                oacc[dt] = __builtin_amdgcn_mfma_f32_16x16x32_bf16(pa1, v1, oacc[dt], 0, 0, 0);
                oacc[dt] = __builtin_amdgcn_mfma_f32_16x16x32_bf16(pa2, v2, oacc[dt], 0, 0, 0);
                oacc[dt] = __builtin_amdgcn_mfma_f32_16x16x32_bf16(pa3, v3, oacc[dt], 0, 0, 0);
            }
            __builtin_amdgcn_s_setprio(0);
        }

        // ---- epilogue for this half ----
#pragma unroll
        for (int dt = 0; dt < 4; ++dt) {
#pragma unroll
            for (int r = 0; r < 4; ++r) {
                const int q = q0w + 4*lg + r;
                ob[((size_t)b*S_ + q)*D_ + h*64 + dt*16 + l15] = f2bf(oacc[dt][r] / lrow[r]);
            }
        }
    }
#undef LOADREG
}

// ---------------- LayerNorm (residual add, nullable outputs) ---------------
__global__ __launch_bounds__(256) void ln_kernel(
    float* __restrict__ dst, unsigned short* __restrict__ dst2,
    const float* __restrict__ src, const float* __restrict__ add,
    const float* __restrict__ w, const float* __restrict__ b, float eps)
{
    const int row = blockIdx.x, tid = threadIdx.x;
    const int lane = tid & 63, wave = tid >> 6;
    float2 v = *reinterpret_cast<const float2*>(src + (size_t)row * D_ + tid*2);
    if (add) {
        float2 a = *reinterpret_cast<const float2*>(add + (size_t)row * D_ + tid*2);
        v.x += a.x; v.y += a.y;
    }
    __shared__ float red[8];
    float s = v.x + v.y;
#pragma unroll
    for (int off = 32; off; off >>= 1) s += __shfl_xor(s, off, 64);
    if (lane == 0) red[wave] = s;
    __syncthreads();
    const float mean = (red[0]+red[1]+red[2]+red[3]) * (1.f/D_);
    const float d0 = v.x - mean, d1 = v.y - mean;
    float sq = d0*d0 + d1*d1;
#pragma unroll
    for (int off = 32; off; off >>= 1) sq += __shfl_xor(sq, off, 64);
    if (lane == 0) red[4+wave] = sq;
    __syncthreads();
    const float var = (red[4]+red[5]+red[6]+red[7]) * (1.f/D_);
    const float inv = rsqrtf(var + eps);
    const float o0 = d0*inv*w[tid*2] + b[tid*2];
    const float o1 = d1*inv*w[tid*2+1] + b[tid*2+1];
    if (dst)
        *reinterpret_cast<float2*>(dst + (size_t)row * D_ + tid*2) = make_float2(o0, o1);
    if (dst2) {
        ushort2 u; u.x = f2bf(o0); u.y = f2bf(o1);
        *reinterpret_cast<ushort2*>(dst2 + (size_t)row * D_ + tid*2) = u;
    }
}

// ---------------- fused patch-CA tail ----------------
__global__ __launch_bounds__(256) void patch_tail_kernel(
    const float* __restrict__ x, const float* __restrict__ kvf,
    const float* __restrict__ ca_qkv_w, const float* __restrict__ ca_qkv_b,
    const float* __restrict__ ca_out_w, const float* __restrict__ ca_out_b,
    const float* __restrict__ ca_ln_w, const float* __restrict__ ca_ln_b,
    const float* __restrict__ norm_w, const float* __restrict__ norm_b,
    float* __restrict__ out)
{
    __shared__ float query[512];
    __shared__ float qs[512];
    __shared__ float ps[8*128];
    __shared__ float os[512];
    __shared__ float red[64];
    __shared__ float mred[8], sred[8];

    const int t  = threadIdx.x;
    const int bp = blockIdx.x;
    const int d0 = t * 2;
    const int lane = t & 63, wave = t >> 6;

    {
        const float* base = x + (size_t)bp * PLEN_ * D_ + d0;
        float s0 = 0.f, s1 = 0.f;
        for (int l = 0; l < PLEN_; ++l) {
            float2 v = *reinterpret_cast<const float2*>(base + (size_t)l * D_);
            s0 += v.x; s1 += v.y;
        }
        query[d0] = s0 * (1.f/PLEN_);
        query[d0+1] = s1 * (1.f/PLEN_);
    }
    __syncthreads();

    float qv0 = query[d0], qv1 = query[d0+1];
    {
        float s = qv0 + qv1;
#pragma unroll
        for (int off = 32; off; off >>= 1) s += __shfl_xor(s, off, 64);
        if (lane == 0) red[wave] = s;
        __syncthreads();
        const float mean = (red[0]+red[1]+red[2]+red[3]) * (1.f/D_);
        const float e0 = qv0 - mean, e1 = qv1 - mean;
        float sq = e0*e0 + e1*e1;
#pragma unroll
        for (int off = 32; off; off >>= 1) sq += __shfl_xor(sq, off, 64);
        if (lane == 0) red[4+wave] = sq;
        __syncthreads();
        const float var = (red[4]+red[5]+red[6]+red[7]) * (1.f/D_);
        const float inv = rsqrtf(var + 1e-6f);
        qs[d0]   = e0*inv*ca_ln_w[d0]   + ca_ln_b[d0];
        qs[d0+1] = e1*inv*ca_ln_w[d0+1] + ca_ln_b[d0+1];
    }
    __syncthreads();

    float qp0, qp1;
    {
        const float* w0 = ca_qkv_w + (size_t)d0 * D_;
        float a0 = ca_qkv_b[d0], a1 = ca_qkv_b[d0+1];
        for (int e = 0; e < D_; e += 4) {
            const float4 qn4 = *reinterpret_cast<const float4*>(&qs[e]);
            const float4 wa = *reinterpret_cast<const float4*>(w0 + e);
            const float4 wb = *reinterpret_cast<const float4*>(w0 + D_ + e);
            a0 += qn4.x*wa.x + qn4.y*wa.y + qn4.z*wa.z + qn4.w*wa.w;
            a1 += qn4.x*wb.x + qn4.y*wb.y + qn4.z*wb.z + qn4.w*wb.w;
        }
        qp0 = a0 * 0.125f; qp1 = a1 * 0.125f;
    }
    __syncthreads();
    qs[d0] = qp0; qs[d0+1] = qp1;
    __syncthreads();

    {
        const int h = t >> 5, c = t & 31;
        const float* qh = &qs[h*64];
#pragma unroll
        for (int j = 0; j < 4; ++j) {
            const int l = c*4 + j;
            const float* krow = kvf + ((size_t)bp*PLEN_ + l)*1024 + h*64;
            float acc = 0.f;
            for (int e = 0; e < 64; e += 4) {
                const float4 qe = *reinterpret_cast<const float4*>(qh + e);
                const float4 ke = *reinterpret_cast<const float4*>(krow + e);
                acc += qe.x*ke.x + qe.y*ke.y + qe.z*ke.z + qe.w*ke.w;
            }
            ps[h*128 + l] = acc;
        }
    }
    __syncthreads();

    {
        const int h = t >> 5, c = t & 31;
        float m4 = fmaxf(fmaxf(ps[h*128+c*4], ps[h*128+c*4+1]),
                         fmaxf(ps[h*128+c*4+2], ps[h*128+c*4+3]));
        red[h*8 + (c>>2)] = 0.f;
        __syncthreads();
        float mt_ = m4;
#pragma unroll
        for (int off = 1; off < 4; off <<= 1) mt_ = fmaxf(mt_, __shfl_xor(mt_, off, 64));
        if ((c & 3) == 0) red[h*8 + (c>>2)] = mt_;
        __syncthreads();
        if (t < 8) {
            float m = red[t*8];
#pragma unroll
            for (int j = 1; j < 8; ++j) m = fmaxf(m, red[t*8+j]);
            mred[t] = m;
        }
        __syncthreads();
        const float mh = mred[h];
        float ssum = 0.f;
#pragma unroll
        for (int j = 0; j < 4; ++j) {
            const float p = __expf(ps[h*128 + c*4 + j] - mh);
            ps[h*128 + c*4 + j] = p;
            ssum += p;
        }
#pragma unroll
        for (int off = 1; off < 4; off <<= 1) ssum += __shfl_xor(ssum, off, 64);
        if ((c & 3) == 0) red[h*8 + (c>>2)] = ssum;
        __syncthreads();
        if (t < 8) {
            float s = 0.f;
#pragma unroll
            for (int j = 0; j < 8; ++j) s += red[t*8+j];
            sred[t] = 1.f / s;
        }
    }
    __syncthreads();

    {
        const int h = t >> 5;
        const float* vbase = kvf + (size_t)bp*PLEN_*1024 + 512 + d0;
        float a0 = 0.f, a1 = 0.f;
        const float* ph = &ps[h*128];
        for (int l = 0; l < PLEN_; ++l) {
            const float p = ph[l];
            const float2 vv = *reinterpret_cast<const float2*>(vbase + (size_t)l*1024);
            a0 += p * vv.x; a1 += p * vv.y;
        }
        os[d0]   = a0 * sred[h];
        os[d0+1] = a1 * sred[h];
    }
    __syncthreads();

    float r0, r1;
    {
        const float* w0 = ca_out_w + (size_t)d0 * D_;
        float a0 = ca_out_b[d0], a1 = ca_out_b[d0+1];
        for (int e = 0; e < D_; e += 4) {
            const float4 oe = *reinterpret_cast<const float4*>(&os[e]);
            const float4 wa = *reinterpret_cast<const float4*>(w0 + e);
            const float4 wb = *reinterpret_cast<const float4*>(w0 + D_ + e);
            a0 += oe.x*wa.x + oe.y*wa.y + oe.z*wa.z + oe.w*wa.w;
            a1 += oe.x*wb.x + oe.y*wb.y + oe.z*wb.z + oe.w*wb.w;
        }
        r0 = query[d0] + a0;
        r1 = query[d0+1] + a1;
    }
    {
        float s = r0 + r1;
#pragma unroll
        for (int off = 32; off; off >>= 1) s += __shfl_xor(s, off, 64);
        __syncthreads();
        if (lane == 0) red[wave] = s;
        __syncthreads();
        const float mean = (red[0]+red[1]+red[2]+red[3]) * (1.f/D_);
        const float e0 = r0 - mean, e1 = r1 - mean;
        float sq = e0*e0 + e1*e1;
#pragma unroll
        for (int off = 32; off; off >>= 1) sq += __shfl_xor(sq, off, 64);
        if (lane == 0) red[4+wave] = sq;
        __syncthreads();
        const float var = (red[4]+red[5]+red[6]+red[7]) * (1.f/D_);
        const float inv = rsqrtf(var + 1e-6f);
        float* orow = out + ((size_t)(B_*S_) + bp) * D_;
        orow[d0]   = e0*inv*norm_w[d0]   + norm_b[d0];
        orow[d0+1] = e1*inv*norm_w[d0+1] + norm_b[d0+1];
    }
}

extern "C" void kernel_launch(void* const* d_in, const int* in_sizes, int n_in,
                              void* d_out, int out_size, void* d_ws, size_t ws_size,
                              hipStream_t stream)
{
    const int*   byte_seq = (const int*)d_in[0];
    const float* byte_emb = (const float*)d_in[2];
    const float* ng_emb   = (const float*)d_in[3];
    const float* qkv_w = (const float*)d_in[4];
    const float* qkv_b = (const float*)d_in[5];
    const float* out_w = (const float*)d_in[6];
    const float* out_b = (const float*)d_in[7];
    const float* ln1_w = (const float*)d_in[8];
    const float* ln1_b = (const float*)d_in[9];
    const float* ln2_w = (const float*)d_in[10];
    const float* ln2_b = (const float*)d_in[11];
    const float* ff1_w = (const float*)d_in[12];
    const float* ff1_b = (const float*)d_in[13];
    const float* ff2_w = (const float*)d_in[14];
    const float* ff2_b = (const float*)d_in[15];
    const float* ca_qkv_w = (const float*)d_in[16];
    const float* ca_qkv_b = (const float*)d_in[17];
    const float* ca_out_w = (const float*)d_in[18];
    const float* ca_out_b = (const float*)d_in[19];
    const float* ca_ln_w  = (const float*)d_in[20];
    const float* ca_ln_b  = (const float*)d_in[21];
    const float* norm_w   = (const float*)d_in[22];
    const float* norm_b   = (const float*)d_in[23];
    float* out = (float*)d_out;

    char* ws = (char*)d_ws;
    const size_t MB = 1024*1024;
    float*          x     = (float*)(ws);                    // [0,16M)
    char*           bufA  = ws + 16*MB;                      // [16,48M) qkvb/ff1b/kvf
    float*          bufB  = (float*)(ws + 48*MB);            // [48,64M) proj/ff2 f32
    unsigned short* vtb   = (unsigned short*)(ws + 48*MB);   // aliases bufB (disjoint lifetime)
    unsigned short* ob    = (unsigned short*)(ws + 64*MB);   // [64,72M)
    unsigned short* xb    = (unsigned short*)(ws + 72*MB);   // [72,80M)
    unsigned short* qkvw_b = (unsigned short*)(ws + 80*MB);
    unsigned short* outw_b = (unsigned short*)(ws + 83*MB);
    unsigned short* ff1w_b = (unsigned short*)(ws + 84*MB);
    unsigned short* ff2w_b = (unsigned short*)(ws + 88*MB);
    unsigned short* kvw_b  = (unsigned short*)(ws + 92*MB);

    unsigned short* qkvb = (unsigned short*)bufA;   // bf16 [8192][1024] ([q|k])
    unsigned short* ff1b = (unsigned short*)bufA;   // bf16 [8192][2048]
    float*          kvf  = (float*)bufA;            // f32  [8192][1024] (32 MiB exact)

    const int M = B_ * S_;

    // 0. one-time weight casts to bf16 (single launch)
    cast5_kernel<<<(C0_+C1_+C2_+C3_+C4_+255)/256, 256, 0, stream>>>(
        qkv_w, out_w, ff1_w, ff2_w, ca_qkv_w + 512*512,
        qkvw_b, outw_b, ff1w_b, ff2w_b, kvw_b);

    // 1. byte embedding + n-gram hash adds
    embed_ngram_kernel<<<M, 128, 0, stream>>>(byte_seq, byte_emb, ng_emb, x, xb);

    // 2. transformer layers
    for (int l = 0; l < L_; ++l) {
        mgemm_kernel<0,1,128,1><<<dim3(1536/128, M/128), 256, 0, stream>>>(
            xb, qkvw_b + (size_t)l*1536*D_, qkv_b + l*1536, qkvb, vtb, M, 1536, D_);
        attn_mfma_kernel<<<dim3(S_/128, B_*H_), 256, 0, stream>>>(qkvb, vtb, ob);
        mgemm_kernel<0,0,64,0><<<dim3(D_/64, M/128), 256, 0, stream>>>(
            ob, outw_b + (size_t)l*D_*D_, out_b + l*D_, bufB, nullptr, M, D_, D_);
        ln_kernel<<<M, 256, 0, stream>>>(x, xb, x, bufB, ln1_w + l*D_, ln1_b + l*D_, 1e-5f);
        mgemm_kernel<1,1,128,0><<<dim3(2048/128, M/128), 256, 0, stream>>>(
            xb, ff1w_b + (size_t)l*2048*D_, ff1_b + l*2048, ff1b, nullptr, M, 2048, D_);
        mgemm_kernel<0,0,64,0><<<dim3(D_/64, M/128), 256, 0, stream>>>(
            ff1b, ff2w_b + (size_t)l*D_*2048, ff2_b + l*D_, bufB, nullptr, M, D_, 2048);
        ln_kernel<<<M, 256, 0, stream>>>(x, xb, x, bufB, ln2_w + l*D_, ln2_b + l*D_, 1e-5f);
    }

    // 3. patch cross-attention: kvn LN (bf16 only) -> kv mgemm -> fused tail
    ln_kernel<<<M, 256, 0, stream>>>(nullptr, xb, x, nullptr, ca_ln_w, ca_ln_b, 1e-6f);
    mgemm_kernel<0,0,128,0><<<dim3(1024/128, M/128), 256, 0, stream>>>(
        xb, kvw_b, ca_qkv_b + 512, kvf, nullptr, M, 1024, D_);
    patch_tail_kernel<<<B_*NPATCH_, 256, 0, stream>>>(
        x, kvf, ca_qkv_w, ca_qkv_b, ca_out_w, ca_out_b,
        ca_ln_w, ca_ln_b, norm_w, norm_b, out);

    // 4. final LayerNorm of x -> f32 outputs
    ln_kernel<<<M, 256, 0, stream>>>(out, nullptr, x, nullptr, norm_w, norm_b, 1e-6f);
}